// Round 2
// baseline (416.474 us; speedup 1.0000x reference)
//
#include <hip/hip_runtime.h>
#include <math.h>

#define NN 25000      // nodes
#define NE 400000     // edges
#define DD 128        // hidden dim
#define HD 384        // heads * dim
#define NEG 0.2f
#define EPS 1e-5f

typedef unsigned int u32;
typedef unsigned short u16;
typedef __attribute__((ext_vector_type(8))) short short8;   // 8 bf16 (4 VGPRs)
typedef __attribute__((ext_vector_type(4))) float floatx4;  // MFMA accumulator
typedef __attribute__((ext_vector_type(2))) float f32x2;    // packed-f32 pair

// ---- bf16 helpers (RNE) ----
__device__ __forceinline__ u32 bf16_1(float x) {
    u32 u = __float_as_uint(x);
    return (u + 0x7fffu + ((u >> 16) & 1u)) >> 16;
}
__device__ __forceinline__ float blo(u32 u) { return __uint_as_float(u << 16); }
__device__ __forceinline__ float bhi(u32 u) { return __uint_as_float(u & 0xffff0000u); }

__device__ __forceinline__ void up8(uint4 u, float* f) {
    f[0] = blo(u.x); f[1] = bhi(u.x); f[2] = blo(u.y); f[3] = bhi(u.y);
    f[4] = blo(u.z); f[5] = bhi(u.z); f[6] = blo(u.w); f[7] = bhi(u.w);
}
__device__ __forceinline__ void up8f2(uint4 u, f32x2* f) {
    f[0] = f32x2{blo(u.x), bhi(u.x)};
    f[1] = f32x2{blo(u.y), bhi(u.y)};
    f[2] = f32x2{blo(u.z), bhi(u.z)};
    f[3] = f32x2{blo(u.w), bhi(u.w)};
}

// ---- packed f32 ops (CDNA2+ v_pk_*, full rate: 2 f32 lanes / inst) ----
__device__ __forceinline__ f32x2 pk_add(f32x2 a, f32x2 b) {
    f32x2 d; asm("v_pk_add_f32 %0, %1, %2" : "=v"(d) : "v"(a), "v"(b)); return d;
}
__device__ __forceinline__ f32x2 pk_fma(f32x2 a, f32x2 b, f32x2 c) {
    f32x2 d; asm("v_pk_fma_f32 %0, %1, %2, %3" : "=v"(d) : "v"(a), "v"(b), "v"(c)); return d;
}
__device__ __forceinline__ f32x2 fabs2(f32x2 v) {
    u32 a = __float_as_uint(v.x) & 0x7fffffffu;
    u32 b = __float_as_uint(v.y) & 0x7fffffffu;
    return f32x2{__uint_as_float(a), __uint_as_float(b)};
}

// ---------------- CSR construction (grouped by dst) ----------------

__global__ void k_scan1(const int* __restrict__ cnt, int* __restrict__ bsum) {
    __shared__ int sh[256];
    int i = blockIdx.x * 256 + threadIdx.x;
    sh[threadIdx.x] = (i < NN) ? (cnt[i] + 1) : 0;
    __syncthreads();
    for (int o = 128; o >= 1; o >>= 1) {
        if ((int)threadIdx.x < o) sh[threadIdx.x] += sh[threadIdx.x + o];
        __syncthreads();
    }
    if (threadIdx.x == 0) bsum[blockIdx.x] = sh[0];
}

__global__ void k_scan3(const int* __restrict__ cnt, const int* __restrict__ bsum,
                        int* __restrict__ row_ptr, int* __restrict__ col_src,
                        int* __restrict__ cur) {
    __shared__ int sh[256];
    __shared__ int sb[128];
    int tid = threadIdx.x;
    if (tid < 128) sb[tid] = (tid < 98) ? bsum[tid] : 0;
    __syncthreads();
    for (int o = 1; o < 128; o <<= 1) {
        int t = (tid >= o && tid < 128) ? sb[tid - o] : 0;
        __syncthreads();
        if (tid < 128) sb[tid] += t;
        __syncthreads();
    }
    int i = blockIdx.x * 256 + tid;
    int v = (i < NN) ? (cnt[i] + 1) : 0;
    sh[tid] = v;
    __syncthreads();
    for (int o = 1; o < 256; o <<= 1) {
        int t = (tid >= o) ? sh[tid - o] : 0;
        __syncthreads();
        sh[tid] += t;
        __syncthreads();
    }
    int base = blockIdx.x ? sb[blockIdx.x - 1] : 0;
    if (i < NN) {
        int incl = base + sh[tid];
        row_ptr[i + 1] = incl;
        int p = incl - v;
        col_src[p] = i;            // self loop first
        cur[i] = p + 1;
    }
    if (i == 0) row_ptr[0] = 0;
}

__global__ void k_fill_edges(const int* __restrict__ src, const int* __restrict__ dst,
                             int* __restrict__ cur, int* __restrict__ col_src) {
    int e = blockIdx.x * 256 + threadIdx.x;
    if (e < NE) { int p = atomicAdd(&cur[dst[e]], 1); col_src[p] = src[e]; }
}

// ---------------- one cast/init kernel (also the edge-count pass) ----------------
__global__ void k_cast_all(const float* __restrict__ x,
                           const float* __restrict__ Wl1, const float* __restrict__ Wr1,
                           const float* __restrict__ W1,
                           const float* __restrict__ Wl2, const float* __restrict__ Wr2,
                           const float* __restrict__ W2,
                           const float* __restrict__ bl1, const float* __restrict__ br1,
                           const float* __restrict__ bl2, const float* __restrict__ br2,
                           const float* __restrict__ att1, const float* __restrict__ att2,
                           const int* __restrict__ edst,
                           u16* __restrict__ xb, u16* __restrict__ WfT1,
                           u16* __restrict__ W1T, u16* __restrict__ WfT2,
                           u16* __restrict__ W2T,
                           float* __restrict__ fb1, float* __restrict__ fb2,
                           float* __restrict__ attc1, float* __restrict__ attc2,
                           int* __restrict__ cnt, float* __restrict__ stats) {
    int i = blockIdx.x * 256 + threadIdx.x;
    if (i < 400000) {   // x cast, 8 elems/thread, coalesced 16B writes
        const float4* xp = (const float4*)(x + (size_t)i * 8);
        float4 a = xp[0], b = xp[1];
        uint4 w;
        w.x = bf16_1(a.x) | (bf16_1(a.y) << 16);
        w.y = bf16_1(a.z) | (bf16_1(a.w) << 16);
        w.z = bf16_1(b.x) | (bf16_1(b.y) << 16);
        w.w = bf16_1(b.z) | (bf16_1(b.w) << 16);
        *(uint4*)(xb + (size_t)i * 8) = w;
        return;
    }
    i -= 400000;
    if (i < 400000) { atomicAdd(&cnt[edst[i]], 1); return; }   // edge count
    i -= 400000;
    if (i < 49152) { int k = i / 384, n = i - k * 384; WfT1[n * 128 + k] = (u16)bf16_1(Wl1[i]); return; }
    i -= 49152;
    if (i < 49152) { int k = i / 384, n = i - k * 384; WfT1[(384 + n) * 128 + k] = (u16)bf16_1(Wr1[i]); return; }
    i -= 49152;
    if (i < 49152) { int k = i / 128, n = i - k * 128; W1T[n * 384 + k] = (u16)bf16_1(W1[i]); return; }
    i -= 49152;
    if (i < 49152) { int k = i / 384, n = i - k * 384; WfT2[n * 128 + k] = (u16)bf16_1(Wl2[i]); return; }
    i -= 49152;
    if (i < 49152) { int k = i / 384, n = i - k * 384; WfT2[(384 + n) * 128 + k] = (u16)bf16_1(Wr2[i]); return; }
    i -= 49152;
    if (i < 98304) { int k = i / 128, n = i - k * 128; W2T[n * 768 + k] = (u16)bf16_1(W2[i]); return; }
    i -= 98304;
    if (i < 768) { fb1[i] = (i < 384) ? bl1[i] : br1[i - 384]; return; }
    i -= 768;
    if (i < 768) { fb2[i] = (i < 384) ? bl2[i] : br2[i - 384]; return; }
    i -= 768;
    // pre-scaled attention vectors: 0.6 * log2(e) * att
    if (i < 384) { attc1[i] = att1[i] * 0.86561702f; return; }
    i -= 384;
    if (i < 384) { attc2[i] = att2[i] * 0.86561702f; return; }
    i -= 384;
    if (i < 512) stats[i] = 0.f;
}
#define CAST_TOTAL (400000 + 400000 + 5 * 49152 + 98304 + 1536 + 768 + 512)

// ---------------- K=128 single-shot GEMM (the xl|xr transforms) ----------------
__global__ __launch_bounds__(256) void k_gemm_k128(
        const u16* __restrict__ A, const u16* __restrict__ BT,
        const float* __restrict__ bias, u16* __restrict__ Cb, int M) {
    __shared__ short sA[128 * 128];
    __shared__ short sB[128 * 128];
    int tid = threadIdx.x;
    int wv = tid >> 6, lane = tid & 63;
    int quad = lane >> 4, m16 = lane & 15;
    int mb = blockIdx.y * 128, nb = blockIdx.x * 128;

#pragma unroll
    for (int j = 0; j < 8; ++j) {
        int L = j * 256 + tid;
        int r = L >> 4, c8 = (L & 15) ^ (r & 15);
        int gr = mb + r; gr = gr < M ? gr : M - 1;
        __builtin_amdgcn_global_load_lds(
            (const __attribute__((address_space(1))) void*)(A + (size_t)gr * 128 + c8 * 8),
            (__attribute__((address_space(3))) void*)(sA + (size_t)L * 8), 16, 0, 0);
    }
#pragma unroll
    for (int j = 0; j < 8; ++j) {
        int L = j * 256 + tid;
        int r = L >> 4, c8 = (L & 15) ^ (r & 15);
        __builtin_amdgcn_global_load_lds(
            (const __attribute__((address_space(1))) void*)(BT + (size_t)(nb + r) * 128 + c8 * 8),
            (__attribute__((address_space(3))) void*)(sB + (size_t)L * 8), 16, 0, 0);
    }
    __syncthreads();

    floatx4 acc[2][8];
#pragma unroll
    for (int mf = 0; mf < 2; ++mf)
#pragma unroll
        for (int nf = 0; nf < 8; ++nf)
#pragma unroll
            for (int r = 0; r < 4; ++r) acc[mf][nf][r] = 0.f;

#pragma unroll
    for (int ks = 0; ks < 4; ++ks) {
        int slot = (ks * 4 + quad) ^ m16;
        int row0 = wv * 32 + m16, row1 = row0 + 16;
        short8 a0 = *(const short8*)(sA + ((size_t)row0 * 16 + slot) * 8);
        short8 a1 = *(const short8*)(sA + ((size_t)row1 * 16 + slot) * 8);
#pragma unroll
        for (int nf = 0; nf < 8; ++nf) {
            short8 b = *(const short8*)(sB + ((size_t)(nf * 16 + m16) * 16 + slot) * 8);
            acc[0][nf] = __builtin_amdgcn_mfma_f32_16x16x32_bf16(a0, b, acc[0][nf], 0, 0, 0);
            acc[1][nf] = __builtin_amdgcn_mfma_f32_16x16x32_bf16(a1, b, acc[1][nf], 0, 0, 0);
        }
    }
    __syncthreads();

#pragma unroll
    for (int mf = 0; mf < 2; ++mf)
#pragma unroll
        for (int nf = 0; nf < 8; ++nf)
#pragma unroll
            for (int r = 0; r < 4; ++r) {
                int row = wv * 32 + mf * 16 + quad * 4 + r;
                int col = nf * 16 + m16;
                sA[row * 128 + col] = (short)bf16_1(acc[mf][nf][r] + bias[nb + col]);
            }
    __syncthreads();
    int xr = nb >= 384;
    int h = (xr ? (nb - 384) : nb) >> 7;
    u16* cb = Cb + ((size_t)(xr * 3 + h) * NN) * 128;
#pragma unroll
    for (int i = 0; i < 8; ++i) {
        int u = i * 256 + tid;
        int row = u >> 4, c8 = u & 15;
        int grow = mb + row;
        if (grow < M)
            *(uint4*)(cb + (size_t)grow * 128 + c8 * 8) = *(const uint4*)(sA + (size_t)u * 8);
    }
}

// ---------------- bf16 MFMA GEMM (K-loop): C[M,N] = A[M,K] @ BT[N,K]^T ----------------
__global__ __launch_bounds__(256) void k_gemm_bf(
        const u16* __restrict__ A, const u16* __restrict__ BT,
        const float* __restrict__ bias,
        float* __restrict__ Cf, float* __restrict__ stats,
        int M, int N, int K, int lda) {
    __shared__ short smem[9216];    // 18 KB: 16K staging/tile + 2K stat partials
    short* sA = smem;               // 64*64
    short* sB = smem + 4096;        // 64*64
    int tid = threadIdx.x;
    int wv = tid >> 6, lane = tid & 63;
    int quad = lane >> 4, m16 = lane & 15;
    int sw = m16 & 7;
    int mb = blockIdx.y * 64, nb = blockIdx.x * 64;

    floatx4 acc[4];
#pragma unroll
    for (int nf = 0; nf < 4; ++nf)
#pragma unroll
        for (int r = 0; r < 4; ++r) acc[nf][r] = 0.f;

    for (int k0 = 0; k0 < K; k0 += 64) {
#pragma unroll
        for (int j = 0; j < 2; ++j) {
            int L = j * 256 + tid;
            int r = L >> 3, c8 = (L & 7) ^ (r & 7);
            int gr = mb + r; gr = gr < M ? gr : M - 1;
            __builtin_amdgcn_global_load_lds(
                (const __attribute__((address_space(1))) void*)(A + (size_t)gr * lda + k0 + c8 * 8),
                (__attribute__((address_space(3))) void*)(sA + (size_t)L * 8), 16, 0, 0);
        }
#pragma unroll
        for (int j = 0; j < 2; ++j) {
            int L = j * 256 + tid;
            int r = L >> 3, c8 = (L & 7) ^ (r & 7);
            __builtin_amdgcn_global_load_lds(
                (const __attribute__((address_space(1))) void*)(BT + (size_t)(nb + r) * K + k0 + c8 * 8),
                (__attribute__((address_space(3))) void*)(sB + (size_t)L * 8), 16, 0, 0);
        }
        __syncthreads();
#pragma unroll
        for (int ks = 0; ks < 2; ++ks) {
            int t = (ks * 4 + quad) ^ sw;
            const short* pa = sA + t * 8;
            const short* pb = sB + t * 8;
            short8 a0 = *(const short8*)(pa + (wv * 16 + m16) * 64);
#pragma unroll
            for (int nf = 0; nf < 4; ++nf) {
                short8 b = *(const short8*)(pb + (nf * 16 + m16) * 64);
                acc[nf] = __builtin_amdgcn_mfma_f32_16x16x32_bf16(a0, b, acc[nf], 0, 0, 0);
            }
        }
        __syncthreads();
    }
    float* fs = (float*)smem;
#pragma unroll
    for (int nf = 0; nf < 4; ++nf)
#pragma unroll
        for (int r = 0; r < 4; ++r) {
            int row = wv * 16 + quad * 4 + r;
            int col = nf * 16 + m16;
            fs[row * 64 + col] = acc[nf][r] + (bias ? bias[nb + col] : 0.f);
        }
    __syncthreads();
#pragma unroll
    for (int i = 0; i < 4; ++i) {
        int u = i * 256 + tid;
        int row = u >> 4, c4 = u & 15;
        int grow = mb + row;
        if (grow < M)
            *(float4*)(Cf + (size_t)grow * N + nb + c4 * 4) = *(const float4*)(fs + (size_t)u * 4);
    }
    if (stats) {
        float* ps = (float*)(smem + 8192);   // [2][4][64]
        int col = tid & 63, qr = tid >> 6;
        int vr = M - mb; vr = vr < 64 ? vr : 64;
        int r0 = qr * 16, r1 = r0 + 16 < vr ? r0 + 16 : vr;
        float s = 0.f, q = 0.f;
        for (int r = r0; r < r1; ++r) { float v = fs[r * 64 + col]; s += v; q += v * v; }
        ps[qr * 64 + col] = s;
        ps[256 + qr * 64 + col] = q;
        __syncthreads();
        if (tid < 64) {
            float ss = ps[tid] + ps[64 + tid] + ps[128 + tid] + ps[192 + tid];
            atomicAdd(&stats[nb + tid], ss);
        } else if (tid < 128) {
            int c = tid - 64;
            float qq = ps[256 + c] + ps[320 + c] + ps[384 + c] + ps[448 + c];
            atomicAdd(&stats[128 + nb + c], qq);
        }
    }
}

// ---------------- GATv2 aggregate: 3 heads FUSED in one pass ----------------
// wave = 1 node; 4 groups of 16 lanes, 1 edge per group per iteration.
// Score math packed-f32 (v_pk_*): att·leaky(v) = (0.6·log2e·att)·(v + 2/3·|v|),
// weight = exp2(p). attc is the pre-scaled att table.
__global__ __launch_bounds__(256) void k_gat3(
        const u32* __restrict__ XLb, const u32* __restrict__ XRb,
        const float* __restrict__ attc, const float* __restrict__ bias,
        const int* __restrict__ row_ptr, const int* __restrict__ col_src,
        u32* __restrict__ outb) {
    int node = blockIdx.x * 4 + (threadIdx.x >> 6);
    int lane = threadIdx.x & 63;
    int g = lane >> 4, gl = lane & 15;

    const u32* XL0 = XLb;
    const u32* XL1 = XLb + (size_t)NN * 64;
    const u32* XL2 = XLb + (size_t)2 * NN * 64;

    f32x2 xr[3][4], a6[3][4], acc[3][4];
    float l[3];
    const f32x2 c23 = {0.66666667f, 0.66666667f};
#pragma unroll
    for (int h = 0; h < 3; ++h) {
        uint4 u = *(const uint4*)(XRb + (size_t)h * NN * 64 + (size_t)node * 64 + 4 * gl);
        up8f2(u, xr[h]);
#pragma unroll
        for (int j = 0; j < 4; ++j) {
            a6[h][j] = *(const f32x2*)(attc + h * 128 + 8 * gl + 2 * j);
            acc[h][j] = f32x2{0.f, 0.f};
        }
        l[h] = 0.f;
    }

    int e0 = row_ptr[node];
    int cnt = row_ptr[node + 1] - e0;
    int elast = e0 + cnt - 1;

    int ea = e0 + g; ea = ea < elast ? ea : elast;
    u32 voff = (u32)col_src[ea] * 64 + 4 * gl;
    uint4 u0 = *(const uint4*)(XL0 + voff);
    uint4 u1 = *(const uint4*)(XL1 + voff);
    uint4 u2 = *(const uint4*)(XL2 + voff);

    for (int t = g; t < cnt; t += 4) {
        int en = e0 + t + 4; en = en < elast ? en : elast;
        u32 voffn = (u32)col_src[en] * 64 + 4 * gl;
        uint4 n0 = *(const uint4*)(XL0 + voffn);
        uint4 n1 = *(const uint4*)(XL1 + voffn);
        uint4 n2 = *(const uint4*)(XL2 + voffn);

#pragma unroll
        for (int h = 0; h < 3; ++h) {
            uint4 uh = (h == 0) ? u0 : (h == 1) ? u1 : u2;
            f32x2 xa[4];
            up8f2(uh, xa);
            f32x2 p2 = {0.f, 0.f};
#pragma unroll
            for (int j = 0; j < 4; ++j) {
                f32x2 v = pk_add(xa[j], xr[h][j]);
                f32x2 tt = pk_fma(fabs2(v), c23, v);
                p2 = pk_fma(tt, a6[h][j], p2);
            }
            float p = p2.x + p2.y;
#pragma unroll
            for (int o = 1; o <= 8; o <<= 1) p += __shfl_xor(p, o);
            float w = __builtin_amdgcn_exp2f(p);
            l[h] += w;
            f32x2 w2 = {w, w};
#pragma unroll
            for (int j = 0; j < 4; ++j) acc[h][j] = pk_fma(xa[j], w2, acc[h][j]);
        }
        u0 = n0; u1 = n1; u2 = n2;
    }

    // cross-group reduce (16-lane groups -> full wave)
#pragma unroll
    for (int o = 16; o <= 32; o <<= 1) {
#pragma unroll
        for (int h = 0; h < 3; ++h) {
            l[h] += __shfl_xor(l[h], o);
#pragma unroll
            for (int j = 0; j < 4; ++j) {
                f32x2 s;
                s.x = __shfl_xor(acc[h][j].x, o);
                s.y = __shfl_xor(acc[h][j].y, o);
                acc[h][j] = pk_add(acc[h][j], s);
            }
        }
    }

    if (g == 0) {
#pragma unroll
        for (int h = 0; h < 3; ++h) {
            float r = 1.f / l[h];
            float bv[8];
            *(float4*)&bv[0] = *(const float4*)&bias[h * 128 + 8 * gl];
            *(float4*)&bv[4] = *(const float4*)&bias[h * 128 + 8 * gl + 4];
            uint4 w;
            w.x = bf16_1(fmaf(acc[h][0].x, r, bv[0])) | (bf16_1(fmaf(acc[h][0].y, r, bv[1])) << 16);
            w.y = bf16_1(fmaf(acc[h][1].x, r, bv[2])) | (bf16_1(fmaf(acc[h][1].y, r, bv[3])) << 16);
            w.z = bf16_1(fmaf(acc[h][2].x, r, bv[4])) | (bf16_1(fmaf(acc[h][2].y, r, bv[5])) << 16);
            w.w = bf16_1(fmaf(acc[h][3].x, r, bv[6])) | (bf16_1(fmaf(acc[h][3].y, r, bv[7])) << 16);
            *(uint4*)(outb + (size_t)node * 384 + h * 64 + 4 * gl) = w;
        }
    }
}

// ---------------- BN apply (stats pre-accumulated in the GEMM) ----------------
__global__ void k_bn_apply(float* __restrict__ y, const float* __restrict__ stats,
                           const float* __restrict__ g, const float* __restrict__ be,
                           u16* __restrict__ yb, int wf) {
    int i = blockIdx.x * 256 + threadIdx.x;
    if (i >= NN * DD / 8) return;
    int idx = i * 8;
    int c0 = idx & 127;
    float v[8];
    *(float4*)&v[0] = *(const float4*)(y + idx);
    *(float4*)&v[4] = *(const float4*)(y + idx + 4);
    const float minv = 1.f / (float)NN;
#pragma unroll
    for (int k = 0; k < 8; ++k) {
        int c = c0 + k;
        float mu = stats[c] * minv;
        float var = stats[128 + c] * minv - mu * mu;
        float sc = g[c] * rsqrtf(var + EPS);
        float sh = be[c] - mu * sc;
        v[k] = fmaxf(fmaf(v[k], sc, sh), 0.f);
    }
    if (wf) {
        *(float4*)(y + idx) = *(const float4*)&v[0];
        *(float4*)(y + idx + 4) = *(const float4*)&v[4];
    }
    if (yb) {
        uint4 w;
        w.x = bf16_1(v[0]) | (bf16_1(v[1]) << 16);
        w.y = bf16_1(v[2]) | (bf16_1(v[3]) << 16);
        w.z = bf16_1(v[4]) | (bf16_1(v[5]) << 16);
        w.w = bf16_1(v[6]) | (bf16_1(v[7]) << 16);
        *(uint4*)(yb + idx) = w;
    }
}

// ---------------- launch ----------------

extern "C" void kernel_launch(void* const* d_in, const int* in_sizes, int n_in,
                              void* d_out, int out_size, void* d_ws, size_t ws_size,
                              hipStream_t stream) {
    const float* x    = (const float*)d_in[0];
    const int*   ei   = (const int*)d_in[1];
    const float* Wl1  = (const float*)d_in[2];
    const float* bl1  = (const float*)d_in[3];
    const float* Wr1  = (const float*)d_in[4];
    const float* br1  = (const float*)d_in[5];
    const float* att1 = (const float*)d_in[6];
    const float* bc1  = (const float*)d_in[7];
    const float* g1   = (const float*)d_in[8];
    const float* be1  = (const float*)d_in[9];
    const float* Wl2  = (const float*)d_in[10];
    const float* bl2  = (const float*)d_in[11];
    const float* Wr2  = (const float*)d_in[12];
    const float* br2  = (const float*)d_in[13];
    const float* att2 = (const float*)d_in[14];
    const float* bc2  = (const float*)d_in[15];
    const float* g2   = (const float*)d_in[16];
    const float* be2  = (const float*)d_in[17];
    const float* W1   = (const float*)d_in[18];
    const float* b1   = (const float*)d_in[19];
    const float* W2   = (const float*)d_in[20];
    const float* b2   = (const float*)d_in[21];
    const int* esrc = ei;
    const int* edst = ei + NE;
    float* out = (float*)d_out;

    // ---- workspace layout ----
    float* bufD   = (float*)d_ws;          // mid fp32 [NN,128]      12.8 MB
    float* stats  = bufD + 3200000;        // 512 f (BN1 +0, BN2 +256)
    int* row_ptr  = (int*)(stats + 512);   // 25002
    int* cnt      = row_ptr + 25002;       // 25000
    int* col_src  = cnt + 25000;           // 425000
    int* bsum     = col_src + 425000;      // 132 (pad)
    float* fb1    = (float*)(bsum + 132);  // 768 fused bias L1
    float* fb2    = fb1 + 768;             // 768 fused bias L2
    float* attc1  = fb2 + 768;             // 384 pre-scaled att L1
    float* attc2  = attc1 + 384;           // 384 pre-scaled att L2
    u16* xb       = (u16*)(attc2 + 384);   // x bf16 [NN,128]         6.4 MB
    u16* XLb      = xb + 3200000;          // head-major xl [3][NN][128]  19.2 MB
    u16* XRb      = XLb + 3 * NN * 128;    // head-major xr [3][NN][128]
    u16* bufCat   = XRb + 3 * NN * 128;    // [NN,768] h2|x_in bf16  38.4 MB
    u16* bufDb    = bufCat + 19200000;     // h bf16 [NN,128]         6.4 MB
    u16* WfT1     = bufDb + 3200000;       // [768][128]
    u16* W1T      = WfT1 + 98304;          // [128][384]
    u16* WfT2     = W1T + 49152;           // [768][128]
    u16* W2T      = WfT2 + 98304;          // [128][768]

    // zero cnt, then casts + transposes + biases + att prescale + edge-count + stats zero
    hipMemsetAsync(cnt, 0, NN * sizeof(int), stream);
    k_cast_all<<<(CAST_TOTAL + 255) / 256, 256, 0, stream>>>(
        x, Wl1, Wr1, W1, Wl2, Wr2, W2, bl1, br1, bl2, br2, att1, att2, edst,
        xb, WfT1, W1T, WfT2, W2T, fb1, fb2, attc1, attc2, cnt, stats);

    // CSR scans (scan2 folded into scan3)
    k_scan1<<<98, 256, 0, stream>>>(cnt, bsum);
    k_scan3<<<98, 256, 0, stream>>>(cnt, bsum, row_ptr, col_src, cnt);
    k_fill_edges<<<(NE + 255) / 256, 256, 0, stream>>>(esrc, edst, cnt, col_src);

    dim3 blk(256);
    dim3 gK(6, (NN + 127) / 128);        // K=128 GEMM
    dim3 g64(2, (NN + 63) / 64);         // BM=64 GEMMs: 782 blocks
    dim3 gGat((NN + 3) / 4);             // gat: 1 block-col, heads fused

    // layer 1
    k_gemm_k128<<<gK, blk, 0, stream>>>(xb, WfT1, fb1, XLb, NN);
    k_gat3<<<gGat, blk, 0, stream>>>((const u32*)XLb, (const u32*)XRb, attc1, bc1,
                                     row_ptr, col_src, (u32*)bufCat + 192);

    // mid MLP (+BN stats folded) + BN apply
    k_gemm_bf<<<g64, blk, 0, stream>>>(bufCat + 384, W1T, b1, bufD, stats, NN, DD, HD, 768);
    k_bn_apply<<<(NN * DD / 8 + 255) / 256, 256, 0, stream>>>(bufD, stats, g1, be1, bufDb, 0);

    // layer 2
    k_gemm_k128<<<gK, blk, 0, stream>>>(bufDb, WfT2, fb2, XLb, NN);
    k_gat3<<<gGat, blk, 0, stream>>>((const u32*)XLb, (const u32*)XRb, attc2, bc2,
                                     row_ptr, col_src, (u32*)bufCat);

    // final GEMM (+BN stats folded) + BN apply
    k_gemm_bf<<<g64, blk, 0, stream>>>(bufCat, W2T, b2, out, stats + 256, NN, DD, 768, 768);
    k_bn_apply<<<(NN * DD / 8 + 255) / 256, 256, 0, stream>>>(out, stats + 256, g2, be2, nullptr, 1);
}

// Round 3
// 383.134 us; speedup vs baseline: 1.0870x; 1.0870x over previous
//
#include <hip/hip_runtime.h>
#include <math.h>

#define NN 25000      // nodes
#define NE 400000     // edges
#define DD 128        // hidden dim
#define HD 384        // heads * dim
#define NEG 0.2f
#define EPS 1e-5f

typedef unsigned int u32;
typedef unsigned short u16;
typedef __attribute__((ext_vector_type(8))) short short8;   // 8 bf16 (4 VGPRs)
typedef __attribute__((ext_vector_type(4))) float floatx4;  // MFMA accumulator
typedef __attribute__((ext_vector_type(2))) float f32x2;    // packed-f32 pair

// ---- bf16 helpers (RNE) ----
__device__ __forceinline__ u32 bf16_1(float x) {
    u32 u = __float_as_uint(x);
    return (u + 0x7fffu + ((u >> 16) & 1u)) >> 16;
}
__device__ __forceinline__ float blo(u32 u) { return __uint_as_float(u << 16); }
__device__ __forceinline__ float bhi(u32 u) { return __uint_as_float(u & 0xffff0000u); }

__device__ __forceinline__ void up8f2(uint4 u, f32x2* f) {
    f[0] = f32x2{blo(u.x), bhi(u.x)};
    f[1] = f32x2{blo(u.y), bhi(u.y)};
    f[2] = f32x2{blo(u.z), bhi(u.z)};
    f[3] = f32x2{blo(u.w), bhi(u.w)};
}

// ---- packed f32 ops (CDNA v_pk_*, 2 f32 lanes / inst) ----
__device__ __forceinline__ f32x2 pk_add(f32x2 a, f32x2 b) {
    f32x2 d; asm("v_pk_add_f32 %0, %1, %2" : "=v"(d) : "v"(a), "v"(b)); return d;
}
__device__ __forceinline__ f32x2 pk_fma(f32x2 a, f32x2 b, f32x2 c) {
    f32x2 d; asm("v_pk_fma_f32 %0, %1, %2, %3" : "=v"(d) : "v"(a), "v"(b), "v"(c)); return d;
}
__device__ __forceinline__ f32x2 fabs2(f32x2 v) {
    u32 a = __float_as_uint(v.x) & 0x7fffffffu;
    u32 b = __float_as_uint(v.y) & 0x7fffffffu;
    return f32x2{__uint_as_float(a), __uint_as_float(b)};
}

// ---------------- CSR construction (grouped by dst) ----------------

__global__ void k_scan1(const int* __restrict__ cnt, int* __restrict__ bsum) {
    __shared__ int sh[256];
    int i = blockIdx.x * 256 + threadIdx.x;
    sh[threadIdx.x] = (i < NN) ? (cnt[i] + 1) : 0;
    __syncthreads();
    for (int o = 128; o >= 1; o >>= 1) {
        if ((int)threadIdx.x < o) sh[threadIdx.x] += sh[threadIdx.x + o];
        __syncthreads();
    }
    if (threadIdx.x == 0) bsum[blockIdx.x] = sh[0];
}

__global__ void k_scan3(const int* __restrict__ cnt, const int* __restrict__ bsum,
                        int* __restrict__ row_ptr, int* __restrict__ col_src,
                        int* __restrict__ cur) {
    __shared__ int sh[256];
    __shared__ int sb[128];
    int tid = threadIdx.x;
    if (tid < 128) sb[tid] = (tid < 98) ? bsum[tid] : 0;
    __syncthreads();
    for (int o = 1; o < 128; o <<= 1) {
        int t = (tid >= o && tid < 128) ? sb[tid - o] : 0;
        __syncthreads();
        if (tid < 128) sb[tid] += t;
        __syncthreads();
    }
    int i = blockIdx.x * 256 + tid;
    int v = (i < NN) ? (cnt[i] + 1) : 0;
    sh[tid] = v;
    __syncthreads();
    for (int o = 1; o < 256; o <<= 1) {
        int t = (tid >= o) ? sh[tid - o] : 0;
        __syncthreads();
        sh[tid] += t;
        __syncthreads();
    }
    int base = blockIdx.x ? sb[blockIdx.x - 1] : 0;
    if (i < NN) {
        int incl = base + sh[tid];
        row_ptr[i + 1] = incl;
        int p = incl - v;
        col_src[p] = i;            // self loop first
        cur[i] = p + 1;
    }
    if (i == 0) row_ptr[0] = 0;
}

__global__ void k_fill_edges(const int* __restrict__ src, const int* __restrict__ dst,
                             int* __restrict__ cur, int* __restrict__ col_src) {
    int e = blockIdx.x * 256 + threadIdx.x;
    if (e < NE) { int p = atomicAdd(&cur[dst[e]], 1); col_src[p] = src[e]; }
}

// ---------------- one cast/init kernel (also the edge-count pass) ----------------
__global__ void k_cast_all(const float* __restrict__ x,
                           const float* __restrict__ Wl1, const float* __restrict__ Wr1,
                           const float* __restrict__ W1,
                           const float* __restrict__ Wl2, const float* __restrict__ Wr2,
                           const float* __restrict__ W2,
                           const float* __restrict__ bl1, const float* __restrict__ br1,
                           const float* __restrict__ bl2, const float* __restrict__ br2,
                           const float* __restrict__ att1, const float* __restrict__ att2,
                           const int* __restrict__ edst,
                           u16* __restrict__ xb, u16* __restrict__ WfT1,
                           u16* __restrict__ W1T, u16* __restrict__ WfT2,
                           u16* __restrict__ W2T,
                           float* __restrict__ fb1, float* __restrict__ fb2,
                           float* __restrict__ attc1, float* __restrict__ attc2,
                           int* __restrict__ cnt, float* __restrict__ stats) {
    int i = blockIdx.x * 256 + threadIdx.x;
    if (i < 400000) {   // x cast, 8 elems/thread, coalesced 16B writes
        const float4* xp = (const float4*)(x + (size_t)i * 8);
        float4 a = xp[0], b = xp[1];
        uint4 w;
        w.x = bf16_1(a.x) | (bf16_1(a.y) << 16);
        w.y = bf16_1(a.z) | (bf16_1(a.w) << 16);
        w.z = bf16_1(b.x) | (bf16_1(b.y) << 16);
        w.w = bf16_1(b.z) | (bf16_1(b.w) << 16);
        *(uint4*)(xb + (size_t)i * 8) = w;
        return;
    }
    i -= 400000;
    if (i < 400000) { atomicAdd(&cnt[edst[i]], 1); return; }   // edge count
    i -= 400000;
    if (i < 49152) { int k = i / 384, n = i - k * 384; WfT1[n * 128 + k] = (u16)bf16_1(Wl1[i]); return; }
    i -= 49152;
    if (i < 49152) { int k = i / 384, n = i - k * 384; WfT1[(384 + n) * 128 + k] = (u16)bf16_1(Wr1[i]); return; }
    i -= 49152;
    if (i < 49152) { int k = i / 128, n = i - k * 128; W1T[n * 384 + k] = (u16)bf16_1(W1[i]); return; }
    i -= 49152;
    if (i < 49152) { int k = i / 384, n = i - k * 384; WfT2[n * 128 + k] = (u16)bf16_1(Wl2[i]); return; }
    i -= 49152;
    if (i < 49152) { int k = i / 384, n = i - k * 384; WfT2[(384 + n) * 128 + k] = (u16)bf16_1(Wr2[i]); return; }
    i -= 49152;
    if (i < 98304) { int k = i / 128, n = i - k * 128; W2T[n * 768 + k] = (u16)bf16_1(W2[i]); return; }
    i -= 98304;
    if (i < 768) { fb1[i] = (i < 384) ? bl1[i] : br1[i - 384]; return; }
    i -= 768;
    if (i < 768) { fb2[i] = (i < 384) ? bl2[i] : br2[i - 384]; return; }
    i -= 768;
    // pre-scaled attention vectors: 0.6 * log2(e) * att
    if (i < 384) { attc1[i] = att1[i] * 0.86561702f; return; }
    i -= 384;
    if (i < 384) { attc2[i] = att2[i] * 0.86561702f; return; }
    i -= 384;
    if (i < 512) stats[i] = 0.f;
}
#define CAST_TOTAL (400000 + 400000 + 5 * 49152 + 98304 + 1536 + 768 + 512)

// ---------------- K=128 single-shot GEMM (the xl|xr transforms) ----------------
__global__ __launch_bounds__(256) void k_gemm_k128(
        const u16* __restrict__ A, const u16* __restrict__ BT,
        const float* __restrict__ bias, u16* __restrict__ Cb, int M) {
    __shared__ short sA[128 * 128];
    __shared__ short sB[128 * 128];
    int tid = threadIdx.x;
    int wv = tid >> 6, lane = tid & 63;
    int quad = lane >> 4, m16 = lane & 15;
    int mb = blockIdx.y * 128, nb = blockIdx.x * 128;

#pragma unroll
    for (int j = 0; j < 8; ++j) {
        int L = j * 256 + tid;
        int r = L >> 4, c8 = (L & 15) ^ (r & 15);
        int gr = mb + r; gr = gr < M ? gr : M - 1;
        __builtin_amdgcn_global_load_lds(
            (const __attribute__((address_space(1))) void*)(A + (size_t)gr * 128 + c8 * 8),
            (__attribute__((address_space(3))) void*)(sA + (size_t)L * 8), 16, 0, 0);
    }
#pragma unroll
    for (int j = 0; j < 8; ++j) {
        int L = j * 256 + tid;
        int r = L >> 4, c8 = (L & 15) ^ (r & 15);
        __builtin_amdgcn_global_load_lds(
            (const __attribute__((address_space(1))) void*)(BT + (size_t)(nb + r) * 128 + c8 * 8),
            (__attribute__((address_space(3))) void*)(sB + (size_t)L * 8), 16, 0, 0);
    }
    __syncthreads();

    floatx4 acc[2][8];
#pragma unroll
    for (int mf = 0; mf < 2; ++mf)
#pragma unroll
        for (int nf = 0; nf < 8; ++nf)
#pragma unroll
            for (int r = 0; r < 4; ++r) acc[mf][nf][r] = 0.f;

#pragma unroll
    for (int ks = 0; ks < 4; ++ks) {
        int slot = (ks * 4 + quad) ^ m16;
        int row0 = wv * 32 + m16, row1 = row0 + 16;
        short8 a0 = *(const short8*)(sA + ((size_t)row0 * 16 + slot) * 8);
        short8 a1 = *(const short8*)(sA + ((size_t)row1 * 16 + slot) * 8);
#pragma unroll
        for (int nf = 0; nf < 8; ++nf) {
            short8 b = *(const short8*)(sB + ((size_t)(nf * 16 + m16) * 16 + slot) * 8);
            acc[0][nf] = __builtin_amdgcn_mfma_f32_16x16x32_bf16(a0, b, acc[0][nf], 0, 0, 0);
            acc[1][nf] = __builtin_amdgcn_mfma_f32_16x16x32_bf16(a1, b, acc[1][nf], 0, 0, 0);
        }
    }
    __syncthreads();

#pragma unroll
    for (int mf = 0; mf < 2; ++mf)
#pragma unroll
        for (int nf = 0; nf < 8; ++nf)
#pragma unroll
            for (int r = 0; r < 4; ++r) {
                int row = wv * 32 + mf * 16 + quad * 4 + r;
                int col = nf * 16 + m16;
                sA[row * 128 + col] = (short)bf16_1(acc[mf][nf][r] + bias[nb + col]);
            }
    __syncthreads();
    int xr = nb >= 384;
    int h = (xr ? (nb - 384) : nb) >> 7;
    u16* cb = Cb + ((size_t)(xr * 3 + h) * NN) * 128;
#pragma unroll
    for (int i = 0; i < 8; ++i) {
        int u = i * 256 + tid;
        int row = u >> 4, c8 = u & 15;
        int grow = mb + row;
        if (grow < M)
            *(uint4*)(cb + (size_t)grow * 128 + c8 * 8) = *(const uint4*)(sA + (size_t)u * 8);
    }
}

// ---------------- bf16 MFMA GEMM (K-loop): C[M,N] = A[M,K] @ BT[N,K]^T ----------------
__global__ __launch_bounds__(256) void k_gemm_bf(
        const u16* __restrict__ A, const u16* __restrict__ BT,
        const float* __restrict__ bias,
        float* __restrict__ Cf, float* __restrict__ stats,
        int M, int N, int K, int lda) {
    __shared__ short smem[9216];    // 18 KB: 16K staging/tile + 2K stat partials
    short* sA = smem;               // 64*64
    short* sB = smem + 4096;        // 64*64
    int tid = threadIdx.x;
    int wv = tid >> 6, lane = tid & 63;
    int quad = lane >> 4, m16 = lane & 15;
    int sw = m16 & 7;
    int mb = blockIdx.y * 64, nb = blockIdx.x * 64;

    floatx4 acc[4];
#pragma unroll
    for (int nf = 0; nf < 4; ++nf)
#pragma unroll
        for (int r = 0; r < 4; ++r) acc[nf][r] = 0.f;

    for (int k0 = 0; k0 < K; k0 += 64) {
#pragma unroll
        for (int j = 0; j < 2; ++j) {
            int L = j * 256 + tid;
            int r = L >> 3, c8 = (L & 7) ^ (r & 7);
            int gr = mb + r; gr = gr < M ? gr : M - 1;
            __builtin_amdgcn_global_load_lds(
                (const __attribute__((address_space(1))) void*)(A + (size_t)gr * lda + k0 + c8 * 8),
                (__attribute__((address_space(3))) void*)(sA + (size_t)L * 8), 16, 0, 0);
        }
#pragma unroll
        for (int j = 0; j < 2; ++j) {
            int L = j * 256 + tid;
            int r = L >> 3, c8 = (L & 7) ^ (r & 7);
            __builtin_amdgcn_global_load_lds(
                (const __attribute__((address_space(1))) void*)(BT + (size_t)(nb + r) * K + k0 + c8 * 8),
                (__attribute__((address_space(3))) void*)(sB + (size_t)L * 8), 16, 0, 0);
        }
        __syncthreads();
#pragma unroll
        for (int ks = 0; ks < 2; ++ks) {
            int t = (ks * 4 + quad) ^ sw;
            const short* pa = sA + t * 8;
            const short* pb = sB + t * 8;
            short8 a0 = *(const short8*)(pa + (wv * 16 + m16) * 64);
#pragma unroll
            for (int nf = 0; nf < 4; ++nf) {
                short8 b = *(const short8*)(pb + (nf * 16 + m16) * 64);
                acc[nf] = __builtin_amdgcn_mfma_f32_16x16x32_bf16(a0, b, acc[nf], 0, 0, 0);
            }
        }
        __syncthreads();
    }
    float* fs = (float*)smem;
#pragma unroll
    for (int nf = 0; nf < 4; ++nf)
#pragma unroll
        for (int r = 0; r < 4; ++r) {
            int row = wv * 16 + quad * 4 + r;
            int col = nf * 16 + m16;
            fs[row * 64 + col] = acc[nf][r] + (bias ? bias[nb + col] : 0.f);
        }
    __syncthreads();
#pragma unroll
    for (int i = 0; i < 4; ++i) {
        int u = i * 256 + tid;
        int row = u >> 4, c4 = u & 15;
        int grow = mb + row;
        if (grow < M)
            *(float4*)(Cf + (size_t)grow * N + nb + c4 * 4) = *(const float4*)(fs + (size_t)u * 4);
    }
    if (stats) {
        float* ps = (float*)(smem + 8192);   // [2][4][64]
        int col = tid & 63, qr = tid >> 6;
        int vr = M - mb; vr = vr < 64 ? vr : 64;
        int r0 = qr * 16, r1 = r0 + 16 < vr ? r0 + 16 : vr;
        float s = 0.f, q = 0.f;
        for (int r = r0; r < r1; ++r) { float v = fs[r * 64 + col]; s += v; q += v * v; }
        ps[qr * 64 + col] = s;
        ps[256 + qr * 64 + col] = q;
        __syncthreads();
        if (tid < 64) {
            float ss = ps[tid] + ps[64 + tid] + ps[128 + tid] + ps[192 + tid];
            atomicAdd(&stats[nb + tid], ss);
        } else if (tid < 128) {
            int c = tid - 64;
            float qq = ps[256 + c] + ps[320 + c] + ps[384 + c] + ps[448 + c];
            atomicAdd(&stats[128 + nb + c], qq);
        }
    }
}

// ---------------- GATv2 aggregate, per-head blocks (R1 memory structure), ----------------
// packed-f32 inner math: att·leaky(v) = (0.6·log2e·att)·(v + 2/3·|v|), w = exp2(p).
__global__ __launch_bounds__(256) void k_gat_h(const u32* __restrict__ XLb,
                                               const u32* __restrict__ XRb,
                                               const float* __restrict__ attc,
                                               const float* __restrict__ bias,
                                               const int* __restrict__ row_ptr,
                                               const int* __restrict__ col_src,
                                               u32* __restrict__ outb) {
    int h = blockIdx.y;
    const u32* XLh = XLb + (size_t)h * NN * 64;
    const u32* XRh = XRb + (size_t)h * NN * 64;
    int node = blockIdx.x * 4 + (threadIdx.x >> 6);
    int lane = threadIdx.x & 63;
    int g = lane >> 4, gl = lane & 15;

    f32x2 xr2[4], a6[4], acc2[4];
    const f32x2 c23 = {0.66666667f, 0.66666667f};
    up8f2(*(const uint4*)(XRh + (size_t)node * 64 + 4 * gl), xr2);
#pragma unroll
    for (int j = 0; j < 4; ++j) {
        a6[j] = *(const f32x2*)(attc + h * 128 + 8 * gl + 2 * j);
        acc2[j] = f32x2{0.f, 0.f};
    }
    float l = 0.f;

    int e0 = row_ptr[node];
    int cntE = row_ptr[node + 1] - e0;
    int elast = e0 + cntE - 1;

    int ea = e0 + g;     ea = ea < elast ? ea : elast;
    int eb = e0 + g + 4; eb = eb < elast ? eb : elast;
    uint4 ua = *(const uint4*)(XLh + (size_t)col_src[ea] * 64 + 4 * gl);
    uint4 ub = *(const uint4*)(XLh + (size_t)col_src[eb] * 64 + 4 * gl);

    for (int t = g; t < cntE; t += 8) {
        int e2 = e0 + t + 8;  e2 = e2 < elast ? e2 : elast;
        int e3 = e0 + t + 12; e3 = e3 < elast ? e3 : elast;
        uint4 un0 = *(const uint4*)(XLh + (size_t)col_src[e2] * 64 + 4 * gl);
        uint4 un1 = *(const uint4*)(XLh + (size_t)col_src[e3] * 64 + 4 * gl);

        f32x2 xa2[4], xb2[4];
        up8f2(ua, xa2); up8f2(ub, xb2);
        f32x2 pa2 = {0.f, 0.f}, pb2 = {0.f, 0.f};
#pragma unroll
        for (int j = 0; j < 4; ++j) {
            f32x2 va = pk_add(xa2[j], xr2[j]);
            f32x2 vb = pk_add(xb2[j], xr2[j]);
            pa2 = pk_fma(pk_fma(fabs2(va), c23, va), a6[j], pa2);
            pb2 = pk_fma(pk_fma(fabs2(vb), c23, vb), a6[j], pb2);
        }
        float pa = pa2.x + pa2.y, pb = pb2.x + pb2.y;
#pragma unroll
        for (int o = 1; o <= 8; o <<= 1) {
            pa += __shfl_xor(pa, o);
            pb += __shfl_xor(pb, o);
        }
        float wa = __builtin_amdgcn_exp2f(pa);
        float wb = ((t + 4) < cntE) ? __builtin_amdgcn_exp2f(pb) : 0.f;
        l += wa + wb;
        f32x2 wa2 = {wa, wa}, wb2 = {wb, wb};
#pragma unroll
        for (int j = 0; j < 4; ++j)
            acc2[j] = pk_fma(xa2[j], wa2, pk_fma(xb2[j], wb2, acc2[j]));

        ua = un0; ub = un1;
    }

#pragma unroll
    for (int o = 16; o <= 32; o <<= 1) {
        l += __shfl_xor(l, o);
#pragma unroll
        for (int j = 0; j < 4; ++j) {
            f32x2 s;
            s.x = __shfl_xor(acc2[j].x, o);
            s.y = __shfl_xor(acc2[j].y, o);
            acc2[j] = pk_add(acc2[j], s);
        }
    }

    if (g == 0) {
        float r = 1.f / l;
        float bv[8];
        *(float4*)&bv[0] = *(const float4*)&bias[h * 128 + 8 * gl];
        *(float4*)&bv[4] = *(const float4*)&bias[h * 128 + 8 * gl + 4];
        uint4 w;
        w.x = bf16_1(fmaf(acc2[0].x, r, bv[0])) | (bf16_1(fmaf(acc2[0].y, r, bv[1])) << 16);
        w.y = bf16_1(fmaf(acc2[1].x, r, bv[2])) | (bf16_1(fmaf(acc2[1].y, r, bv[3])) << 16);
        w.z = bf16_1(fmaf(acc2[2].x, r, bv[4])) | (bf16_1(fmaf(acc2[2].y, r, bv[5])) << 16);
        w.w = bf16_1(fmaf(acc2[3].x, r, bv[6])) | (bf16_1(fmaf(acc2[3].y, r, bv[7])) << 16);
        *(uint4*)(outb + (size_t)node * 384 + h * 64 + 4 * gl) = w;
    }
}

// ---------------- BN apply (stats pre-accumulated in the GEMM) ----------------
__global__ void k_bn_apply(float* __restrict__ y, const float* __restrict__ stats,
                           const float* __restrict__ g, const float* __restrict__ be,
                           u16* __restrict__ yb, int wf) {
    int i = blockIdx.x * 256 + threadIdx.x;
    if (i >= NN * DD / 8) return;
    int idx = i * 8;
    int c0 = idx & 127;
    float v[8];
    *(float4*)&v[0] = *(const float4*)(y + idx);
    *(float4*)&v[4] = *(const float4*)(y + idx + 4);
    const float minv = 1.f / (float)NN;
#pragma unroll
    for (int k = 0; k < 8; ++k) {
        int c = c0 + k;
        float mu = stats[c] * minv;
        float var = stats[128 + c] * minv - mu * mu;
        float sc = g[c] * rsqrtf(var + EPS);
        float sh = be[c] - mu * sc;
        v[k] = fmaxf(fmaf(v[k], sc, sh), 0.f);
    }
    if (wf) {
        *(float4*)(y + idx) = *(const float4*)&v[0];
        *(float4*)(y + idx + 4) = *(const float4*)&v[4];
    }
    if (yb) {
        uint4 w;
        w.x = bf16_1(v[0]) | (bf16_1(v[1]) << 16);
        w.y = bf16_1(v[2]) | (bf16_1(v[3]) << 16);
        w.z = bf16_1(v[4]) | (bf16_1(v[5]) << 16);
        w.w = bf16_1(v[6]) | (bf16_1(v[7]) << 16);
        *(uint4*)(yb + idx) = w;
    }
}

// ---------------- launch ----------------

extern "C" void kernel_launch(void* const* d_in, const int* in_sizes, int n_in,
                              void* d_out, int out_size, void* d_ws, size_t ws_size,
                              hipStream_t stream) {
    const float* x    = (const float*)d_in[0];
    const int*   ei   = (const int*)d_in[1];
    const float* Wl1  = (const float*)d_in[2];
    const float* bl1  = (const float*)d_in[3];
    const float* Wr1  = (const float*)d_in[4];
    const float* br1  = (const float*)d_in[5];
    const float* att1 = (const float*)d_in[6];
    const float* bc1  = (const float*)d_in[7];
    const float* g1   = (const float*)d_in[8];
    const float* be1  = (const float*)d_in[9];
    const float* Wl2  = (const float*)d_in[10];
    const float* bl2  = (const float*)d_in[11];
    const float* Wr2  = (const float*)d_in[12];
    const float* br2  = (const float*)d_in[13];
    const float* att2 = (const float*)d_in[14];
    const float* bc2  = (const float*)d_in[15];
    const float* g2   = (const float*)d_in[16];
    const float* be2  = (const float*)d_in[17];
    const float* W1   = (const float*)d_in[18];
    const float* b1   = (const float*)d_in[19];
    const float* W2   = (const float*)d_in[20];
    const float* b2   = (const float*)d_in[21];
    const int* esrc = ei;
    const int* edst = ei + NE;
    float* out = (float*)d_out;

    // ---- workspace layout ----
    float* bufD   = (float*)d_ws;          // mid fp32 [NN,128]      12.8 MB
    float* stats  = bufD + 3200000;        // 512 f (BN1 +0, BN2 +256)
    int* row_ptr  = (int*)(stats + 512);   // 25002
    int* cnt      = row_ptr + 25002;       // 25000
    int* col_src  = cnt + 25000;           // 425000
    int* bsum     = col_src + 425000;      // 132 (pad)
    float* fb1    = (float*)(bsum + 132);  // 768 fused bias L1
    float* fb2    = fb1 + 768;             // 768 fused bias L2
    float* attc1  = fb2 + 768;             // 384 pre-scaled att L1
    float* attc2  = attc1 + 384;           // 384 pre-scaled att L2
    u16* xb       = (u16*)(attc2 + 384);   // x bf16 [NN,128]         6.4 MB
    u16* XLb      = xb + 3200000;          // head-major xl [3][NN][128]  19.2 MB
    u16* XRb      = XLb + 3 * NN * 128;    // head-major xr [3][NN][128]
    u16* bufCat   = XRb + 3 * NN * 128;    // [NN,768] h2|x_in bf16  38.4 MB
    u16* bufDb    = bufCat + 19200000;     // h bf16 [NN,128]         6.4 MB
    u16* WfT1     = bufDb + 3200000;       // [768][128]
    u16* W1T      = WfT1 + 98304;          // [128][384]
    u16* WfT2     = W1T + 49152;           // [768][128]
    u16* W2T      = WfT2 + 98304;          // [128][768]

    // zero cnt, then casts + transposes + biases + att prescale + edge-count + stats zero
    hipMemsetAsync(cnt, 0, NN * sizeof(int), stream);
    k_cast_all<<<(CAST_TOTAL + 255) / 256, 256, 0, stream>>>(
        x, Wl1, Wr1, W1, Wl2, Wr2, W2, bl1, br1, bl2, br2, att1, att2, edst,
        xb, WfT1, W1T, WfT2, W2T, fb1, fb2, attc1, attc2, cnt, stats);

    // CSR scans (scan2 folded into scan3)
    k_scan1<<<98, 256, 0, stream>>>(cnt, bsum);
    k_scan3<<<98, 256, 0, stream>>>(cnt, bsum, row_ptr, col_src, cnt);
    k_fill_edges<<<(NE + 255) / 256, 256, 0, stream>>>(esrc, edst, cnt, col_src);

    dim3 blk(256);
    dim3 gK(6, (NN + 127) / 128);        // K=128 GEMM
    dim3 g64(2, (NN + 63) / 64);         // BM=64 GEMMs: 782 blocks
    dim3 gGat((NN + 3) / 4, 3);          // gat: per-head blocks (L2 tiling)

    // layer 1
    k_gemm_k128<<<gK, blk, 0, stream>>>(xb, WfT1, fb1, XLb, NN);
    k_gat_h<<<gGat, blk, 0, stream>>>((const u32*)XLb, (const u32*)XRb, attc1, bc1,
                                      row_ptr, col_src, (u32*)bufCat + 192);

    // mid MLP (+BN stats folded) + BN apply
    k_gemm_bf<<<g64, blk, 0, stream>>>(bufCat + 384, W1T, b1, bufD, stats, NN, DD, HD, 768);
    k_bn_apply<<<(NN * DD / 8 + 255) / 256, 256, 0, stream>>>(bufD, stats, g1, be1, bufDb, 0);

    // layer 2
    k_gemm_k128<<<gK, blk, 0, stream>>>(bufDb, WfT2, fb2, XLb, NN);
    k_gat_h<<<gGat, blk, 0, stream>>>((const u32*)XLb, (const u32*)XRb, attc2, bc2,
                                      row_ptr, col_src, (u32*)bufCat);

    // final GEMM (+BN stats folded) + BN apply
    k_gemm_bf<<<g64, blk, 0, stream>>>(bufCat, W2T, b2, out, stats + 256, NN, DD, 768, 768);
    k_bn_apply<<<(NN * DD / 8 + 255) / 256, 256, 0, stream>>>(out, stats + 256, g2, be2, nullptr, 1);
}

// Round 4
// 374.942 us; speedup vs baseline: 1.1108x; 1.0218x over previous
//
#include <hip/hip_runtime.h>
#include <math.h>

#define NN 25000      // nodes
#define NE 400000     // edges
#define DD 128        // hidden dim
#define HD 384        // heads * dim
#define NEG 0.2f
#define EPS 1e-5f

typedef unsigned int u32;
typedef unsigned short u16;
typedef __attribute__((ext_vector_type(8))) short short8;   // 8 bf16 (4 VGPRs)
typedef __attribute__((ext_vector_type(4))) float floatx4;  // MFMA accumulator
typedef __attribute__((ext_vector_type(2))) float f32x2;    // packed-f32 pair

// ---- bf16 helpers (RNE) ----
__device__ __forceinline__ u32 bf16_1(float x) {
    u32 u = __float_as_uint(x);
    return (u + 0x7fffu + ((u >> 16) & 1u)) >> 16;
}
__device__ __forceinline__ float blo(u32 u) { return __uint_as_float(u << 16); }
__device__ __forceinline__ float bhi(u32 u) { return __uint_as_float(u & 0xffff0000u); }

__device__ __forceinline__ void up8f2(uint4 u, f32x2* f) {
    f[0] = f32x2{blo(u.x), bhi(u.x)};
    f[1] = f32x2{blo(u.y), bhi(u.y)};
    f[2] = f32x2{blo(u.z), bhi(u.z)};
    f[3] = f32x2{blo(u.w), bhi(u.w)};
}

// ---- packed f32 ops (CDNA v_pk_*, 2 f32 lanes / inst) ----
__device__ __forceinline__ f32x2 pk_add(f32x2 a, f32x2 b) {
    f32x2 d; asm("v_pk_add_f32 %0, %1, %2" : "=v"(d) : "v"(a), "v"(b)); return d;
}
__device__ __forceinline__ f32x2 pk_fma(f32x2 a, f32x2 b, f32x2 c) {
    f32x2 d; asm("v_pk_fma_f32 %0, %1, %2, %3" : "=v"(d) : "v"(a), "v"(b), "v"(c)); return d;
}
__device__ __forceinline__ f32x2 fabs2(f32x2 v) {
    u32 a = __float_as_uint(v.x) & 0x7fffffffu;
    u32 b = __float_as_uint(v.y) & 0x7fffffffu;
    return f32x2{__uint_as_float(a), __uint_as_float(b)};
}

// ---- 16-lane (DPP row) rotate-reduce: every lane gets the row total ----
// row_ror:n = dpp_ctrl 0x120+n. Strides 1,2,4,8 -> full sum. Single-inst steps,
// no ds_bpermute, no lgkmcnt. Safe under divergence: inactive lanes are whole
// 16-lane rows here, and row-DPP never crosses a row.
__device__ __forceinline__ float row_sum16(float x) {
    int t;
    t = __builtin_amdgcn_update_dpp(0, __float_as_int(x), 0x121, 0xf, 0xf, false);
    x += __int_as_float(t);
    t = __builtin_amdgcn_update_dpp(0, __float_as_int(x), 0x122, 0xf, 0xf, false);
    x += __int_as_float(t);
    t = __builtin_amdgcn_update_dpp(0, __float_as_int(x), 0x124, 0xf, 0xf, false);
    x += __int_as_float(t);
    t = __builtin_amdgcn_update_dpp(0, __float_as_int(x), 0x128, 0xf, 0xf, false);
    x += __int_as_float(t);
    return x;
}

// ---------------- CSR construction (grouped by dst) ----------------

__global__ void k_scan1(const int* __restrict__ cnt, int* __restrict__ bsum) {
    __shared__ int sh[256];
    int i = blockIdx.x * 256 + threadIdx.x;
    sh[threadIdx.x] = (i < NN) ? (cnt[i] + 1) : 0;
    __syncthreads();
    for (int o = 128; o >= 1; o >>= 1) {
        if ((int)threadIdx.x < o) sh[threadIdx.x] += sh[threadIdx.x + o];
        __syncthreads();
    }
    if (threadIdx.x == 0) bsum[blockIdx.x] = sh[0];
}

__global__ void k_scan3(const int* __restrict__ cnt, const int* __restrict__ bsum,
                        int* __restrict__ row_ptr, int* __restrict__ col_src,
                        int* __restrict__ cur) {
    __shared__ int sh[256];
    __shared__ int sb[128];
    int tid = threadIdx.x;
    if (tid < 128) sb[tid] = (tid < 98) ? bsum[tid] : 0;
    __syncthreads();
    for (int o = 1; o < 128; o <<= 1) {
        int t = (tid >= o && tid < 128) ? sb[tid - o] : 0;
        __syncthreads();
        if (tid < 128) sb[tid] += t;
        __syncthreads();
    }
    int i = blockIdx.x * 256 + tid;
    int v = (i < NN) ? (cnt[i] + 1) : 0;
    sh[tid] = v;
    __syncthreads();
    for (int o = 1; o < 256; o <<= 1) {
        int t = (tid >= o) ? sh[tid - o] : 0;
        __syncthreads();
        sh[tid] += t;
        __syncthreads();
    }
    int base = blockIdx.x ? sb[blockIdx.x - 1] : 0;
    if (i < NN) {
        int incl = base + sh[tid];
        row_ptr[i + 1] = incl;
        int p = incl - v;
        col_src[p] = i;            // self loop first
        cur[i] = p + 1;
    }
    if (i == 0) row_ptr[0] = 0;
}

__global__ void k_fill_edges(const int* __restrict__ src, const int* __restrict__ dst,
                             int* __restrict__ cur, int* __restrict__ col_src) {
    int e = blockIdx.x * 256 + threadIdx.x;
    if (e < 24) col_src[NE + NN + e] = 0;   // zero tail pad (unclamped prefetch)
    if (e < NE) { int p = atomicAdd(&cur[dst[e]], 1); col_src[p] = src[e]; }
}

// ---------------- one cast/init kernel (also the edge-count pass) ----------------
__global__ void k_cast_all(const float* __restrict__ x,
                           const float* __restrict__ Wl1, const float* __restrict__ Wr1,
                           const float* __restrict__ W1,
                           const float* __restrict__ Wl2, const float* __restrict__ Wr2,
                           const float* __restrict__ W2,
                           const float* __restrict__ bl1, const float* __restrict__ br1,
                           const float* __restrict__ bl2, const float* __restrict__ br2,
                           const float* __restrict__ att1, const float* __restrict__ att2,
                           const int* __restrict__ edst,
                           u16* __restrict__ xb, u16* __restrict__ WfT1,
                           u16* __restrict__ W1T, u16* __restrict__ WfT2,
                           u16* __restrict__ W2T,
                           float* __restrict__ fb1, float* __restrict__ fb2,
                           float* __restrict__ attc1, float* __restrict__ attc2,
                           int* __restrict__ cnt, float* __restrict__ stats) {
    int i = blockIdx.x * 256 + threadIdx.x;
    if (i < 400000) {   // x cast, 8 elems/thread, coalesced 16B writes
        const float4* xp = (const float4*)(x + (size_t)i * 8);
        float4 a = xp[0], b = xp[1];
        uint4 w;
        w.x = bf16_1(a.x) | (bf16_1(a.y) << 16);
        w.y = bf16_1(a.z) | (bf16_1(a.w) << 16);
        w.z = bf16_1(b.x) | (bf16_1(b.y) << 16);
        w.w = bf16_1(b.z) | (bf16_1(b.w) << 16);
        *(uint4*)(xb + (size_t)i * 8) = w;
        return;
    }
    i -= 400000;
    if (i < 400000) { atomicAdd(&cnt[edst[i]], 1); return; }   // edge count
    i -= 400000;
    if (i < 49152) { int k = i / 384, n = i - k * 384; WfT1[n * 128 + k] = (u16)bf16_1(Wl1[i]); return; }
    i -= 49152;
    if (i < 49152) { int k = i / 384, n = i - k * 384; WfT1[(384 + n) * 128 + k] = (u16)bf16_1(Wr1[i]); return; }
    i -= 49152;
    if (i < 49152) { int k = i / 128, n = i - k * 128; W1T[n * 384 + k] = (u16)bf16_1(W1[i]); return; }
    i -= 49152;
    if (i < 49152) { int k = i / 384, n = i - k * 384; WfT2[n * 128 + k] = (u16)bf16_1(Wl2[i]); return; }
    i -= 49152;
    if (i < 49152) { int k = i / 384, n = i - k * 384; WfT2[(384 + n) * 128 + k] = (u16)bf16_1(Wr2[i]); return; }
    i -= 49152;
    if (i < 98304) { int k = i / 128, n = i - k * 128; W2T[n * 768 + k] = (u16)bf16_1(W2[i]); return; }
    i -= 98304;
    if (i < 768) { fb1[i] = (i < 384) ? bl1[i] : br1[i - 384]; return; }
    i -= 768;
    if (i < 768) { fb2[i] = (i < 384) ? bl2[i] : br2[i - 384]; return; }
    i -= 768;
    // pre-scaled attention vectors: 0.6 * log2(e) * att
    if (i < 384) { attc1[i] = att1[i] * 0.86561702f; return; }
    i -= 384;
    if (i < 384) { attc2[i] = att2[i] * 0.86561702f; return; }
    i -= 384;
    if (i < 512) stats[i] = 0.f;
}
#define CAST_TOTAL (400000 + 400000 + 5 * 49152 + 98304 + 1536 + 768 + 512)

// ---------------- K=128 single-shot GEMM (the xl|xr transforms) ----------------
__global__ __launch_bounds__(256) void k_gemm_k128(
        const u16* __restrict__ A, const u16* __restrict__ BT,
        const float* __restrict__ bias, u16* __restrict__ Cb, int M) {
    __shared__ short sA[128 * 128];
    __shared__ short sB[128 * 128];
    int tid = threadIdx.x;
    int wv = tid >> 6, lane = tid & 63;
    int quad = lane >> 4, m16 = lane & 15;
    int mb = blockIdx.y * 128, nb = blockIdx.x * 128;

#pragma unroll
    for (int j = 0; j < 8; ++j) {
        int L = j * 256 + tid;
        int r = L >> 4, c8 = (L & 15) ^ (r & 15);
        int gr = mb + r; gr = gr < M ? gr : M - 1;
        __builtin_amdgcn_global_load_lds(
            (const __attribute__((address_space(1))) void*)(A + (size_t)gr * 128 + c8 * 8),
            (__attribute__((address_space(3))) void*)(sA + (size_t)L * 8), 16, 0, 0);
    }
#pragma unroll
    for (int j = 0; j < 8; ++j) {
        int L = j * 256 + tid;
        int r = L >> 4, c8 = (L & 15) ^ (r & 15);
        __builtin_amdgcn_global_load_lds(
            (const __attribute__((address_space(1))) void*)(BT + (size_t)(nb + r) * 128 + c8 * 8),
            (__attribute__((address_space(3))) void*)(sB + (size_t)L * 8), 16, 0, 0);
    }
    __syncthreads();

    floatx4 acc[2][8];
#pragma unroll
    for (int mf = 0; mf < 2; ++mf)
#pragma unroll
        for (int nf = 0; nf < 8; ++nf)
#pragma unroll
            for (int r = 0; r < 4; ++r) acc[mf][nf][r] = 0.f;

#pragma unroll
    for (int ks = 0; ks < 4; ++ks) {
        int slot = (ks * 4 + quad) ^ m16;
        int row0 = wv * 32 + m16, row1 = row0 + 16;
        short8 a0 = *(const short8*)(sA + ((size_t)row0 * 16 + slot) * 8);
        short8 a1 = *(const short8*)(sA + ((size_t)row1 * 16 + slot) * 8);
#pragma unroll
        for (int nf = 0; nf < 8; ++nf) {
            short8 b = *(const short8*)(sB + ((size_t)(nf * 16 + m16) * 16 + slot) * 8);
            acc[0][nf] = __builtin_amdgcn_mfma_f32_16x16x32_bf16(a0, b, acc[0][nf], 0, 0, 0);
            acc[1][nf] = __builtin_amdgcn_mfma_f32_16x16x32_bf16(a1, b, acc[1][nf], 0, 0, 0);
        }
    }
    __syncthreads();

#pragma unroll
    for (int mf = 0; mf < 2; ++mf)
#pragma unroll
        for (int nf = 0; nf < 8; ++nf)
#pragma unroll
            for (int r = 0; r < 4; ++r) {
                int row = wv * 32 + mf * 16 + quad * 4 + r;
                int col = nf * 16 + m16;
                sA[row * 128 + col] = (short)bf16_1(acc[mf][nf][r] + bias[nb + col]);
            }
    __syncthreads();
    int xr = nb >= 384;
    int h = (xr ? (nb - 384) : nb) >> 7;
    u16* cb = Cb + ((size_t)(xr * 3 + h) * NN) * 128;
#pragma unroll
    for (int i = 0; i < 8; ++i) {
        int u = i * 256 + tid;
        int row = u >> 4, c8 = u & 15;
        int grow = mb + row;
        if (grow < M)
            *(uint4*)(cb + (size_t)grow * 128 + c8 * 8) = *(const uint4*)(sA + (size_t)u * 8);
    }
}

// ---------------- bf16 MFMA GEMM (K-loop): C[M,N] = A[M,K] @ BT[N,K]^T ----------------
__global__ __launch_bounds__(256) void k_gemm_bf(
        const u16* __restrict__ A, const u16* __restrict__ BT,
        const float* __restrict__ bias,
        float* __restrict__ Cf, float* __restrict__ stats,
        int M, int N, int K, int lda) {
    __shared__ short smem[9216];    // 18 KB: 16K staging/tile + 2K stat partials
    short* sA = smem;               // 64*64
    short* sB = smem + 4096;        // 64*64
    int tid = threadIdx.x;
    int wv = tid >> 6, lane = tid & 63;
    int quad = lane >> 4, m16 = lane & 15;
    int sw = m16 & 7;
    int mb = blockIdx.y * 64, nb = blockIdx.x * 64;

    floatx4 acc[4];
#pragma unroll
    for (int nf = 0; nf < 4; ++nf)
#pragma unroll
        for (int r = 0; r < 4; ++r) acc[nf][r] = 0.f;

    for (int k0 = 0; k0 < K; k0 += 64) {
#pragma unroll
        for (int j = 0; j < 2; ++j) {
            int L = j * 256 + tid;
            int r = L >> 3, c8 = (L & 7) ^ (r & 7);
            int gr = mb + r; gr = gr < M ? gr : M - 1;
            __builtin_amdgcn_global_load_lds(
                (const __attribute__((address_space(1))) void*)(A + (size_t)gr * lda + k0 + c8 * 8),
                (__attribute__((address_space(3))) void*)(sA + (size_t)L * 8), 16, 0, 0);
        }
#pragma unroll
        for (int j = 0; j < 2; ++j) {
            int L = j * 256 + tid;
            int r = L >> 3, c8 = (L & 7) ^ (r & 7);
            __builtin_amdgcn_global_load_lds(
                (const __attribute__((address_space(1))) void*)(BT + (size_t)(nb + r) * K + k0 + c8 * 8),
                (__attribute__((address_space(3))) void*)(sB + (size_t)L * 8), 16, 0, 0);
        }
        __syncthreads();
#pragma unroll
        for (int ks = 0; ks < 2; ++ks) {
            int t = (ks * 4 + quad) ^ sw;
            const short* pa = sA + t * 8;
            const short* pb = sB + t * 8;
            short8 a0 = *(const short8*)(pa + (wv * 16 + m16) * 64);
#pragma unroll
            for (int nf = 0; nf < 4; ++nf) {
                short8 b = *(const short8*)(pb + (nf * 16 + m16) * 64);
                acc[nf] = __builtin_amdgcn_mfma_f32_16x16x32_bf16(a0, b, acc[nf], 0, 0, 0);
            }
        }
        __syncthreads();
    }
    float* fs = (float*)smem;
#pragma unroll
    for (int nf = 0; nf < 4; ++nf)
#pragma unroll
        for (int r = 0; r < 4; ++r) {
            int row = wv * 16 + quad * 4 + r;
            int col = nf * 16 + m16;
            fs[row * 64 + col] = acc[nf][r] + (bias ? bias[nb + col] : 0.f);
        }
    __syncthreads();
#pragma unroll
    for (int i = 0; i < 4; ++i) {
        int u = i * 256 + tid;
        int row = u >> 4, c4 = u & 15;
        int grow = mb + row;
        if (grow < M)
            *(float4*)(Cf + (size_t)grow * N + nb + c4 * 4) = *(const float4*)(fs + (size_t)u * 4);
    }
    if (stats) {
        float* ps = (float*)(smem + 8192);   // [2][4][64]
        int col = tid & 63, qr = tid >> 6;
        int vr = M - mb; vr = vr < 64 ? vr : 64;
        int r0 = qr * 16, r1 = r0 + 16 < vr ? r0 + 16 : vr;
        float s = 0.f, q = 0.f;
        for (int r = r0; r < r1; ++r) { float v = fs[r * 64 + col]; s += v; q += v * v; }
        ps[qr * 64 + col] = s;
        ps[256 + qr * 64 + col] = q;
        __syncthreads();
        if (tid < 64) {
            float ss = ps[tid] + ps[64 + tid] + ps[128 + tid] + ps[192 + tid];
            atomicAdd(&stats[nb + tid], ss);
        } else if (tid < 128) {
            int c = tid - 64;
            float qq = ps[256 + c] + ps[320 + c] + ps[384 + c] + ps[448 + c];
            atomicAdd(&stats[128 + nb + c], qq);
        }
    }
}

// ---------------- GATv2 aggregate, per-head blocks, packed-f32 math, ----------------
// DPP row-reduce (no bpermute), unclamped prefetch (col_src tail-padded).
__global__ __launch_bounds__(256) void k_gat_h(const u32* __restrict__ XLb,
                                               const u32* __restrict__ XRb,
                                               const float* __restrict__ attc,
                                               const float* __restrict__ bias,
                                               const int* __restrict__ row_ptr,
                                               const int* __restrict__ col_src,
                                               u32* __restrict__ outb) {
    int h = blockIdx.y;
    const u32* XLh = XLb + (size_t)h * NN * 64;
    const u32* XRh = XRb + (size_t)h * NN * 64;
    int node = blockIdx.x * 4 + (threadIdx.x >> 6);
    int lane = threadIdx.x & 63;
    int g = lane >> 4, gl = lane & 15;

    f32x2 xr2[4], a6[4], acc2[4];
    const f32x2 c23 = {0.66666667f, 0.66666667f};
    up8f2(*(const uint4*)(XRh + (size_t)node * 64 + 4 * gl), xr2);
#pragma unroll
    for (int j = 0; j < 4; ++j) {
        a6[j] = *(const f32x2*)(attc + h * 128 + 8 * gl + 2 * j);
        acc2[j] = f32x2{0.f, 0.f};
    }
    float l = 0.f;

    int e0 = row_ptr[node];
    int cntE = row_ptr[node + 1] - e0;

    uint4 ua = *(const uint4*)(XLh + (size_t)col_src[e0 + g] * 64 + 4 * gl);
    uint4 ub = *(const uint4*)(XLh + (size_t)col_src[e0 + g + 4] * 64 + 4 * gl);

    for (int t = g; t < cntE; t += 8) {
        uint4 un0 = *(const uint4*)(XLh + (size_t)col_src[e0 + t + 8] * 64 + 4 * gl);
        uint4 un1 = *(const uint4*)(XLh + (size_t)col_src[e0 + t + 12] * 64 + 4 * gl);

        f32x2 xa2[4], xb2[4];
        up8f2(ua, xa2); up8f2(ub, xb2);
        f32x2 pa2 = {0.f, 0.f}, pb2 = {0.f, 0.f};
#pragma unroll
        for (int j = 0; j < 4; ++j) {
            f32x2 va = pk_add(xa2[j], xr2[j]);
            f32x2 vb = pk_add(xb2[j], xr2[j]);
            pa2 = pk_fma(pk_fma(fabs2(va), c23, va), a6[j], pa2);
            pb2 = pk_fma(pk_fma(fabs2(vb), c23, vb), a6[j], pb2);
        }
        float pa = row_sum16(pa2.x + pa2.y);
        float pb = row_sum16(pb2.x + pb2.y);
        float wa = __builtin_amdgcn_exp2f(pa);
        float wb = ((t + 4) < cntE) ? __builtin_amdgcn_exp2f(pb) : 0.f;
        l += wa + wb;
        f32x2 wa2 = {wa, wa}, wb2 = {wb, wb};
#pragma unroll
        for (int j = 0; j < 4; ++j)
            acc2[j] = pk_fma(xa2[j], wa2, pk_fma(xb2[j], wb2, acc2[j]));

        ua = un0; ub = un1;
    }

#pragma unroll
    for (int o = 16; o <= 32; o <<= 1) {
        l += __shfl_xor(l, o);
#pragma unroll
        for (int j = 0; j < 4; ++j) {
            f32x2 s;
            s.x = __shfl_xor(acc2[j].x, o);
            s.y = __shfl_xor(acc2[j].y, o);
            acc2[j] = pk_add(acc2[j], s);
        }
    }

    if (g == 0) {
        float r = 1.f / l;
        float bv[8];
        *(float4*)&bv[0] = *(const float4*)&bias[h * 128 + 8 * gl];
        *(float4*)&bv[4] = *(const float4*)&bias[h * 128 + 8 * gl + 4];
        uint4 w;
        w.x = bf16_1(fmaf(acc2[0].x, r, bv[0])) | (bf16_1(fmaf(acc2[0].y, r, bv[1])) << 16);
        w.y = bf16_1(fmaf(acc2[1].x, r, bv[2])) | (bf16_1(fmaf(acc2[1].y, r, bv[3])) << 16);
        w.z = bf16_1(fmaf(acc2[2].x, r, bv[4])) | (bf16_1(fmaf(acc2[2].y, r, bv[5])) << 16);
        w.w = bf16_1(fmaf(acc2[3].x, r, bv[6])) | (bf16_1(fmaf(acc2[3].y, r, bv[7])) << 16);
        *(uint4*)(outb + (size_t)node * 384 + h * 64 + 4 * gl) = w;
    }
}

// ---------------- BN apply (stats pre-accumulated in the GEMM) ----------------
__global__ void k_bn_apply(float* __restrict__ y, const float* __restrict__ stats,
                           const float* __restrict__ g, const float* __restrict__ be,
                           u16* __restrict__ yb, int wf) {
    int i = blockIdx.x * 256 + threadIdx.x;
    if (i >= NN * DD / 8) return;
    int idx = i * 8;
    int c0 = idx & 127;
    float v[8];
    *(float4*)&v[0] = *(const float4*)(y + idx);
    *(float4*)&v[4] = *(const float4*)(y + idx + 4);
    const float minv = 1.f / (float)NN;
#pragma unroll
    for (int k = 0; k < 8; ++k) {
        int c = c0 + k;
        float mu = stats[c] * minv;
        float var = stats[128 + c] * minv - mu * mu;
        float sc = g[c] * rsqrtf(var + EPS);
        float sh = be[c] - mu * sc;
        v[k] = fmaxf(fmaf(v[k], sc, sh), 0.f);
    }
    if (wf) {
        *(float4*)(y + idx) = *(const float4*)&v[0];
        *(float4*)(y + idx + 4) = *(const float4*)&v[4];
    }
    if (yb) {
        uint4 w;
        w.x = bf16_1(v[0]) | (bf16_1(v[1]) << 16);
        w.y = bf16_1(v[2]) | (bf16_1(v[3]) << 16);
        w.z = bf16_1(v[4]) | (bf16_1(v[5]) << 16);
        w.w = bf16_1(v[6]) | (bf16_1(v[7]) << 16);
        *(uint4*)(yb + idx) = w;
    }
}

// ---------------- launch ----------------

extern "C" void kernel_launch(void* const* d_in, const int* in_sizes, int n_in,
                              void* d_out, int out_size, void* d_ws, size_t ws_size,
                              hipStream_t stream) {
    const float* x    = (const float*)d_in[0];
    const int*   ei   = (const int*)d_in[1];
    const float* Wl1  = (const float*)d_in[2];
    const float* bl1  = (const float*)d_in[3];
    const float* Wr1  = (const float*)d_in[4];
    const float* br1  = (const float*)d_in[5];
    const float* att1 = (const float*)d_in[6];
    const float* bc1  = (const float*)d_in[7];
    const float* g1   = (const float*)d_in[8];
    const float* be1  = (const float*)d_in[9];
    const float* Wl2  = (const float*)d_in[10];
    const float* bl2  = (const float*)d_in[11];
    const float* Wr2  = (const float*)d_in[12];
    const float* br2  = (const float*)d_in[13];
    const float* att2 = (const float*)d_in[14];
    const float* bc2  = (const float*)d_in[15];
    const float* g2   = (const float*)d_in[16];
    const float* be2  = (const float*)d_in[17];
    const float* W1   = (const float*)d_in[18];
    const float* b1   = (const float*)d_in[19];
    const float* W2   = (const float*)d_in[20];
    const float* b2   = (const float*)d_in[21];
    const int* esrc = ei;
    const int* edst = ei + NE;
    float* out = (float*)d_out;

    // ---- workspace layout ----
    float* bufD   = (float*)d_ws;          // mid fp32 [NN,128]      12.8 MB
    float* stats  = bufD + 3200000;        // 512 f (BN1 +0, BN2 +256)
    int* row_ptr  = (int*)(stats + 512);   // 25002
    int* cnt      = row_ptr + 25002;       // 25000
    int* col_src  = cnt + 25000;           // 425000 + 24 pad
    int* bsum     = col_src + 425024;      // 132 (pad)
    float* fb1    = (float*)(bsum + 132);  // 768 fused bias L1
    float* fb2    = fb1 + 768;             // 768 fused bias L2
    float* attc1  = fb2 + 768;             // 384 pre-scaled att L1
    float* attc2  = attc1 + 384;           // 384 pre-scaled att L2
    u16* xb       = (u16*)(attc2 + 384);   // x bf16 [NN,128]         6.4 MB
    u16* XLb      = xb + 3200000;          // head-major xl [3][NN][128]  19.2 MB
    u16* XRb      = XLb + 3 * NN * 128;    // head-major xr [3][NN][128]
    u16* bufCat   = XRb + 3 * NN * 128;    // [NN,768] h2|x_in bf16  38.4 MB
    u16* bufDb    = bufCat + 19200000;     // h bf16 [NN,128]         6.4 MB
    u16* WfT1     = bufDb + 3200000;       // [768][128]
    u16* W1T      = WfT1 + 98304;          // [128][384]
    u16* WfT2     = W1T + 49152;           // [768][128]
    u16* W2T      = WfT2 + 98304;          // [128][768]

    // zero cnt, then casts + transposes + biases + att prescale + edge-count + stats zero
    hipMemsetAsync(cnt, 0, NN * sizeof(int), stream);
    k_cast_all<<<(CAST_TOTAL + 255) / 256, 256, 0, stream>>>(
        x, Wl1, Wr1, W1, Wl2, Wr2, W2, bl1, br1, bl2, br2, att1, att2, edst,
        xb, WfT1, W1T, WfT2, W2T, fb1, fb2, attc1, attc2, cnt, stats);

    // CSR scans (scan2 folded into scan3)
    k_scan1<<<98, 256, 0, stream>>>(cnt, bsum);
    k_scan3<<<98, 256, 0, stream>>>(cnt, bsum, row_ptr, col_src, cnt);
    k_fill_edges<<<(NE + 255) / 256, 256, 0, stream>>>(esrc, edst, cnt, col_src);

    dim3 blk(256);
    dim3 gK(6, (NN + 127) / 128);        // K=128 GEMM
    dim3 g64(2, (NN + 63) / 64);         // BM=64 GEMMs: 782 blocks
    dim3 gGat((NN + 3) / 4, 3);          // gat: per-head blocks (L2 tiling)

    // layer 1
    k_gemm_k128<<<gK, blk, 0, stream>>>(xb, WfT1, fb1, XLb, NN);
    k_gat_h<<<gGat, blk, 0, stream>>>((const u32*)XLb, (const u32*)XRb, attc1, bc1,
                                      row_ptr, col_src, (u32*)bufCat + 192);

    // mid MLP (+BN stats folded) + BN apply
    k_gemm_bf<<<g64, blk, 0, stream>>>(bufCat + 384, W1T, b1, bufD, stats, NN, DD, HD, 768);
    k_bn_apply<<<(NN * DD / 8 + 255) / 256, 256, 0, stream>>>(bufD, stats, g1, be1, bufDb, 0);

    // layer 2
    k_gemm_k128<<<gK, blk, 0, stream>>>(bufDb, WfT2, fb2, XLb, NN);
    k_gat_h<<<gGat, blk, 0, stream>>>((const u32*)XLb, (const u32*)XRb, attc2, bc2,
                                      row_ptr, col_src, (u32*)bufCat);

    // final GEMM (+BN stats folded) + BN apply
    k_gemm_bf<<<g64, blk, 0, stream>>>(bufCat, W2T, b2, out, stats + 256, NN, DD, 768, 768);
    k_bn_apply<<<(NN * DD / 8 + 255) / 256, 256, 0, stream>>>(out, stats + 256, g2, be2, nullptr, 1);
}

// Round 5
// 342.031 us; speedup vs baseline: 1.2177x; 1.0962x over previous
//
#include <hip/hip_runtime.h>
#include <math.h>

#define NN 25000      // nodes
#define NE 400000     // edges
#define DD 128        // hidden dim
#define HD 384        // heads * dim
#define NEG 0.2f
#define EPS 1e-5f

typedef unsigned int u32;
typedef unsigned short u16;
typedef __attribute__((ext_vector_type(8))) short short8;   // 8 bf16 (4 VGPRs)
typedef __attribute__((ext_vector_type(4))) float floatx4;  // MFMA accumulator
typedef __attribute__((ext_vector_type(2))) float f32x2;    // packed-f32 pair

// ---- bf16 helpers (RNE) ----
__device__ __forceinline__ u32 bf16_1(float x) {
    u32 u = __float_as_uint(x);
    return (u + 0x7fffu + ((u >> 16) & 1u)) >> 16;
}
__device__ __forceinline__ float blo(u32 u) { return __uint_as_float(u << 16); }
__device__ __forceinline__ float bhi(u32 u) { return __uint_as_float(u & 0xffff0000u); }

__device__ __forceinline__ void up8f2(uint4 u, f32x2* f) {
    f[0] = f32x2{blo(u.x), bhi(u.x)};
    f[1] = f32x2{blo(u.y), bhi(u.y)};
    f[2] = f32x2{blo(u.z), bhi(u.z)};
    f[3] = f32x2{blo(u.w), bhi(u.w)};
}

// ---- packed f32 ops (CDNA v_pk_*, 2 f32 lanes / inst) ----
__device__ __forceinline__ f32x2 pk_add(f32x2 a, f32x2 b) {
    f32x2 d; asm("v_pk_add_f32 %0, %1, %2" : "=v"(d) : "v"(a), "v"(b)); return d;
}
__device__ __forceinline__ f32x2 pk_fma(f32x2 a, f32x2 b, f32x2 c) {
    f32x2 d; asm("v_pk_fma_f32 %0, %1, %2, %3" : "=v"(d) : "v"(a), "v"(b), "v"(c)); return d;
}
__device__ __forceinline__ f32x2 fabs2(f32x2 v) {
    u32 a = __float_as_uint(v.x) & 0x7fffffffu;
    u32 b = __float_as_uint(v.y) & 0x7fffffffu;
    return f32x2{__uint_as_float(a), __uint_as_float(b)};
}

// ---- 16-lane (DPP row) rotate-reduce: every lane gets the row total ----
__device__ __forceinline__ float row_sum16(float x) {
    int t;
    t = __builtin_amdgcn_update_dpp(0, __float_as_int(x), 0x121, 0xf, 0xf, false);
    x += __int_as_float(t);
    t = __builtin_amdgcn_update_dpp(0, __float_as_int(x), 0x122, 0xf, 0xf, false);
    x += __int_as_float(t);
    t = __builtin_amdgcn_update_dpp(0, __float_as_int(x), 0x124, 0xf, 0xf, false);
    x += __int_as_float(t);
    t = __builtin_amdgcn_update_dpp(0, __float_as_int(x), 0x128, 0xf, 0xf, false);
    x += __int_as_float(t);
    return x;
}

// ---------------- bucketed CSR: one atomic pass, no scans ----------------
// col_src is [NN][64] zero-initialized buckets; cnt zero-initialized.
// Self-loops are handled analytically in k_gat_h (no slot needed).
__global__ void k_fill_edges(const int* __restrict__ src, const int* __restrict__ dst,
                             int* __restrict__ cur, int* __restrict__ col_src) {
    int e = blockIdx.x * 256 + threadIdx.x;
    if (e < NE) {
        int d = dst[e];
        int p = atomicAdd(&cur[d], 1);
        col_src[(d << 6) + p] = src[e];
    }
}

// ---------------- one cast/init kernel ----------------
__global__ void k_cast_all(const float* __restrict__ x,
                           const float* __restrict__ Wl1, const float* __restrict__ Wr1,
                           const float* __restrict__ W1,
                           const float* __restrict__ Wl2, const float* __restrict__ Wr2,
                           const float* __restrict__ W2,
                           const float* __restrict__ bl1, const float* __restrict__ br1,
                           const float* __restrict__ bl2, const float* __restrict__ br2,
                           const float* __restrict__ att1, const float* __restrict__ att2,
                           u16* __restrict__ xb, u16* __restrict__ WfT1,
                           u16* __restrict__ W1T, u16* __restrict__ WfT2,
                           u16* __restrict__ W2T,
                           float* __restrict__ fb1, float* __restrict__ fb2,
                           float* __restrict__ attc1, float* __restrict__ attc2,
                           float* __restrict__ stats) {
    int i = blockIdx.x * 256 + threadIdx.x;
    if (i < 400000) {   // x cast, 8 elems/thread, coalesced 16B writes
        const float4* xp = (const float4*)(x + (size_t)i * 8);
        float4 a = xp[0], b = xp[1];
        uint4 w;
        w.x = bf16_1(a.x) | (bf16_1(a.y) << 16);
        w.y = bf16_1(a.z) | (bf16_1(a.w) << 16);
        w.z = bf16_1(b.x) | (bf16_1(b.y) << 16);
        w.w = bf16_1(b.z) | (bf16_1(b.w) << 16);
        *(uint4*)(xb + (size_t)i * 8) = w;
        return;
    }
    i -= 400000;
    if (i < 49152) { int k = i / 384, n = i - k * 384; WfT1[n * 128 + k] = (u16)bf16_1(Wl1[i]); return; }
    i -= 49152;
    if (i < 49152) { int k = i / 384, n = i - k * 384; WfT1[(384 + n) * 128 + k] = (u16)bf16_1(Wr1[i]); return; }
    i -= 49152;
    if (i < 49152) { int k = i / 128, n = i - k * 128; W1T[n * 384 + k] = (u16)bf16_1(W1[i]); return; }
    i -= 49152;
    if (i < 49152) { int k = i / 384, n = i - k * 384; WfT2[n * 128 + k] = (u16)bf16_1(Wl2[i]); return; }
    i -= 49152;
    if (i < 49152) { int k = i / 384, n = i - k * 384; WfT2[(384 + n) * 128 + k] = (u16)bf16_1(Wr2[i]); return; }
    i -= 49152;
    if (i < 98304) { int k = i / 128, n = i - k * 128; W2T[n * 768 + k] = (u16)bf16_1(W2[i]); return; }
    i -= 98304;
    if (i < 768) { fb1[i] = (i < 384) ? bl1[i] : br1[i - 384]; return; }
    i -= 768;
    if (i < 768) { fb2[i] = (i < 384) ? bl2[i] : br2[i - 384]; return; }
    i -= 768;
    // pre-scaled attention vectors: 0.6 * log2(e) * att
    if (i < 384) { attc1[i] = att1[i] * 0.86561702f; return; }
    i -= 384;
    if (i < 384) { attc2[i] = att2[i] * 0.86561702f; return; }
    i -= 384;
    if (i < 512) stats[i] = 0.f;
}
#define CAST_TOTAL (400000 + 5 * 49152 + 98304 + 1536 + 768 + 512)

// ---------------- K=128 single-shot GEMM (the xl|xr transforms) ----------------
__global__ __launch_bounds__(256) void k_gemm_k128(
        const u16* __restrict__ A, const u16* __restrict__ BT,
        const float* __restrict__ bias, u16* __restrict__ Cb, int M) {
    __shared__ short sA[128 * 128];
    __shared__ short sB[128 * 128];
    int tid = threadIdx.x;
    int wv = tid >> 6, lane = tid & 63;
    int quad = lane >> 4, m16 = lane & 15;
    int mb = blockIdx.y * 128, nb = blockIdx.x * 128;

#pragma unroll
    for (int j = 0; j < 8; ++j) {
        int L = j * 256 + tid;
        int r = L >> 4, c8 = (L & 15) ^ (r & 15);
        int gr = mb + r; gr = gr < M ? gr : M - 1;
        __builtin_amdgcn_global_load_lds(
            (const __attribute__((address_space(1))) void*)(A + (size_t)gr * 128 + c8 * 8),
            (__attribute__((address_space(3))) void*)(sA + (size_t)L * 8), 16, 0, 0);
    }
#pragma unroll
    for (int j = 0; j < 8; ++j) {
        int L = j * 256 + tid;
        int r = L >> 4, c8 = (L & 15) ^ (r & 15);
        __builtin_amdgcn_global_load_lds(
            (const __attribute__((address_space(1))) void*)(BT + (size_t)(nb + r) * 128 + c8 * 8),
            (__attribute__((address_space(3))) void*)(sB + (size_t)L * 8), 16, 0, 0);
    }
    __syncthreads();

    floatx4 acc[2][8];
#pragma unroll
    for (int mf = 0; mf < 2; ++mf)
#pragma unroll
        for (int nf = 0; nf < 8; ++nf)
#pragma unroll
            for (int r = 0; r < 4; ++r) acc[mf][nf][r] = 0.f;

#pragma unroll
    for (int ks = 0; ks < 4; ++ks) {
        int slot = (ks * 4 + quad) ^ m16;
        int row0 = wv * 32 + m16, row1 = row0 + 16;
        short8 a0 = *(const short8*)(sA + ((size_t)row0 * 16 + slot) * 8);
        short8 a1 = *(const short8*)(sA + ((size_t)row1 * 16 + slot) * 8);
#pragma unroll
        for (int nf = 0; nf < 8; ++nf) {
            short8 b = *(const short8*)(sB + ((size_t)(nf * 16 + m16) * 16 + slot) * 8);
            acc[0][nf] = __builtin_amdgcn_mfma_f32_16x16x32_bf16(a0, b, acc[0][nf], 0, 0, 0);
            acc[1][nf] = __builtin_amdgcn_mfma_f32_16x16x32_bf16(a1, b, acc[1][nf], 0, 0, 0);
        }
    }
    __syncthreads();

#pragma unroll
    for (int mf = 0; mf < 2; ++mf)
#pragma unroll
        for (int nf = 0; nf < 8; ++nf)
#pragma unroll
            for (int r = 0; r < 4; ++r) {
                int row = wv * 32 + mf * 16 + quad * 4 + r;
                int col = nf * 16 + m16;
                sA[row * 128 + col] = (short)bf16_1(acc[mf][nf][r] + bias[nb + col]);
            }
    __syncthreads();
    int xr = nb >= 384;
    int h = (xr ? (nb - 384) : nb) >> 7;
    u16* cb = Cb + ((size_t)(xr * 3 + h) * NN) * 128;
#pragma unroll
    for (int i = 0; i < 8; ++i) {
        int u = i * 256 + tid;
        int row = u >> 4, c8 = u & 15;
        int grow = mb + row;
        if (grow < M)
            *(uint4*)(cb + (size_t)grow * 128 + c8 * 8) = *(const uint4*)(sA + (size_t)u * 8);
    }
}

// ---------------- bf16 MFMA GEMM (K-loop, BK=128): C[M,N] = A[M,K] @ BT[N,K]^T ----------------
// BK=128 halves the number of barrier-drained K-steps vs BK=64 (latency-bound
// kernel). Stage/swizzle pattern mirrors k_gemm_k128 (proven). 34 KB LDS.
__global__ __launch_bounds__(256) void k_gemm_bf(
        const u16* __restrict__ A, const u16* __restrict__ BT,
        const float* __restrict__ bias,
        float* __restrict__ Cf, float* __restrict__ stats,
        int M, int N, int K, int lda) {
    __shared__ short smem[17408];   // 34 KB: sA 16K + sB 16K + stat partials 2K
    short* sA = smem;               // 64 x 128
    short* sB = smem + 8192;        // 64 x 128
    int tid = threadIdx.x;
    int wv = tid >> 6, lane = tid & 63;
    int quad = lane >> 4, m16 = lane & 15;
    int mb = blockIdx.y * 64, nb = blockIdx.x * 64;

    floatx4 acc[4];
#pragma unroll
    for (int nf = 0; nf < 4; ++nf)
#pragma unroll
        for (int r = 0; r < 4; ++r) acc[nf][r] = 0.f;

    for (int k0 = 0; k0 < K; k0 += 128) {
#pragma unroll
        for (int j = 0; j < 4; ++j) {
            int L = j * 256 + tid;
            int r = L >> 4, c8 = (L & 15) ^ (r & 15);
            int gr = mb + r; gr = gr < M ? gr : M - 1;
            __builtin_amdgcn_global_load_lds(
                (const __attribute__((address_space(1))) void*)(A + (size_t)gr * lda + k0 + c8 * 8),
                (__attribute__((address_space(3))) void*)(sA + (size_t)L * 8), 16, 0, 0);
        }
#pragma unroll
        for (int j = 0; j < 4; ++j) {
            int L = j * 256 + tid;
            int r = L >> 4, c8 = (L & 15) ^ (r & 15);
            __builtin_amdgcn_global_load_lds(
                (const __attribute__((address_space(1))) void*)(BT + (size_t)(nb + r) * K + k0 + c8 * 8),
                (__attribute__((address_space(3))) void*)(sB + (size_t)L * 8), 16, 0, 0);
        }
        __syncthreads();
#pragma unroll
        for (int ks = 0; ks < 4; ++ks) {
            int slot = (ks * 4 + quad) ^ m16;
            short8 a0 = *(const short8*)(sA + ((size_t)(wv * 16 + m16) * 16 + slot) * 8);
#pragma unroll
            for (int nf = 0; nf < 4; ++nf) {
                short8 b = *(const short8*)(sB + ((size_t)(nf * 16 + m16) * 16 + slot) * 8);
                acc[nf] = __builtin_amdgcn_mfma_f32_16x16x32_bf16(a0, b, acc[nf], 0, 0, 0);
            }
        }
        __syncthreads();
    }
    // fp32 tile [64][64] staged in LDS (16 KB), coalesced float4 stores
    float* fs = (float*)smem;
#pragma unroll
    for (int nf = 0; nf < 4; ++nf)
#pragma unroll
        for (int r = 0; r < 4; ++r) {
            int row = wv * 16 + quad * 4 + r;
            int col = nf * 16 + m16;
            fs[row * 64 + col] = acc[nf][r] + (bias ? bias[nb + col] : 0.f);
        }
    __syncthreads();
#pragma unroll
    for (int i = 0; i < 4; ++i) {
        int u = i * 256 + tid;
        int row = u >> 4, c4 = u & 15;
        int grow = mb + row;
        if (grow < M)
            *(float4*)(Cf + (size_t)grow * N + nb + c4 * 4) = *(const float4*)(fs + (size_t)u * 4);
    }
    // folded BN stats: per-column sum/sumsq partials -> atomicAdd
    if (stats) {
        float* ps = (float*)(smem + 16384);   // [2][4][64]
        int col = tid & 63, qr = tid >> 6;
        int vr = M - mb; vr = vr < 64 ? vr : 64;
        int r0 = qr * 16, r1 = r0 + 16 < vr ? r0 + 16 : vr;
        float s = 0.f, q = 0.f;
        for (int r = r0; r < r1; ++r) { float v = fs[r * 64 + col]; s += v; q += v * v; }
        ps[qr * 64 + col] = s;
        ps[256 + qr * 64 + col] = q;
        __syncthreads();
        if (tid < 64) {
            float ss = ps[tid] + ps[64 + tid] + ps[128 + tid] + ps[192 + tid];
            atomicAdd(&stats[nb + tid], ss);
        } else if (tid < 128) {
            int c = tid - 64;
            float qq = ps[256 + c] + ps[320 + c] + ps[384 + c] + ps[448 + c];
            atomicAdd(&stats[128 + nb + c], qq);
        }
    }
}

// ---------------- GATv2 aggregate, per-head blocks, bucketed CSR ----------------
// e0 = node*64 (implicit buckets), cntE = cnt[node] (edges only).
// Self-loop computed analytically in the prologue (group 0), no slot needed.
__global__ __launch_bounds__(256) void k_gat_h(const u32* __restrict__ XLb,
                                               const u32* __restrict__ XRb,
                                               const float* __restrict__ attc,
                                               const float* __restrict__ bias,
                                               const int* __restrict__ cnt,
                                               const int* __restrict__ col_src,
                                               u32* __restrict__ outb) {
    int h = blockIdx.y;
    const u32* XLh = XLb + (size_t)h * NN * 64;
    const u32* XRh = XRb + (size_t)h * NN * 64;
    int node = blockIdx.x * 4 + (threadIdx.x >> 6);
    int lane = threadIdx.x & 63;
    int g = lane >> 4, gl = lane & 15;

    f32x2 xr2[4], a6[4], acc2[4];
    const f32x2 c23 = {0.66666667f, 0.66666667f};
    up8f2(*(const uint4*)(XRh + (size_t)node * 64 + 4 * gl), xr2);
#pragma unroll
    for (int j = 0; j < 4; ++j) {
        a6[j] = *(const f32x2*)(attc + h * 128 + 8 * gl + 2 * j);
        acc2[j] = f32x2{0.f, 0.f};
    }
    float l = 0.f;

    int e0 = node << 6;
    int cntE = cnt[node];

    // issue first edge-index loads early
    int c0i = col_src[e0 + g];
    int c1i = col_src[e0 + g + 4];

    // self-loop contribution (group 0 only; whole 16-lane DPP row active)
    if (g == 0) {
        f32x2 xs[4];
        up8f2(*(const uint4*)(XLh + (size_t)node * 64 + 4 * gl), xs);
        f32x2 p2 = {0.f, 0.f};
#pragma unroll
        for (int j = 0; j < 4; ++j) {
            f32x2 v = pk_add(xs[j], xr2[j]);
            p2 = pk_fma(pk_fma(fabs2(v), c23, v), a6[j], p2);
        }
        float w = __builtin_amdgcn_exp2f(row_sum16(p2.x + p2.y));
        l = w;
        f32x2 w2 = {w, w};
#pragma unroll
        for (int j = 0; j < 4; ++j) acc2[j] = pk_fma(xs[j], w2, acc2[j]);
    }

    uint4 ua = *(const uint4*)(XLh + (size_t)c0i * 64 + 4 * gl);
    uint4 ub = *(const uint4*)(XLh + (size_t)c1i * 64 + 4 * gl);

    for (int t = g; t < cntE; t += 8) {
        uint4 un0 = *(const uint4*)(XLh + (size_t)col_src[e0 + t + 8] * 64 + 4 * gl);
        uint4 un1 = *(const uint4*)(XLh + (size_t)col_src[e0 + t + 12] * 64 + 4 * gl);

        f32x2 xa2[4], xb2[4];
        up8f2(ua, xa2); up8f2(ub, xb2);
        f32x2 pa2 = {0.f, 0.f}, pb2 = {0.f, 0.f};
#pragma unroll
        for (int j = 0; j < 4; ++j) {
            f32x2 va = pk_add(xa2[j], xr2[j]);
            f32x2 vb = pk_add(xb2[j], xr2[j]);
            pa2 = pk_fma(pk_fma(fabs2(va), c23, va), a6[j], pa2);
            pb2 = pk_fma(pk_fma(fabs2(vb), c23, vb), a6[j], pb2);
        }
        float pa = row_sum16(pa2.x + pa2.y);
        float pb = row_sum16(pb2.x + pb2.y);
        float wa = __builtin_amdgcn_exp2f(pa);
        float wb = ((t + 4) < cntE) ? __builtin_amdgcn_exp2f(pb) : 0.f;
        l += wa + wb;
        f32x2 wa2 = {wa, wa}, wb2 = {wb, wb};
#pragma unroll
        for (int j = 0; j < 4; ++j)
            acc2[j] = pk_fma(xa2[j], wa2, pk_fma(xb2[j], wb2, acc2[j]));

        ua = un0; ub = un1;
    }

#pragma unroll
    for (int o = 16; o <= 32; o <<= 1) {
        l += __shfl_xor(l, o);
#pragma unroll
        for (int j = 0; j < 4; ++j) {
            f32x2 s;
            s.x = __shfl_xor(acc2[j].x, o);
            s.y = __shfl_xor(acc2[j].y, o);
            acc2[j] = pk_add(acc2[j], s);
        }
    }

    if (g == 0) {
        float r = 1.f / l;
        float bv[8];
        *(float4*)&bv[0] = *(const float4*)&bias[h * 128 + 8 * gl];
        *(float4*)&bv[4] = *(const float4*)&bias[h * 128 + 8 * gl + 4];
        uint4 w;
        w.x = bf16_1(fmaf(acc2[0].x, r, bv[0])) | (bf16_1(fmaf(acc2[0].y, r, bv[1])) << 16);
        w.y = bf16_1(fmaf(acc2[1].x, r, bv[2])) | (bf16_1(fmaf(acc2[1].y, r, bv[3])) << 16);
        w.z = bf16_1(fmaf(acc2[2].x, r, bv[4])) | (bf16_1(fmaf(acc2[2].y, r, bv[5])) << 16);
        w.w = bf16_1(fmaf(acc2[3].x, r, bv[6])) | (bf16_1(fmaf(acc2[3].y, r, bv[7])) << 16);
        *(uint4*)(outb + (size_t)node * 384 + h * 64 + 4 * gl) = w;
    }
}

// ---------------- BN apply (stats pre-accumulated in the GEMM) ----------------
__global__ void k_bn_apply(float* __restrict__ y, const float* __restrict__ stats,
                           const float* __restrict__ g, const float* __restrict__ be,
                           u16* __restrict__ yb, int wf) {
    int i = blockIdx.x * 256 + threadIdx.x;
    if (i >= NN * DD / 8) return;
    int idx = i * 8;
    int c0 = idx & 127;
    float v[8];
    *(float4*)&v[0] = *(const float4*)(y + idx);
    *(float4*)&v[4] = *(const float4*)(y + idx + 4);
    const float minv = 1.f / (float)NN;
#pragma unroll
    for (int k = 0; k < 8; ++k) {
        int c = c0 + k;
        float mu = stats[c] * minv;
        float var = stats[128 + c] * minv - mu * mu;
        float sc = g[c] * rsqrtf(var + EPS);
        float sh = be[c] - mu * sc;
        v[k] = fmaxf(fmaf(v[k], sc, sh), 0.f);
    }
    if (wf) {
        *(float4*)(y + idx) = *(const float4*)&v[0];
        *(float4*)(y + idx + 4) = *(const float4*)&v[4];
    }
    if (yb) {
        uint4 w;
        w.x = bf16_1(v[0]) | (bf16_1(v[1]) << 16);
        w.y = bf16_1(v[2]) | (bf16_1(v[3]) << 16);
        w.z = bf16_1(v[4]) | (bf16_1(v[5]) << 16);
        w.w = bf16_1(v[6]) | (bf16_1(v[7]) << 16);
        *(uint4*)(yb + idx) = w;
    }
}

// ---------------- launch ----------------

extern "C" void kernel_launch(void* const* d_in, const int* in_sizes, int n_in,
                              void* d_out, int out_size, void* d_ws, size_t ws_size,
                              hipStream_t stream) {
    const float* x    = (const float*)d_in[0];
    const int*   ei   = (const int*)d_in[1];
    const float* Wl1  = (const float*)d_in[2];
    const float* bl1  = (const float*)d_in[3];
    const float* Wr1  = (const float*)d_in[4];
    const float* br1  = (const float*)d_in[5];
    const float* att1 = (const float*)d_in[6];
    const float* bc1  = (const float*)d_in[7];
    const float* g1   = (const float*)d_in[8];
    const float* be1  = (const float*)d_in[9];
    const float* Wl2  = (const float*)d_in[10];
    const float* bl2  = (const float*)d_in[11];
    const float* Wr2  = (const float*)d_in[12];
    const float* br2  = (const float*)d_in[13];
    const float* att2 = (const float*)d_in[14];
    const float* bc2  = (const float*)d_in[15];
    const float* g2   = (const float*)d_in[16];
    const float* be2  = (const float*)d_in[17];
    const float* W1   = (const float*)d_in[18];
    const float* b1   = (const float*)d_in[19];
    const float* W2   = (const float*)d_in[20];
    const float* b2   = (const float*)d_in[21];
    const int* esrc = ei;
    const int* edst = ei + NE;
    float* out = (float*)d_out;

    // ---- workspace layout (all regions 16B-aligned) ----
    float* bufD   = (float*)d_ws;          // mid fp32 [NN,128]      12.8 MB
    float* stats  = bufD + 3200000;        // 512 f (BN1 +0, BN2 +256)
    int* cnt      = (int*)(stats + 512);   // 25000 edge counters
    int* col_src  = cnt + 25000;           // [NN][64] buckets + 24 pad  6.4 MB
    float* fb1    = (float*)(col_src + 1600024);  // 768 fused bias L1
    float* fb2    = fb1 + 768;             // 768 fused bias L2
    float* attc1  = fb2 + 768;             // 384 pre-scaled att L1
    float* attc2  = attc1 + 384;           // 384 pre-scaled att L2
    u16* xb       = (u16*)(attc2 + 384);   // x bf16 [NN,128]         6.4 MB
    u16* XLb      = xb + 3200000;          // head-major xl [3][NN][128]  19.2 MB
    u16* XRb      = XLb + 3 * NN * 128;    // head-major xr [3][NN][128]
    u16* bufCat   = XRb + 3 * NN * 128;    // [NN,768] h2|x_in bf16  38.4 MB
    u16* bufDb    = bufCat + 19200000;     // h bf16 [NN,128]         6.4 MB
    u16* WfT1     = bufDb + 3200000;       // [768][128]
    u16* W1T      = WfT1 + 98304;          // [128][384]
    u16* WfT2     = W1T + 49152;           // [768][128]
    u16* W2T      = WfT2 + 98304;          // [128][768]

    // zero counters + buckets, then casts/transposes/biases, then bucket fill
    hipMemsetAsync(cnt, 0, NN * sizeof(int), stream);
    hipMemsetAsync(col_src, 0, (NN * 64 + 24) * sizeof(int), stream);
    k_cast_all<<<(CAST_TOTAL + 255) / 256, 256, 0, stream>>>(
        x, Wl1, Wr1, W1, Wl2, Wr2, W2, bl1, br1, bl2, br2, att1, att2,
        xb, WfT1, W1T, WfT2, W2T, fb1, fb2, attc1, attc2, stats);
    k_fill_edges<<<(NE + 255) / 256, 256, 0, stream>>>(esrc, edst, cnt, col_src);

    dim3 blk(256);
    dim3 gK(6, (NN + 127) / 128);        // K=128 GEMM
    dim3 g64(2, (NN + 63) / 64);         // BM=64 GEMMs: 782 blocks
    dim3 gGat((NN + 3) / 4, 3);          // gat: per-head blocks (L2 tiling)

    // layer 1
    k_gemm_k128<<<gK, blk, 0, stream>>>(xb, WfT1, fb1, XLb, NN);
    k_gat_h<<<gGat, blk, 0, stream>>>((const u32*)XLb, (const u32*)XRb, attc1, bc1,
                                      cnt, col_src, (u32*)bufCat + 192);

    // mid MLP (+BN stats folded) + BN apply
    k_gemm_bf<<<g64, blk, 0, stream>>>(bufCat + 384, W1T, b1, bufD, stats, NN, DD, HD, 768);
    k_bn_apply<<<(NN * DD / 8 + 255) / 256, 256, 0, stream>>>(bufD, stats, g1, be1, bufDb, 0);

    // layer 2
    k_gemm_k128<<<gK, blk, 0, stream>>>(bufDb, WfT2, fb2, XLb, NN);
    k_gat_h<<<gGat, blk, 0, stream>>>((const u32*)XLb, (const u32*)XRb, attc2, bc2,
                                      cnt, col_src, (u32*)bufCat);

    // final GEMM (+BN stats folded) + BN apply
    k_gemm_bf<<<g64, blk, 0, stream>>>(bufCat, W2T, b2, out, stats + 256, NN, DD, 768, 768);
    k_bn_apply<<<(NN * DD / 8 + 255) / 256, 256, 0, stream>>>(out, stats + 256, g2, be2, nullptr, 1);
}

// Round 6
// 338.314 us; speedup vs baseline: 1.2310x; 1.0110x over previous
//
#include <hip/hip_runtime.h>
#include <math.h>

#define NN 25000      // nodes
#define NE 400000     // edges
#define DD 128        // hidden dim
#define HD 384        // heads * dim
#define NEG 0.2f
#define EPS 1e-5f

typedef unsigned int u32;
typedef unsigned short u16;
typedef __attribute__((ext_vector_type(8))) short short8;   // 8 bf16 (4 VGPRs)
typedef __attribute__((ext_vector_type(4))) float floatx4;  // MFMA accumulator
typedef __attribute__((ext_vector_type(2))) float f32x2;    // packed-f32 pair

// ---- bf16 helpers (RNE) ----
__device__ __forceinline__ u32 bf16_1(float x) {
    u32 u = __float_as_uint(x);
    return (u + 0x7fffu + ((u >> 16) & 1u)) >> 16;
}
__device__ __forceinline__ float blo(u32 u) { return __uint_as_float(u << 16); }
__device__ __forceinline__ float bhi(u32 u) { return __uint_as_float(u & 0xffff0000u); }

__device__ __forceinline__ void up8f2(uint4 u, f32x2* f) {
    f[0] = f32x2{blo(u.x), bhi(u.x)};
    f[1] = f32x2{blo(u.y), bhi(u.y)};
    f[2] = f32x2{blo(u.z), bhi(u.z)};
    f[3] = f32x2{blo(u.w), bhi(u.w)};
}

// ---- packed f32 ops (CDNA v_pk_*, 2 f32 lanes / inst) ----
__device__ __forceinline__ f32x2 pk_add(f32x2 a, f32x2 b) {
    f32x2 d; asm("v_pk_add_f32 %0, %1, %2" : "=v"(d) : "v"(a), "v"(b)); return d;
}
__device__ __forceinline__ f32x2 pk_fma(f32x2 a, f32x2 b, f32x2 c) {
    f32x2 d; asm("v_pk_fma_f32 %0, %1, %2, %3" : "=v"(d) : "v"(a), "v"(b), "v"(c)); return d;
}
__device__ __forceinline__ f32x2 fabs2(f32x2 v) {
    u32 a = __float_as_uint(v.x) & 0x7fffffffu;
    u32 b = __float_as_uint(v.y) & 0x7fffffffu;
    return f32x2{__uint_as_float(a), __uint_as_float(b)};
}

// ---- 16-lane (DPP row) rotate-reduce: every lane gets the row total ----
__device__ __forceinline__ float row_sum16(float x) {
    int t;
    t = __builtin_amdgcn_update_dpp(0, __float_as_int(x), 0x121, 0xf, 0xf, false);
    x += __int_as_float(t);
    t = __builtin_amdgcn_update_dpp(0, __float_as_int(x), 0x122, 0xf, 0xf, false);
    x += __int_as_float(t);
    t = __builtin_amdgcn_update_dpp(0, __float_as_int(x), 0x124, 0xf, 0xf, false);
    x += __int_as_float(t);
    t = __builtin_amdgcn_update_dpp(0, __float_as_int(x), 0x128, 0xf, 0xf, false);
    x += __int_as_float(t);
    return x;
}

// ---------------- one cast/init kernel (bucket fill folded back in) ----------------
// cnt and col_src pre-zeroed by memsets. Bucketed CSR: col_src[dst*64 + p].
__global__ void k_cast_all(const float* __restrict__ x,
                           const float* __restrict__ Wl1, const float* __restrict__ Wr1,
                           const float* __restrict__ W1,
                           const float* __restrict__ Wl2, const float* __restrict__ Wr2,
                           const float* __restrict__ W2,
                           const float* __restrict__ bl1, const float* __restrict__ br1,
                           const float* __restrict__ bl2, const float* __restrict__ br2,
                           const float* __restrict__ att1, const float* __restrict__ att2,
                           const int* __restrict__ esrc, const int* __restrict__ edst,
                           u16* __restrict__ xb, u16* __restrict__ WfT1,
                           u16* __restrict__ W1T, u16* __restrict__ WfT2,
                           u16* __restrict__ W2T,
                           float* __restrict__ fb1, float* __restrict__ fb2,
                           float* __restrict__ attc1, float* __restrict__ attc2,
                           int* __restrict__ cnt, int* __restrict__ col_src,
                           float* __restrict__ stats) {
    int i = blockIdx.x * 256 + threadIdx.x;
    if (i < 400000) {   // x cast, 8 elems/thread, coalesced 16B writes
        const float4* xp = (const float4*)(x + (size_t)i * 8);
        float4 a = xp[0], b = xp[1];
        uint4 w;
        w.x = bf16_1(a.x) | (bf16_1(a.y) << 16);
        w.y = bf16_1(a.z) | (bf16_1(a.w) << 16);
        w.z = bf16_1(b.x) | (bf16_1(b.y) << 16);
        w.w = bf16_1(b.z) | (bf16_1(b.w) << 16);
        *(uint4*)(xb + (size_t)i * 8) = w;
        return;
    }
    i -= 400000;
    if (i < 400000) {   // bucketed edge fill (one atomic per edge)
        int d = edst[i];
        int p = atomicAdd(&cnt[d], 1);
        col_src[(d << 6) + p] = esrc[i];
        return;
    }
    i -= 400000;
    if (i < 49152) { int k = i / 384, n = i - k * 384; WfT1[n * 128 + k] = (u16)bf16_1(Wl1[i]); return; }
    i -= 49152;
    if (i < 49152) { int k = i / 384, n = i - k * 384; WfT1[(384 + n) * 128 + k] = (u16)bf16_1(Wr1[i]); return; }
    i -= 49152;
    if (i < 49152) { int k = i / 128, n = i - k * 128; W1T[n * 384 + k] = (u16)bf16_1(W1[i]); return; }
    i -= 49152;
    if (i < 49152) { int k = i / 384, n = i - k * 384; WfT2[n * 128 + k] = (u16)bf16_1(Wl2[i]); return; }
    i -= 49152;
    if (i < 49152) { int k = i / 384, n = i - k * 384; WfT2[(384 + n) * 128 + k] = (u16)bf16_1(Wr2[i]); return; }
    i -= 49152;
    if (i < 98304) { int k = i / 128, n = i - k * 128; W2T[n * 768 + k] = (u16)bf16_1(W2[i]); return; }
    i -= 98304;
    if (i < 768) { fb1[i] = (i < 384) ? bl1[i] : br1[i - 384]; return; }
    i -= 768;
    if (i < 768) { fb2[i] = (i < 384) ? bl2[i] : br2[i - 384]; return; }
    i -= 768;
    // pre-scaled attention vectors: 0.6 * log2(e) * att
    if (i < 384) { attc1[i] = att1[i] * 0.86561702f; return; }
    i -= 384;
    if (i < 384) { attc2[i] = att2[i] * 0.86561702f; return; }
    i -= 384;
    if (i < 512) stats[i] = 0.f;
}
#define CAST_TOTAL (400000 + 400000 + 5 * 49152 + 98304 + 1536 + 768 + 512)

// ---------------- K=128 single-shot GEMM (the xl|xr transforms) ----------------
// BM=64, internal loop over the 6 N-tiles: A staged ONCE per block (HBM A
// traffic /6 vs the old grid(6,196) layout where 6 XCD-scattered blocks each
// re-fetched the same A tile). B (196 KB) stays L2-hot. 48 KB LDS.
__global__ __launch_bounds__(256) void k_gemm_k128(
        const u16* __restrict__ A, const u16* __restrict__ BT,
        const float* __restrict__ bias, u16* __restrict__ Cb, int M) {
    __shared__ short sA[64 * 128];    // 16 KB
    __shared__ short sB[128 * 128];   // 32 KB
    int tid = threadIdx.x;
    int wv = tid >> 6, lane = tid & 63;
    int quad = lane >> 4, m16 = lane & 15;
    int mb = blockIdx.x * 64;

    // stage A once (drained by the barrier after the first B stage)
#pragma unroll
    for (int j = 0; j < 4; ++j) {
        int L = j * 256 + tid;
        int r = L >> 4, c8 = (L & 15) ^ (r & 15);
        int gr = mb + r; gr = gr < M ? gr : M - 1;
        __builtin_amdgcn_global_load_lds(
            (const __attribute__((address_space(1))) void*)(A + (size_t)gr * 128 + c8 * 8),
            (__attribute__((address_space(3))) void*)(sA + (size_t)L * 8), 16, 0, 0);
    }

    for (int nb6 = 0; nb6 < 6; ++nb6) {
        int nb = nb6 * 128;
        __syncthreads();   // protect sB from prior iteration's store-reads
#pragma unroll
        for (int j = 0; j < 8; ++j) {
            int L = j * 256 + tid;
            int r = L >> 4, c8 = (L & 15) ^ (r & 15);
            __builtin_amdgcn_global_load_lds(
                (const __attribute__((address_space(1))) void*)(BT + (size_t)(nb + r) * 128 + c8 * 8),
                (__attribute__((address_space(3))) void*)(sB + (size_t)L * 8), 16, 0, 0);
        }
        __syncthreads();   // sA (first iter) + sB staged

        floatx4 acc[8];
#pragma unroll
        for (int nf = 0; nf < 8; ++nf)
#pragma unroll
            for (int r = 0; r < 4; ++r) acc[nf][r] = 0.f;

#pragma unroll
        for (int ks = 0; ks < 4; ++ks) {
            int slot = (ks * 4 + quad) ^ m16;
            short8 a0 = *(const short8*)(sA + ((size_t)(wv * 16 + m16) * 16 + slot) * 8);
#pragma unroll
            for (int nf = 0; nf < 8; ++nf) {
                short8 b = *(const short8*)(sB + ((size_t)(nf * 16 + m16) * 16 + slot) * 8);
                acc[nf] = __builtin_amdgcn_mfma_f32_16x16x32_bf16(a0, b, acc[nf], 0, 0, 0);
            }
        }
        __syncthreads();   // all MFMA reads of sB done

        // repack 64x128 bf16 output tile into sB (+bias)
#pragma unroll
        for (int nf = 0; nf < 8; ++nf)
#pragma unroll
            for (int r = 0; r < 4; ++r) {
                int row = wv * 16 + quad * 4 + r;
                int col = nf * 16 + m16;
                sB[row * 128 + col] = (short)bf16_1(acc[nf][r] + bias[nb + col]);
            }
        __syncthreads();

        int xr = nb >= 384;
        int h = (xr ? (nb - 384) : nb) >> 7;
        u16* cb = Cb + ((size_t)(xr * 3 + h) * NN) * 128;
#pragma unroll
        for (int i = 0; i < 4; ++i) {
            int u = i * 256 + tid;
            int row = u >> 4, c8 = u & 15;
            int grow = mb + row;
            if (grow < M)
                *(uint4*)(cb + (size_t)grow * 128 + c8 * 8) = *(const uint4*)(sB + (size_t)u * 8);
        }
    }
}

// ---------------- bf16 MFMA GEMM (K-loop, BK=128): C[M,N] = A[M,K] @ BT[N,K]^T ----------------
__global__ __launch_bounds__(256) void k_gemm_bf(
        const u16* __restrict__ A, const u16* __restrict__ BT,
        const float* __restrict__ bias,
        float* __restrict__ Cf, float* __restrict__ stats,
        int M, int N, int K, int lda) {
    __shared__ short smem[17408];   // 34 KB: sA 16K + sB 16K + stat partials 2K
    short* sA = smem;               // 64 x 128
    short* sB = smem + 8192;        // 64 x 128
    int tid = threadIdx.x;
    int wv = tid >> 6, lane = tid & 63;
    int quad = lane >> 4, m16 = lane & 15;
    int mb = blockIdx.y * 64, nb = blockIdx.x * 64;

    floatx4 acc[4];
#pragma unroll
    for (int nf = 0; nf < 4; ++nf)
#pragma unroll
        for (int r = 0; r < 4; ++r) acc[nf][r] = 0.f;

    for (int k0 = 0; k0 < K; k0 += 128) {
#pragma unroll
        for (int j = 0; j < 4; ++j) {
            int L = j * 256 + tid;
            int r = L >> 4, c8 = (L & 15) ^ (r & 15);
            int gr = mb + r; gr = gr < M ? gr : M - 1;
            __builtin_amdgcn_global_load_lds(
                (const __attribute__((address_space(1))) void*)(A + (size_t)gr * lda + k0 + c8 * 8),
                (__attribute__((address_space(3))) void*)(sA + (size_t)L * 8), 16, 0, 0);
        }
#pragma unroll
        for (int j = 0; j < 4; ++j) {
            int L = j * 256 + tid;
            int r = L >> 4, c8 = (L & 15) ^ (r & 15);
            __builtin_amdgcn_global_load_lds(
                (const __attribute__((address_space(1))) void*)(BT + (size_t)(nb + r) * K + k0 + c8 * 8),
                (__attribute__((address_space(3))) void*)(sB + (size_t)L * 8), 16, 0, 0);
        }
        __syncthreads();
#pragma unroll
        for (int ks = 0; ks < 4; ++ks) {
            int slot = (ks * 4 + quad) ^ m16;
            short8 a0 = *(const short8*)(sA + ((size_t)(wv * 16 + m16) * 16 + slot) * 8);
#pragma unroll
            for (int nf = 0; nf < 4; ++nf) {
                short8 b = *(const short8*)(sB + ((size_t)(nf * 16 + m16) * 16 + slot) * 8);
                acc[nf] = __builtin_amdgcn_mfma_f32_16x16x32_bf16(a0, b, acc[nf], 0, 0, 0);
            }
        }
        __syncthreads();
    }
    // fp32 tile [64][64] staged in LDS (16 KB), coalesced float4 stores
    float* fs = (float*)smem;
#pragma unroll
    for (int nf = 0; nf < 4; ++nf)
#pragma unroll
        for (int r = 0; r < 4; ++r) {
            int row = wv * 16 + quad * 4 + r;
            int col = nf * 16 + m16;
            fs[row * 64 + col] = acc[nf][r] + (bias ? bias[nb + col] : 0.f);
        }
    __syncthreads();
#pragma unroll
    for (int i = 0; i < 4; ++i) {
        int u = i * 256 + tid;
        int row = u >> 4, c4 = u & 15;
        int grow = mb + row;
        if (grow < M)
            *(float4*)(Cf + (size_t)grow * N + nb + c4 * 4) = *(const float4*)(fs + (size_t)u * 4);
    }
    // folded BN stats: per-column sum/sumsq partials -> atomicAdd
    if (stats) {
        float* ps = (float*)(smem + 16384);   // [2][4][64]
        int col = tid & 63, qr = tid >> 6;
        int vr = M - mb; vr = vr < 64 ? vr : 64;
        int r0 = qr * 16, r1 = r0 + 16 < vr ? r0 + 16 : vr;
        float s = 0.f, q = 0.f;
        for (int r = r0; r < r1; ++r) { float v = fs[r * 64 + col]; s += v; q += v * v; }
        ps[qr * 64 + col] = s;
        ps[256 + qr * 64 + col] = q;
        __syncthreads();
        if (tid < 64) {
            float ss = ps[tid] + ps[64 + tid] + ps[128 + tid] + ps[192 + tid];
            atomicAdd(&stats[nb + tid], ss);
        } else if (tid < 128) {
            int c = tid - 64;
            float qq = ps[256 + c] + ps[320 + c] + ps[384 + c] + ps[448 + c];
            atomicAdd(&stats[128 + nb + c], qq);
        }
    }
}

// ---------------- GATv2 aggregate, per-head blocks, bucketed CSR ----------------
__global__ __launch_bounds__(256) void k_gat_h(const u32* __restrict__ XLb,
                                               const u32* __restrict__ XRb,
                                               const float* __restrict__ attc,
                                               const float* __restrict__ bias,
                                               const int* __restrict__ cnt,
                                               const int* __restrict__ col_src,
                                               u32* __restrict__ outb) {
    int h = blockIdx.y;
    const u32* XLh = XLb + (size_t)h * NN * 64;
    const u32* XRh = XRb + (size_t)h * NN * 64;
    int node = blockIdx.x * 4 + (threadIdx.x >> 6);
    int lane = threadIdx.x & 63;
    int g = lane >> 4, gl = lane & 15;

    f32x2 xr2[4], a6[4], acc2[4];
    const f32x2 c23 = {0.66666667f, 0.66666667f};
    up8f2(*(const uint4*)(XRh + (size_t)node * 64 + 4 * gl), xr2);
#pragma unroll
    for (int j = 0; j < 4; ++j) {
        a6[j] = *(const f32x2*)(attc + h * 128 + 8 * gl + 2 * j);
        acc2[j] = f32x2{0.f, 0.f};
    }
    float l = 0.f;

    int e0 = node << 6;
    int cntE = cnt[node];

    // issue first edge-index loads early
    int c0i = col_src[e0 + g];
    int c1i = col_src[e0 + g + 4];

    // self-loop contribution (group 0 only; whole 16-lane DPP row active)
    if (g == 0) {
        f32x2 xs[4];
        up8f2(*(const uint4*)(XLh + (size_t)node * 64 + 4 * gl), xs);
        f32x2 p2 = {0.f, 0.f};
#pragma unroll
        for (int j = 0; j < 4; ++j) {
            f32x2 v = pk_add(xs[j], xr2[j]);
            p2 = pk_fma(pk_fma(fabs2(v), c23, v), a6[j], p2);
        }
        float w = __builtin_amdgcn_exp2f(row_sum16(p2.x + p2.y));
        l = w;
        f32x2 w2 = {w, w};
#pragma unroll
        for (int j = 0; j < 4; ++j) acc2[j] = pk_fma(xs[j], w2, acc2[j]);
    }

    uint4 ua = *(const uint4*)(XLh + (size_t)c0i * 64 + 4 * gl);
    uint4 ub = *(const uint4*)(XLh + (size_t)c1i * 64 + 4 * gl);

    for (int t = g; t < cntE; t += 8) {
        uint4 un0 = *(const uint4*)(XLh + (size_t)col_src[e0 + t + 8] * 64 + 4 * gl);
        uint4 un1 = *(const uint4*)(XLh + (size_t)col_src[e0 + t + 12] * 64 + 4 * gl);

        f32x2 xa2[4], xb2[4];
        up8f2(ua, xa2); up8f2(ub, xb2);
        f32x2 pa2 = {0.f, 0.f}, pb2 = {0.f, 0.f};
#pragma unroll
        for (int j = 0; j < 4; ++j) {
            f32x2 va = pk_add(xa2[j], xr2[j]);
            f32x2 vb = pk_add(xb2[j], xr2[j]);
            pa2 = pk_fma(pk_fma(fabs2(va), c23, va), a6[j], pa2);
            pb2 = pk_fma(pk_fma(fabs2(vb), c23, vb), a6[j], pb2);
        }
        float pa = row_sum16(pa2.x + pa2.y);
        float pb = row_sum16(pb2.x + pb2.y);
        float wa = __builtin_amdgcn_exp2f(pa);
        float wb = ((t + 4) < cntE) ? __builtin_amdgcn_exp2f(pb) : 0.f;
        l += wa + wb;
        f32x2 wa2 = {wa, wa}, wb2 = {wb, wb};
#pragma unroll
        for (int j = 0; j < 4; ++j)
            acc2[j] = pk_fma(xa2[j], wa2, pk_fma(xb2[j], wb2, acc2[j]));

        ua = un0; ub = un1;
    }

#pragma unroll
    for (int o = 16; o <= 32; o <<= 1) {
        l += __shfl_xor(l, o);
#pragma unroll
        for (int j = 0; j < 4; ++j) {
            f32x2 s;
            s.x = __shfl_xor(acc2[j].x, o);
            s.y = __shfl_xor(acc2[j].y, o);
            acc2[j] = pk_add(acc2[j], s);
        }
    }

    if (g == 0) {
        float r = 1.f / l;
        float bv[8];
        *(float4*)&bv[0] = *(const float4*)&bias[h * 128 + 8 * gl];
        *(float4*)&bv[4] = *(const float4*)&bias[h * 128 + 8 * gl + 4];
        uint4 w;
        w.x = bf16_1(fmaf(acc2[0].x, r, bv[0])) | (bf16_1(fmaf(acc2[0].y, r, bv[1])) << 16);
        w.y = bf16_1(fmaf(acc2[1].x, r, bv[2])) | (bf16_1(fmaf(acc2[1].y, r, bv[3])) << 16);
        w.z = bf16_1(fmaf(acc2[2].x, r, bv[4])) | (bf16_1(fmaf(acc2[2].y, r, bv[5])) << 16);
        w.w = bf16_1(fmaf(acc2[3].x, r, bv[6])) | (bf16_1(fmaf(acc2[3].y, r, bv[7])) << 16);
        *(uint4*)(outb + (size_t)node * 384 + h * 64 + 4 * gl) = w;
    }
}

// ---------------- BN apply (stats pre-accumulated in the GEMM) ----------------
__global__ void k_bn_apply(float* __restrict__ y, const float* __restrict__ stats,
                           const float* __restrict__ g, const float* __restrict__ be,
                           u16* __restrict__ yb, int wf) {
    int i = blockIdx.x * 256 + threadIdx.x;
    if (i >= NN * DD / 8) return;
    int idx = i * 8;
    int c0 = idx & 127;
    float v[8];
    *(float4*)&v[0] = *(const float4*)(y + idx);
    *(float4*)&v[4] = *(const float4*)(y + idx + 4);
    const float minv = 1.f / (float)NN;
#pragma unroll
    for (int k = 0; k < 8; ++k) {
        int c = c0 + k;
        float mu = stats[c] * minv;
        float var = stats[128 + c] * minv - mu * mu;
        float sc = g[c] * rsqrtf(var + EPS);
        float sh = be[c] - mu * sc;
        v[k] = fmaxf(fmaf(v[k], sc, sh), 0.f);
    }
    if (wf) {
        *(float4*)(y + idx) = *(const float4*)&v[0];
        *(float4*)(y + idx + 4) = *(const float4*)&v[4];
    }
    if (yb) {
        uint4 w;
        w.x = bf16_1(v[0]) | (bf16_1(v[1]) << 16);
        w.y = bf16_1(v[2]) | (bf16_1(v[3]) << 16);
        w.z = bf16_1(v[4]) | (bf16_1(v[5]) << 16);
        w.w = bf16_1(v[6]) | (bf16_1(v[7]) << 16);
        *(uint4*)(yb + idx) = w;
    }
}

// ---------------- launch ----------------

extern "C" void kernel_launch(void* const* d_in, const int* in_sizes, int n_in,
                              void* d_out, int out_size, void* d_ws, size_t ws_size,
                              hipStream_t stream) {
    const float* x    = (const float*)d_in[0];
    const int*   ei   = (const int*)d_in[1];
    const float* Wl1  = (const float*)d_in[2];
    const float* bl1  = (const float*)d_in[3];
    const float* Wr1  = (const float*)d_in[4];
    const float* br1  = (const float*)d_in[5];
    const float* att1 = (const float*)d_in[6];
    const float* bc1  = (const float*)d_in[7];
    const float* g1   = (const float*)d_in[8];
    const float* be1  = (const float*)d_in[9];
    const float* Wl2  = (const float*)d_in[10];
    const float* bl2  = (const float*)d_in[11];
    const float* Wr2  = (const float*)d_in[12];
    const float* br2  = (const float*)d_in[13];
    const float* att2 = (const float*)d_in[14];
    const float* bc2  = (const float*)d_in[15];
    const float* g2   = (const float*)d_in[16];
    const float* be2  = (const float*)d_in[17];
    const float* W1   = (const float*)d_in[18];
    const float* b1   = (const float*)d_in[19];
    const float* W2   = (const float*)d_in[20];
    const float* b2   = (const float*)d_in[21];
    const int* esrc = ei;
    const int* edst = ei + NE;
    float* out = (float*)d_out;

    // ---- workspace layout (all regions 16B-aligned) ----
    float* bufD   = (float*)d_ws;          // mid fp32 [NN,128]      12.8 MB
    float* stats  = bufD + 3200000;        // 512 f (BN1 +0, BN2 +256)
    int* cnt      = (int*)(stats + 512);   // 25000 edge counters
    int* col_src  = cnt + 25000;           // [NN][64] buckets + 24 pad  6.4 MB
    float* fb1    = (float*)(col_src + 1600024);  // 768 fused bias L1
    float* fb2    = fb1 + 768;             // 768 fused bias L2
    float* attc1  = fb2 + 768;             // 384 pre-scaled att L1
    float* attc2  = attc1 + 384;           // 384 pre-scaled att L2
    u16* xb       = (u16*)(attc2 + 384);   // x bf16 [NN,128]         6.4 MB
    u16* XLb      = xb + 3200000;          // head-major xl [3][NN][128]  19.2 MB
    u16* XRb      = XLb + 3 * NN * 128;    // head-major xr [3][NN][128]
    u16* bufCat   = XRb + 3 * NN * 128;    // [NN,768] h2|x_in bf16  38.4 MB
    u16* bufDb    = bufCat + 19200000;     // h bf16 [NN,128]         6.4 MB
    u16* WfT1     = bufDb + 3200000;       // [768][128]
    u16* W1T      = WfT1 + 98304;          // [128][384]
    u16* WfT2     = W1T + 49152;           // [768][128]
    u16* W2T      = WfT2 + 98304;          // [128][768]

    // zero counters + buckets, then fused cast/transpose/bias/att/fill kernel
    hipMemsetAsync(cnt, 0, NN * sizeof(int), stream);
    hipMemsetAsync(col_src, 0, (NN * 64 + 24) * sizeof(int), stream);
    k_cast_all<<<(CAST_TOTAL + 255) / 256, 256, 0, stream>>>(
        x, Wl1, Wr1, W1, Wl2, Wr2, W2, bl1, br1, bl2, br2, att1, att2, esrc, edst,
        xb, WfT1, W1T, WfT2, W2T, fb1, fb2, attc1, attc2, cnt, col_src, stats);

    dim3 blk(256);
    dim3 gK((NN + 63) / 64);             // K=128 GEMM: 391 blocks, nb-loop inside
    dim3 g64(2, (NN + 63) / 64);         // BM=64 GEMMs: 782 blocks
    dim3 gGat((NN + 3) / 4, 3);          // gat: per-head blocks (L2 tiling)

    // layer 1
    k_gemm_k128<<<gK, blk, 0, stream>>>(xb, WfT1, fb1, XLb, NN);
    k_gat_h<<<gGat, blk, 0, stream>>>((const u32*)XLb, (const u32*)XRb, attc1, bc1,
                                      cnt, col_src, (u32*)bufCat + 192);

    // mid MLP (+BN stats folded) + BN apply
    k_gemm_bf<<<g64, blk, 0, stream>>>(bufCat + 384, W1T, b1, bufD, stats, NN, DD, HD, 768);
    k_bn_apply<<<(NN * DD / 8 + 255) / 256, 256, 0, stream>>>(bufD, stats, g1, be1, bufDb, 0);

    // layer 2
    k_gemm_k128<<<gK, blk, 0, stream>>>(bufDb, WfT2, fb2, XLb, NN);
    k_gat_h<<<gGat, blk, 0, stream>>>((const u32*)XLb, (const u32*)XRb, attc2, bc2,
                                      cnt, col_src, (u32*)bufCat);

    // final GEMM (+BN stats folded) + BN apply
    k_gemm_bf<<<g64, blk, 0, stream>>>(bufCat, W2T, b2, out, stats + 256, NN, DD, 768, 768);
    k_bn_apply<<<(NN * DD / 8 + 255) / 256, 256, 0, stream>>>(out, stats + 256, g2, be2, nullptr, 1);
}

// Round 7
// 330.892 us; speedup vs baseline: 1.2586x; 1.0224x over previous
//
#include <hip/hip_runtime.h>
#include <math.h>

#define NN 25000      // nodes
#define NE 400000     // edges
#define DD 128        // hidden dim
#define HD 384        // heads * dim
#define NEG 0.2f
#define EPS 1e-5f

typedef unsigned int u32;
typedef unsigned short u16;
typedef __attribute__((ext_vector_type(8))) short short8;   // 8 bf16 (4 VGPRs)
typedef __attribute__((ext_vector_type(4))) float floatx4;  // MFMA accumulator
typedef __attribute__((ext_vector_type(2))) float f32x2;    // packed-f32 pair

// ---- bf16 helpers (RNE) ----
__device__ __forceinline__ u32 bf16_1(float x) {
    u32 u = __float_as_uint(x);
    return (u + 0x7fffu + ((u >> 16) & 1u)) >> 16;
}
__device__ __forceinline__ float blo(u32 u) { return __uint_as_float(u << 16); }
__device__ __forceinline__ float bhi(u32 u) { return __uint_as_float(u & 0xffff0000u); }

__device__ __forceinline__ void up8f2(uint4 u, f32x2* f) {
    f[0] = f32x2{blo(u.x), bhi(u.x)};
    f[1] = f32x2{blo(u.y), bhi(u.y)};
    f[2] = f32x2{blo(u.z), bhi(u.z)};
    f[3] = f32x2{blo(u.w), bhi(u.w)};
}

// ---- packed f32 ops (CDNA v_pk_*, 2 f32 lanes / inst) ----
__device__ __forceinline__ f32x2 pk_add(f32x2 a, f32x2 b) {
    f32x2 d; asm("v_pk_add_f32 %0, %1, %2" : "=v"(d) : "v"(a), "v"(b)); return d;
}
__device__ __forceinline__ f32x2 pk_fma(f32x2 a, f32x2 b, f32x2 c) {
    f32x2 d; asm("v_pk_fma_f32 %0, %1, %2, %3" : "=v"(d) : "v"(a), "v"(b), "v"(c)); return d;
}
__device__ __forceinline__ f32x2 fabs2(f32x2 v) {
    u32 a = __float_as_uint(v.x) & 0x7fffffffu;
    u32 b = __float_as_uint(v.y) & 0x7fffffffu;
    return f32x2{__uint_as_float(a), __uint_as_float(b)};
}

// ---- 16-lane (DPP row) rotate-reduce: every lane gets the row total ----
__device__ __forceinline__ float row_sum16(float x) {
    int t;
    t = __builtin_amdgcn_update_dpp(0, __float_as_int(x), 0x121, 0xf, 0xf, false);
    x += __int_as_float(t);
    t = __builtin_amdgcn_update_dpp(0, __float_as_int(x), 0x122, 0xf, 0xf, false);
    x += __int_as_float(t);
    t = __builtin_amdgcn_update_dpp(0, __float_as_int(x), 0x124, 0xf, 0xf, false);
    x += __int_as_float(t);
    t = __builtin_amdgcn_update_dpp(0, __float_as_int(x), 0x128, 0xf, 0xf, false);
    x += __int_as_float(t);
    return x;
}

// ---------------- one cast/init kernel (bucket fill folded in) ----------------
// cnt and col_src pre-zeroed by memsets. Bucketed CSR: col_src[dst*64 + p].
__global__ void k_cast_all(const float* __restrict__ x,
                           const float* __restrict__ Wl1, const float* __restrict__ Wr1,
                           const float* __restrict__ W1,
                           const float* __restrict__ Wl2, const float* __restrict__ Wr2,
                           const float* __restrict__ W2,
                           const float* __restrict__ bl1, const float* __restrict__ br1,
                           const float* __restrict__ bl2, const float* __restrict__ br2,
                           const float* __restrict__ att1, const float* __restrict__ att2,
                           const int* __restrict__ esrc, const int* __restrict__ edst,
                           u16* __restrict__ xb, u16* __restrict__ WfT1,
                           u16* __restrict__ W1T, u16* __restrict__ WfT2,
                           u16* __restrict__ W2T,
                           float* __restrict__ fb1, float* __restrict__ fb2,
                           float* __restrict__ attc1, float* __restrict__ attc2,
                           int* __restrict__ cnt, int* __restrict__ col_src,
                           float* __restrict__ stats) {
    int i = blockIdx.x * 256 + threadIdx.x;
    if (i < 400000) {   // x cast, 8 elems/thread, coalesced 16B writes
        const float4* xp = (const float4*)(x + (size_t)i * 8);
        float4 a = xp[0], b = xp[1];
        uint4 w;
        w.x = bf16_1(a.x) | (bf16_1(a.y) << 16);
        w.y = bf16_1(a.z) | (bf16_1(a.w) << 16);
        w.z = bf16_1(b.x) | (bf16_1(b.y) << 16);
        w.w = bf16_1(b.z) | (bf16_1(b.w) << 16);
        *(uint4*)(xb + (size_t)i * 8) = w;
        return;
    }
    i -= 400000;
    if (i < 400000) {   // bucketed edge fill (one atomic per edge)
        int d = edst[i];
        int p = atomicAdd(&cnt[d], 1);
        col_src[(d << 6) + p] = esrc[i];
        return;
    }
    i -= 400000;
    if (i < 49152) { int k = i / 384, n = i - k * 384; WfT1[n * 128 + k] = (u16)bf16_1(Wl1[i]); return; }
    i -= 49152;
    if (i < 49152) { int k = i / 384, n = i - k * 384; WfT1[(384 + n) * 128 + k] = (u16)bf16_1(Wr1[i]); return; }
    i -= 49152;
    if (i < 49152) { int k = i / 128, n = i - k * 128; W1T[n * 384 + k] = (u16)bf16_1(W1[i]); return; }
    i -= 49152;
    if (i < 49152) { int k = i / 384, n = i - k * 384; WfT2[n * 128 + k] = (u16)bf16_1(Wl2[i]); return; }
    i -= 49152;
    if (i < 49152) { int k = i / 384, n = i - k * 384; WfT2[(384 + n) * 128 + k] = (u16)bf16_1(Wr2[i]); return; }
    i -= 49152;
    if (i < 98304) { int k = i / 128, n = i - k * 128; W2T[n * 768 + k] = (u16)bf16_1(W2[i]); return; }
    i -= 98304;
    if (i < 768) { fb1[i] = (i < 384) ? bl1[i] : br1[i - 384]; return; }
    i -= 768;
    if (i < 768) { fb2[i] = (i < 384) ? bl2[i] : br2[i - 384]; return; }
    i -= 768;
    // pre-scaled attention vectors: 0.6 * log2(e) * att
    if (i < 384) { attc1[i] = att1[i] * 0.86561702f; return; }
    i -= 384;
    if (i < 384) { attc2[i] = att2[i] * 0.86561702f; return; }
    i -= 384;
    if (i < 512) stats[i] = 0.f;
}
#define CAST_TOTAL (400000 + 400000 + 5 * 49152 + 98304 + 1536 + 768 + 512)

// ---------------- K=128 single-shot GEMM (layer-1 xl|xr transform) ----------------
// grid (3, 391): each block stages A once, loops 2 N-tiles. 1173 blocks
// (4.6/CU wanted, 3 resident at 48 KB LDS) — balance vs A-refetch compromise
// (R6's 391-block 6-tile loop was balance-starved at 1.5 blocks/CU).
__global__ __launch_bounds__(256) void k_gemm_k128(
        const u16* __restrict__ A, const u16* __restrict__ BT,
        const float* __restrict__ bias, u16* __restrict__ Cb, int M) {
    __shared__ short sA[64 * 128];    // 16 KB
    __shared__ short sB[128 * 128];   // 32 KB
    int tid = threadIdx.x;
    int wv = tid >> 6, lane = tid & 63;
    int quad = lane >> 4, m16 = lane & 15;
    int mb = blockIdx.y * 64;

    // stage A once (drained by the barrier after the first B stage)
#pragma unroll
    for (int j = 0; j < 4; ++j) {
        int L = j * 256 + tid;
        int r = L >> 4, c8 = (L & 15) ^ (r & 15);
        int gr = mb + r; gr = gr < M ? gr : M - 1;
        __builtin_amdgcn_global_load_lds(
            (const __attribute__((address_space(1))) void*)(A + (size_t)gr * 128 + c8 * 8),
            (__attribute__((address_space(3))) void*)(sA + (size_t)L * 8), 16, 0, 0);
    }

    for (int j2 = 0; j2 < 2; ++j2) {
        int nb = blockIdx.x * 256 + j2 * 128;
        __syncthreads();   // protect sB from prior iteration's store-reads
#pragma unroll
        for (int j = 0; j < 8; ++j) {
            int L = j * 256 + tid;
            int r = L >> 4, c8 = (L & 15) ^ (r & 15);
            __builtin_amdgcn_global_load_lds(
                (const __attribute__((address_space(1))) void*)(BT + (size_t)(nb + r) * 128 + c8 * 8),
                (__attribute__((address_space(3))) void*)(sB + (size_t)L * 8), 16, 0, 0);
        }
        __syncthreads();   // sA (first iter) + sB staged

        floatx4 acc[8];
#pragma unroll
        for (int nf = 0; nf < 8; ++nf)
#pragma unroll
            for (int r = 0; r < 4; ++r) acc[nf][r] = 0.f;

#pragma unroll
        for (int ks = 0; ks < 4; ++ks) {
            int slot = (ks * 4 + quad) ^ m16;
            short8 a0 = *(const short8*)(sA + ((size_t)(wv * 16 + m16) * 16 + slot) * 8);
#pragma unroll
            for (int nf = 0; nf < 8; ++nf) {
                short8 b = *(const short8*)(sB + ((size_t)(nf * 16 + m16) * 16 + slot) * 8);
                acc[nf] = __builtin_amdgcn_mfma_f32_16x16x32_bf16(a0, b, acc[nf], 0, 0, 0);
            }
        }
        __syncthreads();   // all MFMA reads of sB done

        // repack 64x128 bf16 output tile into sB (+bias)
#pragma unroll
        for (int nf = 0; nf < 8; ++nf)
#pragma unroll
            for (int r = 0; r < 4; ++r) {
                int row = wv * 16 + quad * 4 + r;
                int col = nf * 16 + m16;
                sB[row * 128 + col] = (short)bf16_1(acc[nf][r] + bias[nb + col]);
            }
        __syncthreads();

        int xr = nb >= 384;
        int h = (xr ? (nb - 384) : nb) >> 7;
        u16* cb = Cb + ((size_t)(xr * 3 + h) * NN) * 128;
#pragma unroll
        for (int i = 0; i < 4; ++i) {
            int u = i * 256 + tid;
            int row = u >> 4, c8 = u & 15;
            int grow = mb + row;
            if (grow < M)
                *(uint4*)(cb + (size_t)grow * 128 + c8 * 8) = *(const uint4*)(sB + (size_t)u * 8);
        }
    }
}

// ---------------- K=128 GEMM with fused BN1-apply on A (layer-2 transform) ----------------
// A = bufD fp32 [NN][128]; per-column BN (stats complete: stream-ordered after
// the mid GEMM) + ReLU + bf16 cast applied in registers during reg-staging.
// Replaces the separate k_bn_apply pass + bufDb round-trip. Same swizzled LDS
// granule layout as global_load_lds staging: slot = r*16 + (c8 ^ (r&15)).
__global__ __launch_bounds__(256) void k_gemm_k128_bn(
        const float* __restrict__ Af, const float* __restrict__ stats,
        const float* __restrict__ gg, const float* __restrict__ be,
        const u16* __restrict__ BT,
        const float* __restrict__ bias, u16* __restrict__ Cb, int M) {
    __shared__ short sA[64 * 128];    // 16 KB
    __shared__ short sB[128 * 128];   // 32 KB
    int tid = threadIdx.x;
    int wv = tid >> 6, lane = tid & 63;
    int quad = lane >> 4, m16 = lane & 15;
    int mb = blockIdx.y * 64;

    // BN scale/shift for this thread's fixed 8 columns (c8 = tid&15)
    int c8t = tid & 15;
    const float minv = 1.f / (float)NN;
    float sc[8], sh[8];
#pragma unroll
    for (int k = 0; k < 8; ++k) {
        int c = c8t * 8 + k;
        float mu = stats[c] * minv;
        float var = stats[128 + c] * minv - mu * mu;
        float s = gg[c] * rsqrtf(var + EPS);
        sc[k] = s;
        sh[k] = be[c] - mu * s;
    }
    // reg-stage A: load fp32, BN+ReLU, cast bf16, swizzled ds_write
#pragma unroll
    for (int j = 0; j < 4; ++j) {
        int L = j * 256 + tid;
        int r = L >> 4;
        int gr = mb + r; gr = gr < M ? gr : M - 1;
        const float* ap = Af + (size_t)gr * 128 + c8t * 8;
        float4 a = *(const float4*)ap;
        float4 b = *(const float4*)(ap + 4);
        float v[8] = {a.x, a.y, a.z, a.w, b.x, b.y, b.z, b.w};
        u32 pk[4];
#pragma unroll
        for (int k = 0; k < 4; ++k) {
            u32 lo = bf16_1(fmaxf(fmaf(v[2 * k], sc[2 * k], sh[2 * k]), 0.f));
            u32 hi = bf16_1(fmaxf(fmaf(v[2 * k + 1], sc[2 * k + 1], sh[2 * k + 1]), 0.f));
            pk[k] = lo | (hi << 16);
        }
        uint4 w = {pk[0], pk[1], pk[2], pk[3]};
        *(uint4*)(sA + ((size_t)(r * 16 + (c8t ^ (r & 15)))) * 8) = w;
    }

    for (int j2 = 0; j2 < 2; ++j2) {
        int nb = blockIdx.x * 256 + j2 * 128;
        __syncthreads();   // protect sB reuse; (iter0: also orders sA ds_writes)
#pragma unroll
        for (int j = 0; j < 8; ++j) {
            int L = j * 256 + tid;
            int r = L >> 4, c8 = (L & 15) ^ (r & 15);
            __builtin_amdgcn_global_load_lds(
                (const __attribute__((address_space(1))) void*)(BT + (size_t)(nb + r) * 128 + c8 * 8),
                (__attribute__((address_space(3))) void*)(sB + (size_t)L * 8), 16, 0, 0);
        }
        __syncthreads();   // sA + sB staged

        floatx4 acc[8];
#pragma unroll
        for (int nf = 0; nf < 8; ++nf)
#pragma unroll
            for (int r = 0; r < 4; ++r) acc[nf][r] = 0.f;

#pragma unroll
        for (int ks = 0; ks < 4; ++ks) {
            int slot = (ks * 4 + quad) ^ m16;
            short8 a0 = *(const short8*)(sA + ((size_t)(wv * 16 + m16) * 16 + slot) * 8);
#pragma unroll
            for (int nf = 0; nf < 8; ++nf) {
                short8 b = *(const short8*)(sB + ((size_t)(nf * 16 + m16) * 16 + slot) * 8);
                acc[nf] = __builtin_amdgcn_mfma_f32_16x16x32_bf16(a0, b, acc[nf], 0, 0, 0);
            }
        }
        __syncthreads();

#pragma unroll
        for (int nf = 0; nf < 8; ++nf)
#pragma unroll
            for (int r = 0; r < 4; ++r) {
                int row = wv * 16 + quad * 4 + r;
                int col = nf * 16 + m16;
                sB[row * 128 + col] = (short)bf16_1(acc[nf][r] + bias[nb + col]);
            }
        __syncthreads();

        int xr = nb >= 384;
        int h = (xr ? (nb - 384) : nb) >> 7;
        u16* cb = Cb + ((size_t)(xr * 3 + h) * NN) * 128;
#pragma unroll
        for (int i = 0; i < 4; ++i) {
            int u = i * 256 + tid;
            int row = u >> 4, c8 = u & 15;
            int grow = mb + row;
            if (grow < M)
                *(uint4*)(cb + (size_t)grow * 128 + c8 * 8) = *(const uint4*)(sB + (size_t)u * 8);
        }
    }
}

// ---------------- bf16 MFMA GEMM (K-loop, BK=128): C[M,N] = A[M,K] @ BT[N,K]^T ----------------
__global__ __launch_bounds__(256) void k_gemm_bf(
        const u16* __restrict__ A, const u16* __restrict__ BT,
        const float* __restrict__ bias,
        float* __restrict__ Cf, float* __restrict__ stats,
        int M, int N, int K, int lda) {
    __shared__ short smem[17408];   // 34 KB: sA 16K + sB 16K + stat partials 2K
    short* sA = smem;               // 64 x 128
    short* sB = smem + 8192;        // 64 x 128
    int tid = threadIdx.x;
    int wv = tid >> 6, lane = tid & 63;
    int quad = lane >> 4, m16 = lane & 15;
    int mb = blockIdx.y * 64, nb = blockIdx.x * 64;

    floatx4 acc[4];
#pragma unroll
    for (int nf = 0; nf < 4; ++nf)
#pragma unroll
        for (int r = 0; r < 4; ++r) acc[nf][r] = 0.f;

    for (int k0 = 0; k0 < K; k0 += 128) {
#pragma unroll
        for (int j = 0; j < 4; ++j) {
            int L = j * 256 + tid;
            int r = L >> 4, c8 = (L & 15) ^ (r & 15);
            int gr = mb + r; gr = gr < M ? gr : M - 1;
            __builtin_amdgcn_global_load_lds(
                (const __attribute__((address_space(1))) void*)(A + (size_t)gr * lda + k0 + c8 * 8),
                (__attribute__((address_space(3))) void*)(sA + (size_t)L * 8), 16, 0, 0);
        }
#pragma unroll
        for (int j = 0; j < 4; ++j) {
            int L = j * 256 + tid;
            int r = L >> 4, c8 = (L & 15) ^ (r & 15);
            __builtin_amdgcn_global_load_lds(
                (const __attribute__((address_space(1))) void*)(BT + (size_t)(nb + r) * K + k0 + c8 * 8),
                (__attribute__((address_space(3))) void*)(sB + (size_t)L * 8), 16, 0, 0);
        }
        __syncthreads();
#pragma unroll
        for (int ks = 0; ks < 4; ++ks) {
            int slot = (ks * 4 + quad) ^ m16;
            short8 a0 = *(const short8*)(sA + ((size_t)(wv * 16 + m16) * 16 + slot) * 8);
#pragma unroll
            for (int nf = 0; nf < 4; ++nf) {
                short8 b = *(const short8*)(sB + ((size_t)(nf * 16 + m16) * 16 + slot) * 8);
                acc[nf] = __builtin_amdgcn_mfma_f32_16x16x32_bf16(a0, b, acc[nf], 0, 0, 0);
            }
        }
        __syncthreads();
    }
    // fp32 tile [64][64] staged in LDS (16 KB), coalesced float4 stores
    float* fs = (float*)smem;
#pragma unroll
    for (int nf = 0; nf < 4; ++nf)
#pragma unroll
        for (int r = 0; r < 4; ++r) {
            int row = wv * 16 + quad * 4 + r;
            int col = nf * 16 + m16;
            fs[row * 64 + col] = acc[nf][r] + (bias ? bias[nb + col] : 0.f);
        }
    __syncthreads();
#pragma unroll
    for (int i = 0; i < 4; ++i) {
        int u = i * 256 + tid;
        int row = u >> 4, c4 = u & 15;
        int grow = mb + row;
        if (grow < M)
            *(float4*)(Cf + (size_t)grow * N + nb + c4 * 4) = *(const float4*)(fs + (size_t)u * 4);
    }
    // folded BN stats: per-column sum/sumsq partials -> atomicAdd
    if (stats) {
        float* ps = (float*)(smem + 16384);   // [2][4][64]
        int col = tid & 63, qr = tid >> 6;
        int vr = M - mb; vr = vr < 64 ? vr : 64;
        int r0 = qr * 16, r1 = r0 + 16 < vr ? r0 + 16 : vr;
        float s = 0.f, q = 0.f;
        for (int r = r0; r < r1; ++r) { float v = fs[r * 64 + col]; s += v; q += v * v; }
        ps[qr * 64 + col] = s;
        ps[256 + qr * 64 + col] = q;
        __syncthreads();
        if (tid < 64) {
            float ss = ps[tid] + ps[64 + tid] + ps[128 + tid] + ps[192 + tid];
            atomicAdd(&stats[nb + tid], ss);
        } else if (tid < 128) {
            int c = tid - 64;
            float qq = ps[256 + c] + ps[320 + c] + ps[384 + c] + ps[448 + c];
            atomicAdd(&stats[128 + nb + c], qq);
        }
    }
}

// ---------------- GATv2 aggregate, per-head blocks, bucketed CSR ----------------
__global__ __launch_bounds__(256) void k_gat_h(const u32* __restrict__ XLb,
                                               const u32* __restrict__ XRb,
                                               const float* __restrict__ attc,
                                               const float* __restrict__ bias,
                                               const int* __restrict__ cnt,
                                               const int* __restrict__ col_src,
                                               u32* __restrict__ outb) {
    int h = blockIdx.y;
    const u32* XLh = XLb + (size_t)h * NN * 64;
    const u32* XRh = XRb + (size_t)h * NN * 64;
    int node = blockIdx.x * 4 + (threadIdx.x >> 6);
    int lane = threadIdx.x & 63;
    int g = lane >> 4, gl = lane & 15;

    f32x2 xr2[4], a6[4], acc2[4];
    const f32x2 c23 = {0.66666667f, 0.66666667f};
    up8f2(*(const uint4*)(XRh + (size_t)node * 64 + 4 * gl), xr2);
#pragma unroll
    for (int j = 0; j < 4; ++j) {
        a6[j] = *(const f32x2*)(attc + h * 128 + 8 * gl + 2 * j);
        acc2[j] = f32x2{0.f, 0.f};
    }
    float l = 0.f;

    int e0 = node << 6;
    int cntE = cnt[node];

    // issue first edge-index loads early
    int c0i = col_src[e0 + g];
    int c1i = col_src[e0 + g + 4];

    // self-loop contribution (group 0 only; whole 16-lane DPP row active)
    if (g == 0) {
        f32x2 xs[4];
        up8f2(*(const uint4*)(XLh + (size_t)node * 64 + 4 * gl), xs);
        f32x2 p2 = {0.f, 0.f};
#pragma unroll
        for (int j = 0; j < 4; ++j) {
            f32x2 v = pk_add(xs[j], xr2[j]);
            p2 = pk_fma(pk_fma(fabs2(v), c23, v), a6[j], p2);
        }
        float w = __builtin_amdgcn_exp2f(row_sum16(p2.x + p2.y));
        l = w;
        f32x2 w2 = {w, w};
#pragma unroll
        for (int j = 0; j < 4; ++j) acc2[j] = pk_fma(xs[j], w2, acc2[j]);
    }

    uint4 ua = *(const uint4*)(XLh + (size_t)c0i * 64 + 4 * gl);
    uint4 ub = *(const uint4*)(XLh + (size_t)c1i * 64 + 4 * gl);

    for (int t = g; t < cntE; t += 8) {
        uint4 un0 = *(const uint4*)(XLh + (size_t)col_src[e0 + t + 8] * 64 + 4 * gl);
        uint4 un1 = *(const uint4*)(XLh + (size_t)col_src[e0 + t + 12] * 64 + 4 * gl);

        f32x2 xa2[4], xb2[4];
        up8f2(ua, xa2); up8f2(ub, xb2);
        f32x2 pa2 = {0.f, 0.f}, pb2 = {0.f, 0.f};
#pragma unroll
        for (int j = 0; j < 4; ++j) {
            f32x2 va = pk_add(xa2[j], xr2[j]);
            f32x2 vb = pk_add(xb2[j], xr2[j]);
            pa2 = pk_fma(pk_fma(fabs2(va), c23, va), a6[j], pa2);
            pb2 = pk_fma(pk_fma(fabs2(vb), c23, vb), a6[j], pb2);
        }
        float pa = row_sum16(pa2.x + pa2.y);
        float pb = row_sum16(pb2.x + pb2.y);
        float wa = __builtin_amdgcn_exp2f(pa);
        float wb = ((t + 4) < cntE) ? __builtin_amdgcn_exp2f(pb) : 0.f;
        l += wa + wb;
        f32x2 wa2 = {wa, wa}, wb2 = {wb, wb};
#pragma unroll
        for (int j = 0; j < 4; ++j)
            acc2[j] = pk_fma(xa2[j], wa2, pk_fma(xb2[j], wb2, acc2[j]));

        ua = un0; ub = un1;
    }

#pragma unroll
    for (int o = 16; o <= 32; o <<= 1) {
        l += __shfl_xor(l, o);
#pragma unroll
        for (int j = 0; j < 4; ++j) {
            f32x2 s;
            s.x = __shfl_xor(acc2[j].x, o);
            s.y = __shfl_xor(acc2[j].y, o);
            acc2[j] = pk_add(acc2[j], s);
        }
    }

    if (g == 0) {
        float r = 1.f / l;
        float bv[8];
        *(float4*)&bv[0] = *(const float4*)&bias[h * 128 + 8 * gl];
        *(float4*)&bv[4] = *(const float4*)&bias[h * 128 + 8 * gl + 4];
        uint4 w;
        w.x = bf16_1(fmaf(acc2[0].x, r, bv[0])) | (bf16_1(fmaf(acc2[0].y, r, bv[1])) << 16);
        w.y = bf16_1(fmaf(acc2[1].x, r, bv[2])) | (bf16_1(fmaf(acc2[1].y, r, bv[3])) << 16);
        w.z = bf16_1(fmaf(acc2[2].x, r, bv[4])) | (bf16_1(fmaf(acc2[2].y, r, bv[5])) << 16);
        w.w = bf16_1(fmaf(acc2[3].x, r, bv[6])) | (bf16_1(fmaf(acc2[3].y, r, bv[7])) << 16);
        *(uint4*)(outb + (size_t)node * 384 + h * 64 + 4 * gl) = w;
    }
}

// ---------------- BN apply (final output only) ----------------
__global__ void k_bn_apply(float* __restrict__ y, const float* __restrict__ stats,
                           const float* __restrict__ g, const float* __restrict__ be,
                           u16* __restrict__ yb, int wf) {
    int i = blockIdx.x * 256 + threadIdx.x;
    if (i >= NN * DD / 8) return;
    int idx = i * 8;
    int c0 = idx & 127;
    float v[8];
    *(float4*)&v[0] = *(const float4*)(y + idx);
    *(float4*)&v[4] = *(const float4*)(y + idx + 4);
    const float minv = 1.f / (float)NN;
#pragma unroll
    for (int k = 0; k < 8; ++k) {
        int c = c0 + k;
        float mu = stats[c] * minv;
        float var = stats[128 + c] * minv - mu * mu;
        float sc = g[c] * rsqrtf(var + EPS);
        float sh = be[c] - mu * sc;
        v[k] = fmaxf(fmaf(v[k], sc, sh), 0.f);
    }
    if (wf) {
        *(float4*)(y + idx) = *(const float4*)&v[0];
        *(float4*)(y + idx + 4) = *(const float4*)&v[4];
    }
    if (yb) {
        uint4 w;
        w.x = bf16_1(v[0]) | (bf16_1(v[1]) << 16);
        w.y = bf16_1(v[2]) | (bf16_1(v[3]) << 16);
        w.z = bf16_1(v[4]) | (bf16_1(v[5]) << 16);
        w.w = bf16_1(v[6]) | (bf16_1(v[7]) << 16);
        *(uint4*)(yb + idx) = w;
    }
}

// ---------------- launch ----------------

extern "C" void kernel_launch(void* const* d_in, const int* in_sizes, int n_in,
                              void* d_out, int out_size, void* d_ws, size_t ws_size,
                              hipStream_t stream) {
    const float* x    = (const float*)d_in[0];
    const int*   ei   = (const int*)d_in[1];
    const float* Wl1  = (const float*)d_in[2];
    const float* bl1  = (const float*)d_in[3];
    const float* Wr1  = (const float*)d_in[4];
    const float* br1  = (const float*)d_in[5];
    const float* att1 = (const float*)d_in[6];
    const float* bc1  = (const float*)d_in[7];
    const float* g1   = (const float*)d_in[8];
    const float* be1  = (const float*)d_in[9];
    const float* Wl2  = (const float*)d_in[10];
    const float* bl2  = (const float*)d_in[11];
    const float* Wr2  = (const float*)d_in[12];
    const float* br2  = (const float*)d_in[13];
    const float* att2 = (const float*)d_in[14];
    const float* bc2  = (const float*)d_in[15];
    const float* g2   = (const float*)d_in[16];
    const float* be2  = (const float*)d_in[17];
    const float* W1   = (const float*)d_in[18];
    const float* b1   = (const float*)d_in[19];
    const float* W2   = (const float*)d_in[20];
    const float* b2   = (const float*)d_in[21];
    const int* esrc = ei;
    const int* edst = ei + NE;
    float* out = (float*)d_out;

    // ---- workspace layout (all regions 16B-aligned) ----
    float* bufD   = (float*)d_ws;          // mid fp32 [NN,128]      12.8 MB
    float* stats  = bufD + 3200000;        // 512 f (BN1 +0, BN2 +256)
    int* cnt      = (int*)(stats + 512);   // 25000 edge counters
    int* col_src  = cnt + 25000;           // [NN][64] buckets + 24 pad  6.4 MB
    float* fb1    = (float*)(col_src + 1600024);  // 768 fused bias L1
    float* fb2    = fb1 + 768;             // 768 fused bias L2
    float* attc1  = fb2 + 768;             // 384 pre-scaled att L1
    float* attc2  = attc1 + 384;           // 384 pre-scaled att L2
    u16* xb       = (u16*)(attc2 + 384);   // x bf16 [NN,128]         6.4 MB
    u16* XLb      = xb + 3200000;          // head-major xl [3][NN][128]  19.2 MB
    u16* XRb      = XLb + 3 * NN * 128;    // head-major xr [3][NN][128]
    u16* bufCat   = XRb + 3 * NN * 128;    // [NN,768] h2|x_in bf16  38.4 MB
    u16* WfT1     = bufCat + 19200000;     // [768][128]
    u16* W1T      = WfT1 + 98304;          // [128][384]
    u16* WfT2     = W1T + 49152;           // [768][128]
    u16* W2T      = WfT2 + 98304;          // [128][768]

    // zero counters + buckets, then fused cast/transpose/bias/att/fill kernel
    hipMemsetAsync(cnt, 0, NN * sizeof(int), stream);
    hipMemsetAsync(col_src, 0, (NN * 64 + 24) * sizeof(int), stream);
    k_cast_all<<<(CAST_TOTAL + 255) / 256, 256, 0, stream>>>(
        x, Wl1, Wr1, W1, Wl2, Wr2, W2, bl1, br1, bl2, br2, att1, att2, esrc, edst,
        xb, WfT1, W1T, WfT2, W2T, fb1, fb2, attc1, attc2, cnt, col_src, stats);

    dim3 blk(256);
    dim3 gK(3, (NN + 63) / 64);          // K=128 GEMMs: 1173 blocks, 2-tile loop
    dim3 g64(2, (NN + 63) / 64);         // BM=64 GEMMs: 782 blocks
    dim3 gGat((NN + 3) / 4, 3);          // gat: per-head blocks (L2 tiling)

    // layer 1
    k_gemm_k128<<<gK, blk, 0, stream>>>(xb, WfT1, fb1, XLb, NN);
    k_gat_h<<<gGat, blk, 0, stream>>>((const u32*)XLb, (const u32*)XRb, attc1, bc1,
                                      cnt, col_src, (u32*)bufCat + 192);

    // mid MLP (+BN stats folded); BN1-apply fused into the layer-2 transform
    k_gemm_bf<<<g64, blk, 0, stream>>>(bufCat + 384, W1T, b1, bufD, stats, NN, DD, HD, 768);

    // layer 2 (A = bufD fp32, BN1+ReLU+cast fused into staging)
    k_gemm_k128_bn<<<gK, blk, 0, stream>>>(bufD, stats, g1, be1, WfT2, fb2, XLb, NN);
    k_gat_h<<<gGat, blk, 0, stream>>>((const u32*)XLb, (const u32*)XRb, attc2, bc2,
                                      cnt, col_src, (u32*)bufCat);

    // final GEMM (+BN stats folded) + BN apply
    k_gemm_bf<<<g64, blk, 0, stream>>>(bufCat, W2T, b2, out, stats + 256, NN, DD, 768, 768);
    k_bn_apply<<<(NN * DD / 8 + 255) / 256, 256, 0, stream>>>(out, stats + 256, g2, be2, nullptr, 1);
}

// Round 9
// 328.986 us; speedup vs baseline: 1.2659x; 1.0058x over previous
//
#include <hip/hip_runtime.h>
#include <math.h>

#define NN 25000      // nodes
#define NE 400000     // edges
#define DD 128        // hidden dim
#define HD 384        // heads * dim
#define NEG 0.2f
#define EPS 1e-5f

typedef unsigned int u32;
typedef unsigned short u16;
typedef __attribute__((ext_vector_type(8))) short short8;   // 8 bf16 (4 VGPRs)
typedef __attribute__((ext_vector_type(4))) float floatx4;  // MFMA accumulator
typedef __attribute__((ext_vector_type(2))) float f32x2;    // packed-f32 pair

// ---- bf16 helpers (RNE) ----
__device__ __forceinline__ u32 bf16_1(float x) {
    u32 u = __float_as_uint(x);
    return (u + 0x7fffu + ((u >> 16) & 1u)) >> 16;
}
__device__ __forceinline__ float blo(u32 u) { return __uint_as_float(u << 16); }
__device__ __forceinline__ float bhi(u32 u) { return __uint_as_float(u & 0xffff0000u); }

__device__ __forceinline__ void up8f2(uint4 u, f32x2* f) {
    f[0] = f32x2{blo(u.x), bhi(u.x)};
    f[1] = f32x2{blo(u.y), bhi(u.y)};
    f[2] = f32x2{blo(u.z), bhi(u.z)};
    f[3] = f32x2{blo(u.w), bhi(u.w)};
}

// ---- packed f32 ops (CDNA v_pk_*, 2 f32 lanes / inst) ----
__device__ __forceinline__ f32x2 pk_add(f32x2 a, f32x2 b) {
    f32x2 d; asm("v_pk_add_f32 %0, %1, %2" : "=v"(d) : "v"(a), "v"(b)); return d;
}
__device__ __forceinline__ f32x2 pk_fma(f32x2 a, f32x2 b, f32x2 c) {
    f32x2 d; asm("v_pk_fma_f32 %0, %1, %2, %3" : "=v"(d) : "v"(a), "v"(b), "v"(c)); return d;
}
__device__ __forceinline__ f32x2 fabs2(f32x2 v) {
    u32 a = __float_as_uint(v.x) & 0x7fffffffu;
    u32 b = __float_as_uint(v.y) & 0x7fffffffu;
    return f32x2{__uint_as_float(a), __uint_as_float(b)};
}

// ---- 16-lane (DPP row) rotate-reduce: every lane gets the row total ----
__device__ __forceinline__ float row_sum16(float x) {
    int t;
    t = __builtin_amdgcn_update_dpp(0, __float_as_int(x), 0x121, 0xf, 0xf, false);
    x += __int_as_float(t);
    t = __builtin_amdgcn_update_dpp(0, __float_as_int(x), 0x122, 0xf, 0xf, false);
    x += __int_as_float(t);
    t = __builtin_amdgcn_update_dpp(0, __float_as_int(x), 0x124, 0xf, 0xf, false);
    x += __int_as_float(t);
    t = __builtin_amdgcn_update_dpp(0, __float_as_int(x), 0x128, 0xf, 0xf, false);
    x += __int_as_float(t);
    return x;
}

// ---------------- cast/init kernel (weights, edges, biases; x-cast removed) ----------------
// cnt and col_src pre-zeroed by one memset. Bucketed CSR: col_src[dst*64 + p].
__global__ void k_cast_all(const float* __restrict__ Wl1, const float* __restrict__ Wr1,
                           const float* __restrict__ W1,
                           const float* __restrict__ Wl2, const float* __restrict__ Wr2,
                           const float* __restrict__ W2,
                           const float* __restrict__ bl1, const float* __restrict__ br1,
                           const float* __restrict__ bl2, const float* __restrict__ br2,
                           const float* __restrict__ att1, const float* __restrict__ att2,
                           const int* __restrict__ esrc, const int* __restrict__ edst,
                           u16* __restrict__ WfT1,
                           u16* __restrict__ W1T, u16* __restrict__ WfT2,
                           u16* __restrict__ W2T,
                           float* __restrict__ fb1, float* __restrict__ fb2,
                           float* __restrict__ attc1, float* __restrict__ attc2,
                           int* __restrict__ cnt, int* __restrict__ col_src,
                           float* __restrict__ stats) {
    int i = blockIdx.x * 256 + threadIdx.x;
    if (i < 400000) {   // bucketed edge fill (one atomic per edge)
        int d = edst[i];
        int p = atomicAdd(&cnt[d], 1);
        col_src[(d << 6) + p] = esrc[i];
        return;
    }
    i -= 400000;
    if (i < 49152) { int k = i / 384, n = i - k * 384; WfT1[n * 128 + k] = (u16)bf16_1(Wl1[i]); return; }
    i -= 49152;
    if (i < 49152) { int k = i / 384, n = i - k * 384; WfT1[(384 + n) * 128 + k] = (u16)bf16_1(Wr1[i]); return; }
    i -= 49152;
    if (i < 49152) { int k = i / 128, n = i - k * 128; W1T[n * 384 + k] = (u16)bf16_1(W1[i]); return; }
    i -= 49152;
    if (i < 49152) { int k = i / 384, n = i - k * 384; WfT2[n * 128 + k] = (u16)bf16_1(Wl2[i]); return; }
    i -= 49152;
    if (i < 49152) { int k = i / 384, n = i - k * 384; WfT2[(384 + n) * 128 + k] = (u16)bf16_1(Wr2[i]); return; }
    i -= 49152;
    if (i < 98304) { int k = i / 128, n = i - k * 128; W2T[n * 768 + k] = (u16)bf16_1(W2[i]); return; }
    i -= 98304;
    if (i < 768) { fb1[i] = (i < 384) ? bl1[i] : br1[i - 384]; return; }
    i -= 768;
    if (i < 768) { fb2[i] = (i < 384) ? bl2[i] : br2[i - 384]; return; }
    i -= 768;
    // pre-scaled attention vectors: 0.6 * log2(e) * att
    if (i < 384) { attc1[i] = att1[i] * 0.86561702f; return; }
    i -= 384;
    if (i < 384) { attc2[i] = att2[i] * 0.86561702f; return; }
    i -= 384;
    if (i < 512) stats[i] = 0.f;
}
#define CAST_TOTAL (400000 + 5 * 49152 + 98304 + 1536 + 768 + 512)

// ---------------- K=128 GEMM, A cast fused (layer-1 transform) ----------------
// A = x fp32 [NN][128], bf16-cast applied in registers during reg-staging
// (same swizzled granule layout as global_load_lds: dest granule written at
// c8t ^ (r&15) — pattern proven in k_gemm_k128_bn, R7-passing).
// grid (3, 391): A staged once, 2 N-tile loop.
__global__ __launch_bounds__(256) void k_gemm_k128c(
        const float* __restrict__ Af, const u16* __restrict__ BT,
        const float* __restrict__ bias, u16* __restrict__ Cb, int M) {
    __shared__ short sA[64 * 128];    // 16 KB
    __shared__ short sB[128 * 128];   // 32 KB
    int tid = threadIdx.x;
    int wv = tid >> 6, lane = tid & 63;
    int quad = lane >> 4, m16 = lane & 15;
    int mb = blockIdx.y * 64;
    int c8t = tid & 15;

    // reg-stage A: load fp32, cast bf16, swizzled ds_write
#pragma unroll
    for (int j = 0; j < 4; ++j) {
        int L = j * 256 + tid;
        int r = L >> 4;
        int gr = mb + r; gr = gr < M ? gr : M - 1;
        const float* ap = Af + (size_t)gr * 128 + c8t * 8;
        float4 a = *(const float4*)ap;
        float4 b = *(const float4*)(ap + 4);
        uint4 w;
        w.x = bf16_1(a.x) | (bf16_1(a.y) << 16);
        w.y = bf16_1(a.z) | (bf16_1(a.w) << 16);
        w.z = bf16_1(b.x) | (bf16_1(b.y) << 16);
        w.w = bf16_1(b.z) | (bf16_1(b.w) << 16);
        *(uint4*)(sA + ((size_t)(r * 16 + (c8t ^ (r & 15)))) * 8) = w;
    }

    for (int j2 = 0; j2 < 2; ++j2) {
        int nb = blockIdx.x * 256 + j2 * 128;
        __syncthreads();   // protect sB reuse; (iter0: also orders sA ds_writes)
#pragma unroll
        for (int j = 0; j < 8; ++j) {
            int L = j * 256 + tid;
            int r = L >> 4, c8 = (L & 15) ^ (r & 15);
            __builtin_amdgcn_global_load_lds(
                (const __attribute__((address_space(1))) void*)(BT + (size_t)(nb + r) * 128 + c8 * 8),
                (__attribute__((address_space(3))) void*)(sB + (size_t)L * 8), 16, 0, 0);
        }
        __syncthreads();   // sA + sB staged

        floatx4 acc[8];
#pragma unroll
        for (int nf = 0; nf < 8; ++nf)
#pragma unroll
            for (int r = 0; r < 4; ++r) acc[nf][r] = 0.f;

#pragma unroll
        for (int ks = 0; ks < 4; ++ks) {
            int slot = (ks * 4 + quad) ^ m16;
            short8 a0 = *(const short8*)(sA + ((size_t)(wv * 16 + m16) * 16 + slot) * 8);
#pragma unroll
            for (int nf = 0; nf < 8; ++nf) {
                short8 b = *(const short8*)(sB + ((size_t)(nf * 16 + m16) * 16 + slot) * 8);
                acc[nf] = __builtin_amdgcn_mfma_f32_16x16x32_bf16(a0, b, acc[nf], 0, 0, 0);
            }
        }
        __syncthreads();   // all MFMA reads of sB done

        // repack 64x128 bf16 output tile into sB (+bias)
#pragma unroll
        for (int nf = 0; nf < 8; ++nf)
#pragma unroll
            for (int r = 0; r < 4; ++r) {
                int row = wv * 16 + quad * 4 + r;
                int col = nf * 16 + m16;
                sB[row * 128 + col] = (short)bf16_1(acc[nf][r] + bias[nb + col]);
            }
        __syncthreads();

        int xr = nb >= 384;
        int h = (xr ? (nb - 384) : nb) >> 7;
        u16* cb = Cb + ((size_t)(xr * 3 + h) * NN) * 128;
#pragma unroll
        for (int i = 0; i < 4; ++i) {
            int u = i * 256 + tid;
            int row = u >> 4, c8 = u & 15;
            int grow = mb + row;
            if (grow < M)
                *(uint4*)(cb + (size_t)grow * 128 + c8 * 8) = *(const uint4*)(sB + (size_t)u * 8);
        }
    }
}

// ---------------- K=128 GEMM with fused BN1-apply on A (layer-2 transform) ----------------
__global__ __launch_bounds__(256) void k_gemm_k128_bn(
        const float* __restrict__ Af, const float* __restrict__ stats,
        const float* __restrict__ gg, const float* __restrict__ be,
        const u16* __restrict__ BT,
        const float* __restrict__ bias, u16* __restrict__ Cb, int M) {
    __shared__ short sA[64 * 128];    // 16 KB
    __shared__ short sB[128 * 128];   // 32 KB
    int tid = threadIdx.x;
    int wv = tid >> 6, lane = tid & 63;
    int quad = lane >> 4, m16 = lane & 15;
    int mb = blockIdx.y * 64;

    // BN scale/shift for this thread's fixed 8 columns (c8 = tid&15)
    int c8t = tid & 15;
    const float minv = 1.f / (float)NN;
    float sc[8], sh[8];
#pragma unroll
    for (int k = 0; k < 8; ++k) {
        int c = c8t * 8 + k;
        float mu = stats[c] * minv;
        float var = stats[128 + c] * minv - mu * mu;
        float s = gg[c] * rsqrtf(var + EPS);
        sc[k] = s;
        sh[k] = be[c] - mu * s;
    }
    // reg-stage A: load fp32, BN+ReLU, cast bf16, swizzled ds_write
#pragma unroll
    for (int j = 0; j < 4; ++j) {
        int L = j * 256 + tid;
        int r = L >> 4;
        int gr = mb + r; gr = gr < M ? gr : M - 1;
        const float* ap = Af + (size_t)gr * 128 + c8t * 8;
        float4 a = *(const float4*)ap;
        float4 b = *(const float4*)(ap + 4);
        float v[8] = {a.x, a.y, a.z, a.w, b.x, b.y, b.z, b.w};
        u32 pk[4];
#pragma unroll
        for (int k = 0; k < 4; ++k) {
            u32 lo = bf16_1(fmaxf(fmaf(v[2 * k], sc[2 * k], sh[2 * k]), 0.f));
            u32 hi = bf16_1(fmaxf(fmaf(v[2 * k + 1], sc[2 * k + 1], sh[2 * k + 1]), 0.f));
            pk[k] = lo | (hi << 16);
        }
        uint4 w = {pk[0], pk[1], pk[2], pk[3]};
        *(uint4*)(sA + ((size_t)(r * 16 + (c8t ^ (r & 15)))) * 8) = w;
    }

    for (int j2 = 0; j2 < 2; ++j2) {
        int nb = blockIdx.x * 256 + j2 * 128;
        __syncthreads();   // protect sB reuse; (iter0: also orders sA ds_writes)
#pragma unroll
        for (int j = 0; j < 8; ++j) {
            int L = j * 256 + tid;
            int r = L >> 4, c8 = (L & 15) ^ (r & 15);
            __builtin_amdgcn_global_load_lds(
                (const __attribute__((address_space(1))) void*)(BT + (size_t)(nb + r) * 128 + c8 * 8),
                (__attribute__((address_space(3))) void*)(sB + (size_t)L * 8), 16, 0, 0);
        }
        __syncthreads();   // sA + sB staged

        floatx4 acc[8];
#pragma unroll
        for (int nf = 0; nf < 8; ++nf)
#pragma unroll
            for (int r = 0; r < 4; ++r) acc[nf][r] = 0.f;

#pragma unroll
        for (int ks = 0; ks < 4; ++ks) {
            int slot = (ks * 4 + quad) ^ m16;
            short8 a0 = *(const short8*)(sA + ((size_t)(wv * 16 + m16) * 16 + slot) * 8);
#pragma unroll
            for (int nf = 0; nf < 8; ++nf) {
                short8 b = *(const short8*)(sB + ((size_t)(nf * 16 + m16) * 16 + slot) * 8);
                acc[nf] = __builtin_amdgcn_mfma_f32_16x16x32_bf16(a0, b, acc[nf], 0, 0, 0);
            }
        }
        __syncthreads();

#pragma unroll
        for (int nf = 0; nf < 8; ++nf)
#pragma unroll
            for (int r = 0; r < 4; ++r) {
                int row = wv * 16 + quad * 4 + r;
                int col = nf * 16 + m16;
                sB[row * 128 + col] = (short)bf16_1(acc[nf][r] + bias[nb + col]);
            }
        __syncthreads();

        int xr = nb >= 384;
        int h = (xr ? (nb - 384) : nb) >> 7;
        u16* cb = Cb + ((size_t)(xr * 3 + h) * NN) * 128;
#pragma unroll
        for (int i = 0; i < 4; ++i) {
            int u = i * 256 + tid;
            int row = u >> 4, c8 = u & 15;
            int grow = mb + row;
            if (grow < M)
                *(uint4*)(cb + (size_t)grow * 128 + c8 * 8) = *(const uint4*)(sB + (size_t)u * 8);
        }
    }
}

// ---------------- bf16 MFMA GEMM (K-loop, BK=128), stats folded ----------------
__global__ __launch_bounds__(256) void k_gemm_bf(
        const u16* __restrict__ A, const u16* __restrict__ BT,
        const float* __restrict__ bias,
        float* __restrict__ Cf, float* __restrict__ stats,
        int M, int N, int K, int lda) {
    __shared__ short smem[17408];   // 34 KB: sA 16K + sB 16K + stat partials 2K
    short* sA = smem;               // 64 x 128
    short* sB = smem + 8192;        // 64 x 128
    int tid = threadIdx.x;
    int wv = tid >> 6, lane = tid & 63;
    int quad = lane >> 4, m16 = lane & 15;
    int mb = blockIdx.y * 64, nb = blockIdx.x * 64;

    floatx4 acc[4];
#pragma unroll
    for (int nf = 0; nf < 4; ++nf)
#pragma unroll
        for (int r = 0; r < 4; ++r) acc[nf][r] = 0.f;

    for (int k0 = 0; k0 < K; k0 += 128) {
#pragma unroll
        for (int j = 0; j < 4; ++j) {
            int L = j * 256 + tid;
            int r = L >> 4, c8 = (L & 15) ^ (r & 15);
            int gr = mb + r; gr = gr < M ? gr : M - 1;
            __builtin_amdgcn_global_load_lds(
                (const __attribute__((address_space(1))) void*)(A + (size_t)gr * lda + k0 + c8 * 8),
                (__attribute__((address_space(3))) void*)(sA + (size_t)L * 8), 16, 0, 0);
        }
#pragma unroll
        for (int j = 0; j < 4; ++j) {
            int L = j * 256 + tid;
            int r = L >> 4, c8 = (L & 15) ^ (r & 15);
            __builtin_amdgcn_global_load_lds(
                (const __attribute__((address_space(1))) void*)(BT + (size_t)(nb + r) * K + k0 + c8 * 8),
                (__attribute__((address_space(3))) void*)(sB + (size_t)L * 8), 16, 0, 0);
        }
        __syncthreads();
#pragma unroll
        for (int ks = 0; ks < 4; ++ks) {
            int slot = (ks * 4 + quad) ^ m16;
            short8 a0 = *(const short8*)(sA + ((size_t)(wv * 16 + m16) * 16 + slot) * 8);
#pragma unroll
            for (int nf = 0; nf < 4; ++nf) {
                short8 b = *(const short8*)(sB + ((size_t)(nf * 16 + m16) * 16 + slot) * 8);
                acc[nf] = __builtin_amdgcn_mfma_f32_16x16x32_bf16(a0, b, acc[nf], 0, 0, 0);
            }
        }
        __syncthreads();
    }
    // fp32 tile [64][64] staged in LDS (16 KB), coalesced float4 stores
    float* fs = (float*)smem;
#pragma unroll
    for (int nf = 0; nf < 4; ++nf)
#pragma unroll
        for (int r = 0; r < 4; ++r) {
            int row = wv * 16 + quad * 4 + r;
            int col = nf * 16 + m16;
            fs[row * 64 + col] = acc[nf][r] + (bias ? bias[nb + col] : 0.f);
        }
    __syncthreads();
#pragma unroll
    for (int i = 0; i < 4; ++i) {
        int u = i * 256 + tid;
        int row = u >> 4, c4 = u & 15;
        int grow = mb + row;
        if (grow < M)
            *(float4*)(Cf + (size_t)grow * N + nb + c4 * 4) = *(const float4*)(fs + (size_t)u * 4);
    }
    // folded BN stats: per-column sum/sumsq partials -> atomicAdd
    if (stats) {
        float* ps = (float*)(smem + 16384);   // [2][4][64]
        int col = tid & 63, qr = tid >> 6;
        int vr = M - mb; vr = vr < 64 ? vr : 64;
        int r0 = qr * 16, r1 = r0 + 16 < vr ? r0 + 16 : vr;
        float s = 0.f, q = 0.f;
        for (int r = r0; r < r1; ++r) { float v = fs[r * 64 + col]; s += v; q += v * v; }
        ps[qr * 64 + col] = s;
        ps[256 + qr * 64 + col] = q;
        __syncthreads();
        if (tid < 64) {
            float ss = ps[tid] + ps[64 + tid] + ps[128 + tid] + ps[192 + tid];
            atomicAdd(&stats[nb + tid], ss);
        } else if (tid < 128) {
            int c = tid - 64;
            float qq = ps[256 + c] + ps[320 + c] + ps[384 + c] + ps[448 + c];
            atomicAdd(&stats[128 + nb + c], qq);
        }
    }
}

// ---------------- GATv2 aggregate, per-head blocks, bucketed CSR ----------------
__global__ __launch_bounds__(256) void k_gat_h(const u32* __restrict__ XLb,
                                               const u32* __restrict__ XRb,
                                               const float* __restrict__ attc,
                                               const float* __restrict__ bias,
                                               const int* __restrict__ cnt,
                                               const int* __restrict__ col_src,
                                               u32* __restrict__ outb) {
    int h = blockIdx.y;
    const u32* XLh = XLb + (size_t)h * NN * 64;
    const u32* XRh = XRb + (size_t)h * NN * 64;
    int node = blockIdx.x * 4 + (threadIdx.x >> 6);
    int lane = threadIdx.x & 63;
    int g = lane >> 4, gl = lane & 15;

    f32x2 xr2[4], a6[4], acc2[4];
    const f32x2 c23 = {0.66666667f, 0.66666667f};
    up8f2(*(const uint4*)(XRh + (size_t)node * 64 + 4 * gl), xr2);
#pragma unroll
    for (int j = 0; j < 4; ++j) {
        a6[j] = *(const f32x2*)(attc + h * 128 + 8 * gl + 2 * j);
        acc2[j] = f32x2{0.f, 0.f};
    }
    float l = 0.f;

    int e0 = node << 6;
    int cntE = cnt[node];

    // issue first edge-index loads early
    int c0i = col_src[e0 + g];
    int c1i = col_src[e0 + g + 4];

    // self-loop contribution (group 0 only; whole 16-lane DPP row active)
    if (g == 0) {
        f32x2 xs[4];
        up8f2(*(const uint4*)(XLh + (size_t)node * 64 + 4 * gl), xs);
        f32x2 p2 = {0.f, 0.f};
#pragma unroll
        for (int j = 0; j < 4; ++j) {
            f32x2 v = pk_add(xs[j], xr2[j]);
            p2 = pk_fma(pk_fma(fabs2(v), c23, v), a6[j], p2);
        }
        float w = __builtin_amdgcn_exp2f(row_sum16(p2.x + p2.y));
        l = w;
        f32x2 w2 = {w, w};
#pragma unroll
        for (int j = 0; j < 4; ++j) acc2[j] = pk_fma(xs[j], w2, acc2[j]);
    }

    uint4 ua = *(const uint4*)(XLh + (size_t)c0i * 64 + 4 * gl);
    uint4 ub = *(const uint4*)(XLh + (size_t)c1i * 64 + 4 * gl);

    for (int t = g; t < cntE; t += 8) {
        uint4 un0 = *(const uint4*)(XLh + (size_t)col_src[e0 + t + 8] * 64 + 4 * gl);
        uint4 un1 = *(const uint4*)(XLh + (size_t)col_src[e0 + t + 12] * 64 + 4 * gl);

        f32x2 xa2[4], xb2[4];
        up8f2(ua, xa2); up8f2(ub, xb2);
        f32x2 pa2 = {0.f, 0.f}, pb2 = {0.f, 0.f};
#pragma unroll
        for (int j = 0; j < 4; ++j) {
            f32x2 va = pk_add(xa2[j], xr2[j]);
            f32x2 vb = pk_add(xb2[j], xr2[j]);
            pa2 = pk_fma(pk_fma(fabs2(va), c23, va), a6[j], pa2);
            pb2 = pk_fma(pk_fma(fabs2(vb), c23, vb), a6[j], pb2);
        }
        float pa = row_sum16(pa2.x + pa2.y);
        float pb = row_sum16(pb2.x + pb2.y);
        float wa = __builtin_amdgcn_exp2f(pa);
        float wb = ((t + 4) < cntE) ? __builtin_amdgcn_exp2f(pb) : 0.f;
        l += wa + wb;
        f32x2 wa2 = {wa, wa}, wb2 = {wb, wb};
#pragma unroll
        for (int j = 0; j < 4; ++j)
            acc2[j] = pk_fma(xa2[j], wa2, pk_fma(xb2[j], wb2, acc2[j]));

        ua = un0; ub = un1;
    }

#pragma unroll
    for (int o = 16; o <= 32; o <<= 1) {
        l += __shfl_xor(l, o);
#pragma unroll
        for (int j = 0; j < 4; ++j) {
            f32x2 s;
            s.x = __shfl_xor(acc2[j].x, o);
            s.y = __shfl_xor(acc2[j].y, o);
            acc2[j] = pk_add(acc2[j], s);
        }
    }

    if (g == 0) {
        float r = 1.f / l;
        float bv[8];
        *(float4*)&bv[0] = *(const float4*)&bias[h * 128 + 8 * gl];
        *(float4*)&bv[4] = *(const float4*)&bias[h * 128 + 8 * gl + 4];
        uint4 w;
        w.x = bf16_1(fmaf(acc2[0].x, r, bv[0])) | (bf16_1(fmaf(acc2[0].y, r, bv[1])) << 16);
        w.y = bf16_1(fmaf(acc2[1].x, r, bv[2])) | (bf16_1(fmaf(acc2[1].y, r, bv[3])) << 16);
        w.z = bf16_1(fmaf(acc2[2].x, r, bv[4])) | (bf16_1(fmaf(acc2[2].y, r, bv[5])) << 16);
        w.w = bf16_1(fmaf(acc2[3].x, r, bv[6])) | (bf16_1(fmaf(acc2[3].y, r, bv[7])) << 16);
        *(uint4*)(outb + (size_t)node * 384 + h * 64 + 4 * gl) = w;
    }
}

// ---------------- BN apply (final output only) ----------------
__global__ void k_bn_apply(float* __restrict__ y, const float* __restrict__ stats,
                           const float* __restrict__ g, const float* __restrict__ be,
                           u16* __restrict__ yb, int wf) {
    int i = blockIdx.x * 256 + threadIdx.x;
    if (i >= NN * DD / 8) return;
    int idx = i * 8;
    int c0 = idx & 127;
    float v[8];
    *(float4*)&v[0] = *(const float4*)(y + idx);
    *(float4*)&v[4] = *(const float4*)(y + idx + 4);
    const float minv = 1.f / (float)NN;
#pragma unroll
    for (int k = 0; k < 8; ++k) {
        int c = c0 + k;
        float mu = stats[c] * minv;
        float var = stats[128 + c] * minv - mu * mu;
        float sc = g[c] * rsqrtf(var + EPS);
        float sh = be[c] - mu * sc;
        v[k] = fmaxf(fmaf(v[k], sc, sh), 0.f);
    }
    if (wf) {
        *(float4*)(y + idx) = *(const float4*)&v[0];
        *(float4*)(y + idx + 4) = *(const float4*)&v[4];
    }
    if (yb) {
        uint4 w;
        w.x = bf16_1(v[0]) | (bf16_1(v[1]) << 16);
        w.y = bf16_1(v[2]) | (bf16_1(v[3]) << 16);
        w.z = bf16_1(v[4]) | (bf16_1(v[5]) << 16);
        w.w = bf16_1(v[6]) | (bf16_1(v[7]) << 16);
        *(uint4*)(yb + idx) = w;
    }
}

// ---------------- launch ----------------

extern "C" void kernel_launch(void* const* d_in, const int* in_sizes, int n_in,
                              void* d_out, int out_size, void* d_ws, size_t ws_size,
                              hipStream_t stream) {
    const float* x    = (const float*)d_in[0];
    const int*   ei   = (const int*)d_in[1];
    const float* Wl1  = (const float*)d_in[2];
    const float* bl1  = (const float*)d_in[3];
    const float* Wr1  = (const float*)d_in[4];
    const float* br1  = (const float*)d_in[5];
    const float* att1 = (const float*)d_in[6];
    const float* bc1  = (const float*)d_in[7];
    const float* g1   = (const float*)d_in[8];
    const float* be1  = (const float*)d_in[9];
    const float* Wl2  = (const float*)d_in[10];
    const float* bl2  = (const float*)d_in[11];
    const float* Wr2  = (const float*)d_in[12];
    const float* br2  = (const float*)d_in[13];
    const float* att2 = (const float*)d_in[14];
    const float* bc2  = (const float*)d_in[15];
    const float* g2   = (const float*)d_in[16];
    const float* be2  = (const float*)d_in[17];
    const float* W1   = (const float*)d_in[18];
    const float* b1   = (const float*)d_in[19];
    const float* W2   = (const float*)d_in[20];
    const float* b2   = (const float*)d_in[21];
    const int* esrc = ei;
    const int* edst = ei + NE;
    float* out = (float*)d_out;

    // ---- workspace layout (all regions 16B-aligned) ----
    float* bufD   = (float*)d_ws;          // mid fp32 [NN,128]      12.8 MB
    float* stats  = bufD + 3200000;        // 512 f (BN1 +0, BN2 +256)
    int* cnt      = (int*)(stats + 512);   // 25000 edge counters
    int* col_src  = cnt + 25000;           // [NN][64] buckets + 24 pad  6.4 MB
    float* fb1    = (float*)(col_src + 1600024);  // 768 fused bias L1
    float* fb2    = fb1 + 768;             // 768 fused bias L2
    float* attc1  = fb2 + 768;             // 384 pre-scaled att L1
    float* attc2  = attc1 + 384;           // 384 pre-scaled att L2
    u16* XLb      = (u16*)(attc2 + 384);   // head-major xl [3][NN][128]  19.2 MB
    u16* XRb      = XLb + 3 * NN * 128;    // head-major xr [3][NN][128]
    u16* bufCat   = XRb + 3 * NN * 128;    // [NN,768] h2|x_in bf16  38.4 MB
    u16* WfT1     = bufCat + 19200000;     // [768][128]
    u16* W1T      = WfT1 + 98304;          // [128][384]
    u16* WfT2     = W1T + 49152;           // [768][128]
    u16* W2T      = WfT2 + 98304;          // [128][768]

    // one memset over contiguous cnt+col_src, then fused cast/fill kernel
    hipMemsetAsync(cnt, 0, (25000 + NN * 64 + 24) * sizeof(int), stream);
    k_cast_all<<<(CAST_TOTAL + 255) / 256, 256, 0, stream>>>(
        Wl1, Wr1, W1, Wl2, Wr2, W2, bl1, br1, bl2, br2, att1, att2, esrc, edst,
        WfT1, W1T, WfT2, W2T, fb1, fb2, attc1, attc2, cnt, col_src, stats);

    dim3 blk(256);
    dim3 gK(3, (NN + 63) / 64);          // K=128 GEMMs: 1173 blocks, 2-tile loop
    dim3 g64(2, (NN + 63) / 64);         // BM=64 GEMMs: 782 blocks
    dim3 gGat((NN + 3) / 4, 3);          // gat: per-head blocks (L2 tiling)

    // layer 1 (x cast fused into A staging)
    k_gemm_k128c<<<gK, blk, 0, stream>>>(x, WfT1, fb1, XLb, NN);
    k_gat_h<<<gGat, blk, 0, stream>>>((const u32*)XLb, (const u32*)XRb, attc1, bc1,
                                      cnt, col_src, (u32*)bufCat + 192);

    // mid MLP (+BN stats folded); BN1-apply fused into the layer-2 transform
    k_gemm_bf<<<g64, blk, 0, stream>>>(bufCat + 384, W1T, b1, bufD, stats, NN, DD, HD, 768);

    // layer 2 (A = bufD fp32, BN1+ReLU+cast fused into staging)
    k_gemm_k128_bn<<<gK, blk, 0, stream>>>(bufD, stats, g1, be1, WfT2, fb2, XLb, NN);
    k_gat_h<<<gGat, blk, 0, stream>>>((const u32*)XLb, (const u32*)XRb, attc2, bc2,
                                      cnt, col_src, (u32*)bufCat);

    // final GEMM (+BN stats folded) + BN apply
    k_gemm_bf<<<g64, blk, 0, stream>>>(bufCat, W2T, b2, out, stats + 256, NN, DD, 768, 768);
    k_bn_apply<<<(NN * DD / 8 + 255) / 256, 256, 0, stream>>>(out, stats + 256, g2, be2, nullptr, 1);
}

// Round 10
// 319.852 us; speedup vs baseline: 1.3021x; 1.0286x over previous
//
#include <hip/hip_runtime.h>
#include <math.h>

#define NN 25000      // nodes
#define NE 400000     // edges
#define DD 128        // hidden dim
#define HD 384        // heads * dim
#define NEG 0.2f
#define EPS 1e-5f

typedef unsigned int u32;
typedef unsigned short u16;
typedef __attribute__((ext_vector_type(8))) short short8;   // 8 bf16 (4 VGPRs)
typedef __attribute__((ext_vector_type(4))) float floatx4;  // MFMA accumulator
typedef __attribute__((ext_vector_type(2))) float f32x2;    // packed-f32 pair

// ---- bf16 helpers (RNE) ----
__device__ __forceinline__ u32 bf16_1(float x) {
    u32 u = __float_as_uint(x);
    return (u + 0x7fffu + ((u >> 16) & 1u)) >> 16;
}
__device__ __forceinline__ float blo(u32 u) { return __uint_as_float(u << 16); }
__device__ __forceinline__ float bhi(u32 u) { return __uint_as_float(u & 0xffff0000u); }

__device__ __forceinline__ void up8f2(uint4 u, f32x2* f) {
    f[0] = f32x2{blo(u.x), bhi(u.x)};
    f[1] = f32x2{blo(u.y), bhi(u.y)};
    f[2] = f32x2{blo(u.z), bhi(u.z)};
    f[3] = f32x2{blo(u.w), bhi(u.w)};
}

// ---- packed f32 ops (CDNA v_pk_*, 2 f32 lanes / inst) ----
__device__ __forceinline__ f32x2 pk_add(f32x2 a, f32x2 b) {
    f32x2 d; asm("v_pk_add_f32 %0, %1, %2" : "=v"(d) : "v"(a), "v"(b)); return d;
}
__device__ __forceinline__ f32x2 pk_fma(f32x2 a, f32x2 b, f32x2 c) {
    f32x2 d; asm("v_pk_fma_f32 %0, %1, %2, %3" : "=v"(d) : "v"(a), "v"(b), "v"(c)); return d;
}
__device__ __forceinline__ f32x2 fabs2(f32x2 v) {
    u32 a = __float_as_uint(v.x) & 0x7fffffffu;
    u32 b = __float_as_uint(v.y) & 0x7fffffffu;
    return f32x2{__uint_as_float(a), __uint_as_float(b)};
}

// ---- 16-lane (DPP row) rotate-reduce: every lane gets the row total ----
__device__ __forceinline__ float row_sum16(float x) {
    int t;
    t = __builtin_amdgcn_update_dpp(0, __float_as_int(x), 0x121, 0xf, 0xf, false);
    x += __int_as_float(t);
    t = __builtin_amdgcn_update_dpp(0, __float_as_int(x), 0x122, 0xf, 0xf, false);
    x += __int_as_float(t);
    t = __builtin_amdgcn_update_dpp(0, __float_as_int(x), 0x124, 0xf, 0xf, false);
    x += __int_as_float(t);
    t = __builtin_amdgcn_update_dpp(0, __float_as_int(x), 0x128, 0xf, 0xf, false);
    x += __int_as_float(t);
    return x;
}

// ---------------- cast/init kernel (weights, edges, biases) ----------------
// cnt and col_src pre-zeroed by one memset. Bucketed CSR: col_src[dst*64 + p]
// stores src*256 = BYTE offset of the source row (saves the shift in gat).
__global__ void k_cast_all(const float* __restrict__ Wl1, const float* __restrict__ Wr1,
                           const float* __restrict__ W1,
                           const float* __restrict__ Wl2, const float* __restrict__ Wr2,
                           const float* __restrict__ W2,
                           const float* __restrict__ bl1, const float* __restrict__ br1,
                           const float* __restrict__ bl2, const float* __restrict__ br2,
                           const float* __restrict__ att1, const float* __restrict__ att2,
                           const int* __restrict__ esrc, const int* __restrict__ edst,
                           u16* __restrict__ WfT1,
                           u16* __restrict__ W1T, u16* __restrict__ WfT2,
                           u16* __restrict__ W2T,
                           float* __restrict__ fb1, float* __restrict__ fb2,
                           float* __restrict__ attc1, float* __restrict__ attc2,
                           int* __restrict__ cnt, int* __restrict__ col_src,
                           float* __restrict__ stats) {
    int i = blockIdx.x * 256 + threadIdx.x;
    if (i < 400000) {   // bucketed edge fill (one atomic per edge), pre-scaled
        int d = edst[i];
        int p = atomicAdd(&cnt[d], 1);
        col_src[(d << 6) + p] = esrc[i] << 8;
        return;
    }
    i -= 400000;
    if (i < 49152) { int k = i / 384, n = i - k * 384; WfT1[n * 128 + k] = (u16)bf16_1(Wl1[i]); return; }
    i -= 49152;
    if (i < 49152) { int k = i / 384, n = i - k * 384; WfT1[(384 + n) * 128 + k] = (u16)bf16_1(Wr1[i]); return; }
    i -= 49152;
    if (i < 49152) { int k = i / 128, n = i - k * 128; W1T[n * 384 + k] = (u16)bf16_1(W1[i]); return; }
    i -= 49152;
    if (i < 49152) { int k = i / 384, n = i - k * 384; WfT2[n * 128 + k] = (u16)bf16_1(Wl2[i]); return; }
    i -= 49152;
    if (i < 49152) { int k = i / 384, n = i - k * 384; WfT2[(384 + n) * 128 + k] = (u16)bf16_1(Wr2[i]); return; }
    i -= 49152;
    if (i < 98304) { int k = i / 128, n = i - k * 128; W2T[n * 768 + k] = (u16)bf16_1(W2[i]); return; }
    i -= 98304;
    if (i < 768) { fb1[i] = (i < 384) ? bl1[i] : br1[i - 384]; return; }
    i -= 768;
    if (i < 768) { fb2[i] = (i < 384) ? bl2[i] : br2[i - 384]; return; }
    i -= 768;
    // pre-scaled attention vectors: 0.6 * log2(e) * att
    if (i < 384) { attc1[i] = att1[i] * 0.86561702f; return; }
    i -= 384;
    if (i < 384) { attc2[i] = att2[i] * 0.86561702f; return; }
    i -= 384;
    if (i < 512) stats[i] = 0.f;
}
#define CAST_TOTAL (400000 + 5 * 49152 + 98304 + 1536 + 768 + 512)

// ---------------- K=128 GEMM, A cast fused (layer-1 transform) ----------------
__global__ __launch_bounds__(256) void k_gemm_k128c(
        const float* __restrict__ Af, const u16* __restrict__ BT,
        const float* __restrict__ bias, u16* __restrict__ Cb, int M) {
    __shared__ short sA[64 * 128];    // 16 KB
    __shared__ short sB[128 * 128];   // 32 KB
    int tid = threadIdx.x;
    int wv = tid >> 6, lane = tid & 63;
    int quad = lane >> 4, m16 = lane & 15;
    int mb = blockIdx.y * 64;
    int c8t = tid & 15;

    // reg-stage A: load fp32, cast bf16, swizzled ds_write
#pragma unroll
    for (int j = 0; j < 4; ++j) {
        int L = j * 256 + tid;
        int r = L >> 4;
        int gr = mb + r; gr = gr < M ? gr : M - 1;
        const float* ap = Af + (size_t)gr * 128 + c8t * 8;
        float4 a = *(const float4*)ap;
        float4 b = *(const float4*)(ap + 4);
        uint4 w;
        w.x = bf16_1(a.x) | (bf16_1(a.y) << 16);
        w.y = bf16_1(a.z) | (bf16_1(a.w) << 16);
        w.z = bf16_1(b.x) | (bf16_1(b.y) << 16);
        w.w = bf16_1(b.z) | (bf16_1(b.w) << 16);
        *(uint4*)(sA + ((size_t)(r * 16 + (c8t ^ (r & 15)))) * 8) = w;
    }

    for (int j2 = 0; j2 < 2; ++j2) {
        int nb = blockIdx.x * 256 + j2 * 128;
        __syncthreads();   // protect sB reuse; (iter0: also orders sA ds_writes)
#pragma unroll
        for (int j = 0; j < 8; ++j) {
            int L = j * 256 + tid;
            int r = L >> 4, c8 = (L & 15) ^ (r & 15);
            __builtin_amdgcn_global_load_lds(
                (const __attribute__((address_space(1))) void*)(BT + (size_t)(nb + r) * 128 + c8 * 8),
                (__attribute__((address_space(3))) void*)(sB + (size_t)L * 8), 16, 0, 0);
        }
        __syncthreads();   // sA + sB staged

        floatx4 acc[8];
#pragma unroll
        for (int nf = 0; nf < 8; ++nf)
#pragma unroll
            for (int r = 0; r < 4; ++r) acc[nf][r] = 0.f;

#pragma unroll
        for (int ks = 0; ks < 4; ++ks) {
            int slot = (ks * 4 + quad) ^ m16;
            short8 a0 = *(const short8*)(sA + ((size_t)(wv * 16 + m16) * 16 + slot) * 8);
#pragma unroll
            for (int nf = 0; nf < 8; ++nf) {
                short8 b = *(const short8*)(sB + ((size_t)(nf * 16 + m16) * 16 + slot) * 8);
                acc[nf] = __builtin_amdgcn_mfma_f32_16x16x32_bf16(a0, b, acc[nf], 0, 0, 0);
            }
        }
        __syncthreads();   // all MFMA reads of sB done

        // repack 64x128 bf16 output tile into sB (+bias)
#pragma unroll
        for (int nf = 0; nf < 8; ++nf)
#pragma unroll
            for (int r = 0; r < 4; ++r) {
                int row = wv * 16 + quad * 4 + r;
                int col = nf * 16 + m16;
                sB[row * 128 + col] = (short)bf16_1(acc[nf][r] + bias[nb + col]);
            }
        __syncthreads();

        int xr = nb >= 384;
        int h = (xr ? (nb - 384) : nb) >> 7;
        u16* cb = Cb + ((size_t)(xr * 3 + h) * NN) * 128;
#pragma unroll
        for (int i = 0; i < 4; ++i) {
            int u = i * 256 + tid;
            int row = u >> 4, c8 = u & 15;
            int grow = mb + row;
            if (grow < M)
                *(uint4*)(cb + (size_t)grow * 128 + c8 * 8) = *(const uint4*)(sB + (size_t)u * 8);
        }
    }
}

// ---------------- K=128 GEMM with fused BN1-apply on A (layer-2 transform) ----------------
__global__ __launch_bounds__(256) void k_gemm_k128_bn(
        const float* __restrict__ Af, const float* __restrict__ stats,
        const float* __restrict__ gg, const float* __restrict__ be,
        const u16* __restrict__ BT,
        const float* __restrict__ bias, u16* __restrict__ Cb, int M) {
    __shared__ short sA[64 * 128];    // 16 KB
    __shared__ short sB[128 * 128];   // 32 KB
    int tid = threadIdx.x;
    int wv = tid >> 6, lane = tid & 63;
    int quad = lane >> 4, m16 = lane & 15;
    int mb = blockIdx.y * 64;

    // BN scale/shift for this thread's fixed 8 columns (c8 = tid&15)
    int c8t = tid & 15;
    const float minv = 1.f / (float)NN;
    float sc[8], sh[8];
#pragma unroll
    for (int k = 0; k < 8; ++k) {
        int c = c8t * 8 + k;
        float mu = stats[c] * minv;
        float var = stats[128 + c] * minv - mu * mu;
        float s = gg[c] * rsqrtf(var + EPS);
        sc[k] = s;
        sh[k] = be[c] - mu * s;
    }
    // reg-stage A: load fp32, BN+ReLU, cast bf16, swizzled ds_write
#pragma unroll
    for (int j = 0; j < 4; ++j) {
        int L = j * 256 + tid;
        int r = L >> 4;
        int gr = mb + r; gr = gr < M ? gr : M - 1;
        const float* ap = Af + (size_t)gr * 128 + c8t * 8;
        float4 a = *(const float4*)ap;
        float4 b = *(const float4*)(ap + 4);
        float v[8] = {a.x, a.y, a.z, a.w, b.x, b.y, b.z, b.w};
        u32 pk[4];
#pragma unroll
        for (int k = 0; k < 4; ++k) {
            u32 lo = bf16_1(fmaxf(fmaf(v[2 * k], sc[2 * k], sh[2 * k]), 0.f));
            u32 hi = bf16_1(fmaxf(fmaf(v[2 * k + 1], sc[2 * k + 1], sh[2 * k + 1]), 0.f));
            pk[k] = lo | (hi << 16);
        }
        uint4 w = {pk[0], pk[1], pk[2], pk[3]};
        *(uint4*)(sA + ((size_t)(r * 16 + (c8t ^ (r & 15)))) * 8) = w;
    }

    for (int j2 = 0; j2 < 2; ++j2) {
        int nb = blockIdx.x * 256 + j2 * 128;
        __syncthreads();   // protect sB reuse; (iter0: also orders sA ds_writes)
#pragma unroll
        for (int j = 0; j < 8; ++j) {
            int L = j * 256 + tid;
            int r = L >> 4, c8 = (L & 15) ^ (r & 15);
            __builtin_amdgcn_global_load_lds(
                (const __attribute__((address_space(1))) void*)(BT + (size_t)(nb + r) * 128 + c8 * 8),
                (__attribute__((address_space(3))) void*)(sB + (size_t)L * 8), 16, 0, 0);
        }
        __syncthreads();   // sA + sB staged

        floatx4 acc[8];
#pragma unroll
        for (int nf = 0; nf < 8; ++nf)
#pragma unroll
            for (int r = 0; r < 4; ++r) acc[nf][r] = 0.f;

#pragma unroll
        for (int ks = 0; ks < 4; ++ks) {
            int slot = (ks * 4 + quad) ^ m16;
            short8 a0 = *(const short8*)(sA + ((size_t)(wv * 16 + m16) * 16 + slot) * 8);
#pragma unroll
            for (int nf = 0; nf < 8; ++nf) {
                short8 b = *(const short8*)(sB + ((size_t)(nf * 16 + m16) * 16 + slot) * 8);
                acc[nf] = __builtin_amdgcn_mfma_f32_16x16x32_bf16(a0, b, acc[nf], 0, 0, 0);
            }
        }
        __syncthreads();

#pragma unroll
        for (int nf = 0; nf < 8; ++nf)
#pragma unroll
            for (int r = 0; r < 4; ++r) {
                int row = wv * 16 + quad * 4 + r;
                int col = nf * 16 + m16;
                sB[row * 128 + col] = (short)bf16_1(acc[nf][r] + bias[nb + col]);
            }
        __syncthreads();

        int xr = nb >= 384;
        int h = (xr ? (nb - 384) : nb) >> 7;
        u16* cb = Cb + ((size_t)(xr * 3 + h) * NN) * 128;
#pragma unroll
        for (int i = 0; i < 4; ++i) {
            int u = i * 256 + tid;
            int row = u >> 4, c8 = u & 15;
            int grow = mb + row;
            if (grow < M)
                *(uint4*)(cb + (size_t)grow * 128 + c8 * 8) = *(const uint4*)(sB + (size_t)u * 8);
        }
    }
}

// ---------------- bf16 MFMA GEMM (K-loop, BK=128), stats folded ----------------
__global__ __launch_bounds__(256) void k_gemm_bf(
        const u16* __restrict__ A, const u16* __restrict__ BT,
        const float* __restrict__ bias,
        float* __restrict__ Cf, float* __restrict__ stats,
        int M, int N, int K, int lda) {
    __shared__ short smem[17408];   // 34 KB: sA 16K + sB 16K + stat partials 2K
    short* sA = smem;               // 64 x 128
    short* sB = smem + 8192;        // 64 x 128
    int tid = threadIdx.x;
    int wv = tid >> 6, lane = tid & 63;
    int quad = lane >> 4, m16 = lane & 15;
    int mb = blockIdx.y * 64, nb = blockIdx.x * 64;

    floatx4 acc[4];
#pragma unroll
    for (int nf = 0; nf < 4; ++nf)
#pragma unroll
        for (int r = 0; r < 4; ++r) acc[nf][r] = 0.f;

    for (int k0 = 0; k0 < K; k0 += 128) {
#pragma unroll
        for (int j = 0; j < 4; ++j) {
            int L = j * 256 + tid;
            int r = L >> 4, c8 = (L & 15) ^ (r & 15);
            int gr = mb + r; gr = gr < M ? gr : M - 1;
            __builtin_amdgcn_global_load_lds(
                (const __attribute__((address_space(1))) void*)(A + (size_t)gr * lda + k0 + c8 * 8),
                (__attribute__((address_space(3))) void*)(sA + (size_t)L * 8), 16, 0, 0);
        }
#pragma unroll
        for (int j = 0; j < 4; ++j) {
            int L = j * 256 + tid;
            int r = L >> 4, c8 = (L & 15) ^ (r & 15);
            __builtin_amdgcn_global_load_lds(
                (const __attribute__((address_space(1))) void*)(BT + (size_t)(nb + r) * K + k0 + c8 * 8),
                (__attribute__((address_space(3))) void*)(sB + (size_t)L * 8), 16, 0, 0);
        }
        __syncthreads();
#pragma unroll
        for (int ks = 0; ks < 4; ++ks) {
            int slot = (ks * 4 + quad) ^ m16;
            short8 a0 = *(const short8*)(sA + ((size_t)(wv * 16 + m16) * 16 + slot) * 8);
#pragma unroll
            for (int nf = 0; nf < 4; ++nf) {
                short8 b = *(const short8*)(sB + ((size_t)(nf * 16 + m16) * 16 + slot) * 8);
                acc[nf] = __builtin_amdgcn_mfma_f32_16x16x32_bf16(a0, b, acc[nf], 0, 0, 0);
            }
        }
        __syncthreads();
    }
    // fp32 tile [64][64] staged in LDS (16 KB), coalesced float4 stores
    float* fs = (float*)smem;
#pragma unroll
    for (int nf = 0; nf < 4; ++nf)
#pragma unroll
        for (int r = 0; r < 4; ++r) {
            int row = wv * 16 + quad * 4 + r;
            int col = nf * 16 + m16;
            fs[row * 64 + col] = acc[nf][r] + (bias ? bias[nb + col] : 0.f);
        }
    __syncthreads();
#pragma unroll
    for (int i = 0; i < 4; ++i) {
        int u = i * 256 + tid;
        int row = u >> 4, c4 = u & 15;
        int grow = mb + row;
        if (grow < M)
            *(float4*)(Cf + (size_t)grow * N + nb + c4 * 4) = *(const float4*)(fs + (size_t)u * 4);
    }
    // folded BN stats: per-column sum/sumsq partials -> atomicAdd
    if (stats) {
        float* ps = (float*)(smem + 16384);   // [2][4][64]
        int col = tid & 63, qr = tid >> 6;
        int vr = M - mb; vr = vr < 64 ? vr : 64;
        int r0 = qr * 16, r1 = r0 + 16 < vr ? r0 + 16 : vr;
        float s = 0.f, q = 0.f;
        for (int r = r0; r < r1; ++r) { float v = fs[r * 64 + col]; s += v; q += v * v; }
        ps[qr * 64 + col] = s;
        ps[256 + qr * 64 + col] = q;
        __syncthreads();
        if (tid < 64) {
            float ss = ps[tid] + ps[64 + tid] + ps[128 + tid] + ps[192 + tid];
            atomicAdd(&stats[nb + tid], ss);
        } else if (tid < 128) {
            int c = tid - 64;
            float qq = ps[256 + c] + ps[320 + c] + ps[384 + c] + ps[448 + c];
            atomicAdd(&stats[128 + nb + c], qq);
        }
    }
}

// ---------------- GATv2 aggregate, per-head blocks, bucketed CSR ----------------
// col_src holds pre-scaled BYTE offsets (src*256); per-lane base pointer XLp
// folds the +16*gl term once — each gather address is one 64-bit add.
__global__ __launch_bounds__(256) void k_gat_h(const u32* __restrict__ XLb,
                                               const u32* __restrict__ XRb,
                                               const float* __restrict__ attc,
                                               const float* __restrict__ bias,
                                               const int* __restrict__ cnt,
                                               const int* __restrict__ col_src,
                                               u32* __restrict__ outb) {
    int h = blockIdx.y;
    const u32* XLh = XLb + (size_t)h * NN * 64;
    const u32* XRh = XRb + (size_t)h * NN * 64;
    int node = blockIdx.x * 4 + (threadIdx.x >> 6);
    int lane = threadIdx.x & 63;
    int g = lane >> 4, gl = lane & 15;

    const char* XLp = (const char*)XLh + 16 * gl;   // per-lane base

    f32x2 xr2[4], a6[4], acc2[4];
    const f32x2 c23 = {0.66666667f, 0.66666667f};
    up8f2(*(const uint4*)(XRh + (size_t)node * 64 + 4 * gl), xr2);
#pragma unroll
    for (int j = 0; j < 4; ++j) {
        a6[j] = *(const f32x2*)(attc + h * 128 + 8 * gl + 2 * j);
        acc2[j] = f32x2{0.f, 0.f};
    }
    float l = 0.f;

    int e0 = node << 6;
    int cntE = cnt[node];

    // issue first edge-offset loads early (byte offsets)
    u32 c0o = (u32)col_src[e0 + g];
    u32 c1o = (u32)col_src[e0 + g + 4];

    // self-loop contribution (group 0 only; whole 16-lane DPP row active)
    if (g == 0) {
        f32x2 xs[4];
        up8f2(*(const uint4*)(XLp + ((u32)node << 8)), xs);
        f32x2 p2 = {0.f, 0.f};
#pragma unroll
        for (int j = 0; j < 4; ++j) {
            f32x2 v = pk_add(xs[j], xr2[j]);
            p2 = pk_fma(pk_fma(fabs2(v), c23, v), a6[j], p2);
        }
        float w = __builtin_amdgcn_exp2f(row_sum16(p2.x + p2.y));
        l = w;
        f32x2 w2 = {w, w};
#pragma unroll
        for (int j = 0; j < 4; ++j) acc2[j] = pk_fma(xs[j], w2, acc2[j]);
    }

    uint4 ua = *(const uint4*)(XLp + c0o);
    uint4 ub = *(const uint4*)(XLp + c1o);

    for (int t = g; t < cntE; t += 8) {
        uint4 un0 = *(const uint4*)(XLp + (u32)col_src[e0 + t + 8]);
        uint4 un1 = *(const uint4*)(XLp + (u32)col_src[e0 + t + 12]);

        f32x2 xa2[4], xb2[4];
        up8f2(ua, xa2); up8f2(ub, xb2);
        f32x2 pa2 = {0.f, 0.f}, pb2 = {0.f, 0.f};
#pragma unroll
        for (int j = 0; j < 4; ++j) {
            f32x2 va = pk_add(xa2[j], xr2[j]);
            f32x2 vb = pk_add(xb2[j], xr2[j]);
            pa2 = pk_fma(pk_fma(fabs2(va), c23, va), a6[j], pa2);
            pb2 = pk_fma(pk_fma(fabs2(vb), c23, vb), a6[j], pb2);
        }
        float pa = row_sum16(pa2.x + pa2.y);
        float pb = row_sum16(pb2.x + pb2.y);
        float wa = __builtin_amdgcn_exp2f(pa);
        float wb = ((t + 4) < cntE) ? __builtin_amdgcn_exp2f(pb) : 0.f;
        l += wa + wb;
        f32x2 wa2 = {wa, wa}, wb2 = {wb, wb};
#pragma unroll
        for (int j = 0; j < 4; ++j)
            acc2[j] = pk_fma(xa2[j], wa2, pk_fma(xb2[j], wb2, acc2[j]));

        ua = un0; ub = un1;
    }

#pragma unroll
    for (int o = 16; o <= 32; o <<= 1) {
        l += __shfl_xor(l, o);
#pragma unroll
        for (int j = 0; j < 4; ++j) {
            f32x2 s;
            s.x = __shfl_xor(acc2[j].x, o);
            s.y = __shfl_xor(acc2[j].y, o);
            acc2[j] = pk_add(acc2[j], s);
        }
    }

    if (g == 0) {
        float r = 1.f / l;
        float bv[8];
        *(float4*)&bv[0] = *(const float4*)&bias[h * 128 + 8 * gl];
        *(float4*)&bv[4] = *(const float4*)&bias[h * 128 + 8 * gl + 4];
        uint4 w;
        w.x = bf16_1(fmaf(acc2[0].x, r, bv[0])) | (bf16_1(fmaf(acc2[0].y, r, bv[1])) << 16);
        w.y = bf16_1(fmaf(acc2[1].x, r, bv[2])) | (bf16_1(fmaf(acc2[1].y, r, bv[3])) << 16);
        w.z = bf16_1(fmaf(acc2[2].x, r, bv[4])) | (bf16_1(fmaf(acc2[2].y, r, bv[5])) << 16);
        w.w = bf16_1(fmaf(acc2[3].x, r, bv[6])) | (bf16_1(fmaf(acc2[3].y, r, bv[7])) << 16);
        *(uint4*)(outb + (size_t)node * 384 + h * 64 + 4 * gl) = w;
    }
}

// ---------------- BN apply (final output only) ----------------
__global__ void k_bn_apply(float* __restrict__ y, const float* __restrict__ stats,
                           const float* __restrict__ g, const float* __restrict__ be,
                           u16* __restrict__ yb, int wf) {
    int i = blockIdx.x * 256 + threadIdx.x;
    if (i >= NN * DD / 8) return;
    int idx = i * 8;
    int c0 = idx & 127;
    float v[8];
    *(float4*)&v[0] = *(const float4*)(y + idx);
    *(float4*)&v[4] = *(const float4*)(y + idx + 4);
    const float minv = 1.f / (float)NN;
#pragma unroll
    for (int k = 0; k < 8; ++k) {
        int c = c0 + k;
        float mu = stats[c] * minv;
        float var = stats[128 + c] * minv - mu * mu;
        float sc = g[c] * rsqrtf(var + EPS);
        float sh = be[c] - mu * sc;
        v[k] = fmaxf(fmaf(v[k], sc, sh), 0.f);
    }
    if (wf) {
        *(float4*)(y + idx) = *(const float4*)&v[0];
        *(float4*)(y + idx + 4) = *(const float4*)&v[4];
    }
    if (yb) {
        uint4 w;
        w.x = bf16_1(v[0]) | (bf16_1(v[1]) << 16);
        w.y = bf16_1(v[2]) | (bf16_1(v[3]) << 16);
        w.z = bf16_1(v[4]) | (bf16_1(v[5]) << 16);
        w.w = bf16_1(v[6]) | (bf16_1(v[7]) << 16);
        *(uint4*)(yb + idx) = w;
    }
}

// ---------------- launch ----------------

extern "C" void kernel_launch(void* const* d_in, const int* in_sizes, int n_in,
                              void* d_out, int out_size, void* d_ws, size_t ws_size,
                              hipStream_t stream) {
    const float* x    = (const float*)d_in[0];
    const int*   ei   = (const int*)d_in[1];
    const float* Wl1  = (const float*)d_in[2];
    const float* bl1  = (const float*)d_in[3];
    const float* Wr1  = (const float*)d_in[4];
    const float* br1  = (const float*)d_in[5];
    const float* att1 = (const float*)d_in[6];
    const float* bc1  = (const float*)d_in[7];
    const float* g1   = (const float*)d_in[8];
    const float* be1  = (const float*)d_in[9];
    const float* Wl2  = (const float*)d_in[10];
    const float* bl2  = (const float*)d_in[11];
    const float* Wr2  = (const float*)d_in[12];
    const float* br2  = (const float*)d_in[13];
    const float* att2 = (const float*)d_in[14];
    const float* bc2  = (const float*)d_in[15];
    const float* g2   = (const float*)d_in[16];
    const float* be2  = (const float*)d_in[17];
    const float* W1   = (const float*)d_in[18];
    const float* b1   = (const float*)d_in[19];
    const float* W2   = (const float*)d_in[20];
    const float* b2   = (const float*)d_in[21];
    const int* esrc = ei;
    const int* edst = ei + NE;
    float* out = (float*)d_out;

    // ---- workspace layout (all regions 16B-aligned) ----
    float* bufD   = (float*)d_ws;          // mid fp32 [NN,128]      12.8 MB
    float* stats  = bufD + 3200000;        // 512 f (BN1 +0, BN2 +256)
    int* cnt      = (int*)(stats + 512);   // 25000 edge counters
    int* col_src  = cnt + 25000;           // [NN][64] buckets + 24 pad  6.4 MB
    float* fb1    = (float*)(col_src + 1600024);  // 768 fused bias L1
    float* fb2    = fb1 + 768;             // 768 fused bias L2
    float* attc1  = fb2 + 768;             // 384 pre-scaled att L1
    float* attc2  = attc1 + 384;           // 384 pre-scaled att L2
    u16* XLb      = (u16*)(attc2 + 384);   // head-major xl [3][NN][128]  19.2 MB
    u16* XRb      = XLb + 3 * NN * 128;    // head-major xr [3][NN][128]
    u16* bufCat   = XRb + 3 * NN * 128;    // [NN,768] h2|x_in bf16  38.4 MB
    u16* WfT1     = bufCat + 19200000;     // [768][128]
    u16* W1T      = WfT1 + 98304;          // [128][384]
    u16* WfT2     = W1T + 49152;           // [768][128]
    u16* W2T      = WfT2 + 98304;          // [128][768]

    // one memset over contiguous cnt+col_src, then fused cast/fill kernel
    hipMemsetAsync(cnt, 0, (25000 + NN * 64 + 24) * sizeof(int), stream);
    k_cast_all<<<(CAST_TOTAL + 255) / 256, 256, 0, stream>>>(
        Wl1, Wr1, W1, Wl2, Wr2, W2, bl1, br1, bl2, br2, att1, att2, esrc, edst,
        WfT1, W1T, WfT2, W2T, fb1, fb2, attc1, attc2, cnt, col_src, stats);

    dim3 blk(256);
    dim3 gK(3, (NN + 63) / 64);          // K=128 GEMMs: 1173 blocks, 2-tile loop
    dim3 g64(2, (NN + 63) / 64);         // BM=64 GEMMs: 782 blocks
    dim3 gGat((NN + 3) / 4, 3);          // gat: per-head blocks (L2 tiling)

    // layer 1 (x cast fused into A staging)
    k_gemm_k128c<<<gK, blk, 0, stream>>>(x, WfT1, fb1, XLb, NN);
    k_gat_h<<<gGat, blk, 0, stream>>>((const u32*)XLb, (const u32*)XRb, attc1, bc1,
                                      cnt, col_src, (u32*)bufCat + 192);

    // mid MLP (+BN stats folded); BN1-apply fused into the layer-2 transform
    k_gemm_bf<<<g64, blk, 0, stream>>>(bufCat + 384, W1T, b1, bufD, stats, NN, DD, HD, 768);

    // layer 2 (A = bufD fp32, BN1+ReLU+cast fused into staging)
    k_gemm_k128_bn<<<gK, blk, 0, stream>>>(bufD, stats, g1, be1, WfT2, fb2, XLb, NN);
    k_gat_h<<<gGat, blk, 0, stream>>>((const u32*)XLb, (const u32*)XRb, attc2, bc2,
                                      cnt, col_src, (u32*)bufCat);

    // final GEMM (+BN stats folded) + BN apply
    k_gemm_bf<<<g64, blk, 0, stream>>>(bufCat, W2T, b2, out, stats + 256, NN, DD, 768, 768);
    k_bn_apply<<<(NN * DD / 8 + 255) / 256, 256, 0, stream>>>(out, stats + 256, g2, be2, nullptr, 1);
}